// Round 13
// baseline (3382.873 us; speedup 1.0000x reference)
//
#include <hip/hip_runtime.h>
#include <math.h>

// ---- problem constants ----
constexpr int SEQ = 2048;
constexpr int DIM = 1024;
constexpr int NH  = 16;
constexpr int HD  = 64;
constexpr int FF  = 4096;
constexpr int NL  = 12;
constexpr int VOC = 1400;
constexpr int VOCP = 1408;   // padded to 64

typedef __bf16 bf16_t;
typedef __bf16 bf16x8 __attribute__((ext_vector_type(8)));
typedef float  f32x4  __attribute__((ext_vector_type(4)));

typedef __attribute__((address_space(1))) const void GV;
typedef __attribute__((address_space(3))) void LV;

__device__ __forceinline__ void gll16(const bf16_t* g, bf16_t* l) {
  __builtin_amdgcn_global_load_lds((GV*)g, (LV*)l, 16, 0, 0);
}

// ---------------- embedding gather ----------------
__global__ __launch_bounds__(256) void k_embed(const int* __restrict__ ids,
                                               const float* __restrict__ emb,
                                               float* __restrict__ x) {
  int s = blockIdx.x;
  int d = threadIdx.x * 4;
  const float4 v = *(const float4*)&emb[(size_t)ids[s] * DIM + d];
  *(float4*)&x[(size_t)s * DIM + d] = v;
}

// ---------------- RoPE cos/sin table: [s][i], i = freq idx 0..31 ----------------
__global__ __launch_bounds__(256) void k_rtab(float* __restrict__ ct,
                                              float* __restrict__ st) {
  int id = blockIdx.x * 256 + threadIdx.x;   // SEQ*32
  int i = id & 31;
  int s = id >> 5;
  float ang = (float)s * powf(10000.f, -(float)i * (1.f / 32.f));
  float sn, cs;
  sincosf(ang, &sn, &cs);
  ct[id] = cs;
  st[id] = sn;
}

// ------- layernorm (f32 in -> bf16 out), 4 rows/block, 1 wave per row -------
__global__ __launch_bounds__(256) void k_ln(const float* __restrict__ x,
                                            const float* __restrict__ sc,
                                            const float* __restrict__ bi,
                                            bf16_t* __restrict__ out) {
  int s = blockIdx.x * 4 + (threadIdx.x >> 6);
  int l = threadIdx.x & 63;
  const float* xr = x + (size_t)s * DIM;
  float4 v[4];
  float sum = 0.f, sq = 0.f;
#pragma unroll
  for (int i = 0; i < 4; ++i) {
    v[i] = *(const float4*)&xr[i * 256 + l * 4];
#pragma unroll
    for (int j = 0; j < 4; ++j) { sum += v[i][j]; sq += v[i][j] * v[i][j]; }
  }
#pragma unroll
  for (int d = 1; d < 64; d <<= 1) {
    sum += __shfl_xor(sum, d);
    sq  += __shfl_xor(sq, d);
  }
  float mean = sum * (1.f / DIM);
  float var  = sq * (1.f / DIM) - mean * mean;
  float inv  = rsqrtf(var + 1e-5f);
#pragma unroll
  for (int i = 0; i < 4; ++i) {
    int off = i * 256 + l * 4;
    float4 scv = *(const float4*)&sc[off];
    float4 biv = *(const float4*)&bi[off];
#pragma unroll
    for (int j = 0; j < 4; ++j) {
      float o = (v[i][j] - mean) * inv * scv[j] + biv[j];
      out[(size_t)s * DIM + off + j] = (bf16_t)o;
    }
  }
}

// ------- weight convert + transpose: src[K][N] f32 -> dst[...][K] bf16 -------
// imode 0: dst row = n. imode 1: w1 f -> (f>>4)*32+(f&15). imode 2: w3 -> +16.
__global__ __launch_bounds__(256) void k_cvt_t(const float* __restrict__ src,
                                               bf16_t* __restrict__ dst,
                                               int K_, int N_, int Npad_,
                                               size_t dstride, int imode) {
  __shared__ bf16_t T[64][66];
  const int k0 = blockIdx.y * 64;
  const int n0 = blockIdx.x * 64;
  const size_t so = (size_t)blockIdx.z * K_ * N_;
  const size_t dof = (size_t)blockIdx.z * dstride;
  const int t = threadIdx.x;
  const int kk = t >> 4;
  const int nn = (t & 15) * 4;
#pragma unroll
  for (int it = 0; it < 4; ++it) {
    int krow = kk + it * 16;
    float4 v = {0.f, 0.f, 0.f, 0.f};
    if (n0 + nn < N_) v = *(const float4*)&src[so + (size_t)(k0 + krow) * N_ + n0 + nn];
#pragma unroll
    for (int q = 0; q < 4; ++q) T[nn + q][krow] = (bf16_t)v[q];
  }
  __syncthreads();
#pragma unroll
  for (int it = 0; it < 4; ++it) {
    int c = it * 256 + t;
    int nr = c >> 4;
    int kc = (c & 15) * 4;
    int f = n0 + nr;
    int drow = (imode == 0) ? f : ((f >> 4) * 32 + ((imode == 2) ? 16 : 0) + (f & 15));
    ushort4 o = *(const ushort4*)&T[nr][kc];
    *(ushort4*)&dst[dof + (size_t)drow * K_ + k0 + kc] = o;
  }
}

// ---------------- GEMM: C[M,N] = A[M,K] * Bt[N][K], bf16 MFMA ----------------
// tile 128 x TN, BK=64, 4 waves (2x2). XOR-swizzled staging (round-9 verified).
// OUTMODE 0: f32 store | 2: f32 += | 4: fused QKV(+RoPE) | 6: interleaved silu-gate
template <int TN, int OUTMODE>
__global__ __launch_bounds__(256) void k_gemm2(const bf16_t* __restrict__ A,
                                               const bf16_t* __restrict__ Bt,
                                               float* __restrict__ Cf,
                                               bf16_t* __restrict__ Cb,
                                               bf16_t* __restrict__ aux1,
                                               bf16_t* __restrict__ aux2,
                                               const float* __restrict__ ct,
                                               const float* __restrict__ st,
                                               int M, int N, int K) {
  constexpr int JN = TN / 32;            // B frags per wave
  constexpr int NBI = TN / 32;           // B stage issues (rows/32)
  __shared__ bf16_t As[128 * 64];
  __shared__ bf16_t Bs[TN * 64];
  const int t = threadIdx.x;
  const int w = t >> 6, l = t & 63;
  const int h = l >> 4, r16 = l & 15;
  const int m0 = blockIdx.y * 128, n0 = blockIdx.x * TN;
  const int wr = (w >> 1) * 64;
  const int wc = (w & 1) * (TN / 2);
  const int sr8  = l >> 3;               // 0..7 row within wave-slab
  const int xch  = ((l & 7) ^ sr8) * 8;  // pre-swizzled k-chunk offset (elems)
  const int s7   = r16 & 7;              // reader swizzle key

  f32x4 acc[4][JN] = {};

  const bf16_t* pa = &A[(size_t)(m0 + w * 8 + sr8) * K + xch];
  const bf16_t* pb = &Bt[(size_t)(n0 + w * 8 + sr8) * K + xch];

  for (int k0 = 0; k0 < K; k0 += 64) {
#pragma unroll
    for (int i = 0; i < 4; ++i)
      gll16(pa + (size_t)i * 32 * K + k0, &As[(i * 32 + w * 8) * 64]);
#pragma unroll
    for (int i = 0; i < NBI; ++i)
      gll16(pb + (size_t)i * 32 * K + k0, &Bs[(i * 32 + w * 8) * 64]);
    __syncthreads();
#pragma unroll
    for (int kk = 0; kk < 2; ++kk) {
      const int p = ((kk * 4 + h) ^ s7) * 8;   // swizzled read position (elems)
      bf16x8 af[4], bfr[JN];
#pragma unroll
      for (int i = 0; i < 4; ++i)
        af[i] = *(const bf16x8*)&As[(wr + i * 16 + r16) * 64 + p];
#pragma unroll
      for (int j = 0; j < JN; ++j)
        bfr[j] = *(const bf16x8*)&Bs[(wc + j * 16 + r16) * 64 + p];
#pragma unroll
      for (int i = 0; i < 4; ++i)
#pragma unroll
        for (int j = 0; j < JN; ++j)
          acc[i][j] = __builtin_amdgcn_mfma_f32_16x16x32_bf16(af[i], bfr[j], acc[i][j], 0, 0, 0);
    }
    __syncthreads();
  }

  if constexpr (OUTMODE == 4) {
    const int reg = n0 >> 10;
    const int cbase = (n0 & 1023) + wc;
    if (reg == 2) {
#pragma unroll
      for (int i = 0; i < 4; ++i)
#pragma unroll
        for (int j = 0; j < JN; ++j)
#pragma unroll
          for (int r = 0; r < 4; ++r) {
            int row = m0 + wr + i * 16 + h * 4 + r;
            Cb[(size_t)row * DIM + cbase + j * 16 + r16] = (bf16_t)acc[i][j][r];
          }
    } else {
      bf16_t* dst = reg ? aux2 : aux1;
#pragma unroll
      for (int i = 0; i < 4; ++i)
#pragma unroll
        for (int r = 0; r < 4; ++r) {
          int row = m0 + wr + i * 16 + h * 4 + r;
          float c0 = ct[row * 32 + r16],      s0 = st[row * 32 + r16];
          float c1 = ct[row * 32 + 16 + r16], s1 = st[row * 32 + 16 + r16];
          float lo0 = acc[i][0][r], hi0 = acc[i][2][r];
          float lo1 = acc[i][1][r], hi1 = acc[i][3][r];
          size_t rb = (size_t)row * DIM + cbase;
          dst[rb + r16]      = (bf16_t)(lo0 * c0 - hi0 * s0);
          dst[rb + 32 + r16] = (bf16_t)(hi0 * c0 + lo0 * s0);
          dst[rb + 16 + r16] = (bf16_t)(lo1 * c1 - hi1 * s1);
          dst[rb + 48 + r16] = (bf16_t)(hi1 * c1 + lo1 * s1);
        }
    }
  } else if constexpr (OUTMODE == 6) {
    const int fbase = ((n0 + wc) >> 5) * 16;
#pragma unroll
    for (int i = 0; i < 4; ++i)
#pragma unroll
      for (int r = 0; r < 4; ++r) {
        int row = m0 + wr + i * 16 + h * 4 + r;
        float a0 = acc[i][0][r], b0 = acc[i][1][r];
        float a1 = acc[i][2][r], b1 = acc[i][3][r];
        float g0 = a0 / (1.f + expf(-a0)) * b0;
        float g1v = a1 / (1.f + expf(-a1)) * b1;
        size_t rb = (size_t)row * FF + fbase;
        aux1[rb + r16]      = (bf16_t)g0;
        aux1[rb + 16 + r16] = (bf16_t)g1v;
      }
  } else {
#pragma unroll
    for (int i = 0; i < 4; ++i)
#pragma unroll
      for (int j = 0; j < JN; ++j)
#pragma unroll
        for (int r = 0; r < 4; ++r) {
          int row = m0 + wr + i * 16 + h * 4 + r;
          int col = n0 + wc + j * 16 + r16;
          if (col < N) {
            float vv = acc[i][j][r];
            size_t idx = (size_t)row * N + col;
            if (OUTMODE == 0) Cf[idx] = vv;
            else Cf[idx] += vv;
          }
        }
  }
}

// ------- w13 GEMM: 256x256 tile, BK=32, 8 waves, TRIPLE-buffered LDS ----------
// Depth-2 counted-vmcnt pipeline (T3+T4): iter t reads buf[t%3], issues
// STAGE(t+2) into buf[(t+2)%3], then waits vmcnt(4) — stage(t+1) retired,
// stage(t+2)'s 4 loads stay in flight across the barrier (never drains to 0
// in steady state). T5 setprio around the 32-MFMA cluster.
// Interleaved w1/w3 silu-gate epilogue (same math/order as k_gemm2<128,6>).
__global__ __launch_bounds__(512, 1) void k_gemm256_gate(const bf16_t* __restrict__ A,
                                                         const bf16_t* __restrict__ Bt,
                                                         bf16_t* __restrict__ gate,
                                                         int K) {
  __shared__ bf16_t As[3][256 * 32];
  __shared__ bf16_t Bs[3][256 * 32];
  const int t = threadIdx.x;
  const int w = t >> 6, l = t & 63;
  const int h = l >> 4, r16 = l & 15;
  const int m0 = blockIdx.y * 256, n0 = blockIdx.x * 256;
  const int wr = (w >> 2) * 128;       // wave M offset: 0 or 128
  const int wc = (w & 3) * 64;         // wave N offset: 0,64,128,192
  const int sr = t >> 2;               // staging row 0..127 (within 128-row half)
  const int sc = t & 3;                // 16B chunk 0..3
  const int xch = (sc ^ (sr & 3)) * 8; // pre-swizzled global chunk (elems)
  const int s3 = r16 & 3;              // reader swizzle key

  f32x4 acc[8][4] = {};

  const bf16_t* pa = &A[(size_t)(m0 + sr) * K + xch];
  const bf16_t* pb = &Bt[(size_t)(n0 + sr) * K + xch];
  const int NT = K >> 5;               // 32-wide K-tiles

  auto STAGE = [&](int kt) {
    const int b = kt % 3;
    const int k0 = kt << 5;
    // wave-uniform LDS base (elems): wave w covers rows w*16..w*16+15 of each half
    bf16_t* baseA = &As[b][w * 512];
    bf16_t* baseB = &Bs[b][w * 512];
    gll16(pa + k0, baseA);
    gll16(pa + (size_t)128 * K + k0, baseA + 128 * 32);
    gll16(pb + k0, baseB);
    gll16(pb + (size_t)128 * K + k0, baseB + 128 * 32);
  };

  STAGE(0);
  STAGE(1);
  asm volatile("s_waitcnt vmcnt(4)" ::: "memory");   // stage(0) landed; stage(1) in flight
  __builtin_amdgcn_s_barrier();
  __builtin_amdgcn_sched_barrier(0);

  for (int tt = 0; tt < NT; ++tt) {
    const int cur = tt % 3;
    if (tt + 2 < NT) STAGE(tt + 2);    // depth-2 prefetch, overlaps compute below
    const int p = (h ^ s3) * 8;        // swizzled read position (elems)
    bf16x8 af[8], bfr[4];
#pragma unroll
    for (int i = 0; i < 8; ++i)
      af[i] = *(const bf16x8*)&As[cur][(wr + i * 16 + r16) * 32 + p];
#pragma unroll
    for (int j = 0; j < 4; ++j)
      bfr[j] = *(const bf16x8*)&Bs[cur][(wc + j * 16 + r16) * 32 + p];
    __builtin_amdgcn_s_setprio(1);
#pragma unroll
    for (int i = 0; i < 8; ++i)
#pragma unroll
      for (int j = 0; j < 4; ++j)
        acc[i][j] = __builtin_amdgcn_mfma_f32_16x16x32_bf16(af[i], bfr[j], acc[i][j], 0, 0, 0);
    __builtin_amdgcn_s_setprio(0);
    if (tt + 2 < NT) {
      asm volatile("s_waitcnt vmcnt(4)" ::: "memory");   // stage(tt+1) landed; keep t+2 in flight
    } else {
      asm volatile("s_waitcnt vmcnt(0)" ::: "memory");   // epilogue: full drain required
    }
    __builtin_amdgcn_s_barrier();
    __builtin_amdgcn_sched_barrier(0);
  }

  // interleaved silu-gate epilogue: j even = w1, j odd = w3 (same features)
  const int fbase = ((n0 + wc) >> 5) * 16;
#pragma unroll
  for (int i = 0; i < 8; ++i)
#pragma unroll
    for (int r = 0; r < 4; ++r) {
      int row = m0 + wr + i * 16 + h * 4 + r;
      float a0 = acc[i][0][r], b0 = acc[i][1][r];
      float a1 = acc[i][2][r], b1 = acc[i][3][r];
      float g0 = a0 / (1.f + expf(-a0)) * b0;
      float g1v = a1 / (1.f + expf(-a1)) * b1;
      size_t rb = (size_t)row * FF + fbase;
      gate[rb + r16]      = (bf16_t)g0;
      gate[rb + 16 + r16] = (bf16_t)g1v;
    }
}

// ------- flash attention: 4 waves/block, swapped-QK, one 64-row tile/block -------
// 512 blocks (2/CU). Complementary pairing via grid map: qt = head<8 ? raw : 31-raw.
__global__ __launch_bounds__(256) void k_attn4(const bf16_t* __restrict__ qb,
                                               const bf16_t* __restrict__ kb,
                                               const bf16_t* __restrict__ vb,
                                               bf16_t* __restrict__ ao) {
  __shared__ bf16_t Ks[64][72];       // K chunk: [key][dh]
  __shared__ bf16_t Vt[64][72];       // V chunk transposed: [dh][key]
  __shared__ bf16_t Pl[4][16][72];    // per-wave P: [qrow][key]
  const int raw = blockIdx.x;         // 0..31
  const int head = blockIdx.y;        // 0..15
  const int qt = (head < 8) ? raw : (31 - raw);   // complementary per-CU pairing
  const int t = threadIdx.x;
  const int w = t >> 6, l = t & 63;
  const int h = l >> 4, r16 = l & 15;
  const size_t hoff = (size_t)head * HD;
  const int srow = t >> 2;            // 0..63 staging row
  const int ssg  = (t & 3) * 8;       // 0,8,16,24

  const int q0 = qt * 64 + w * 16;    // this wave's first q row
  const int q_abs = q0 + r16;         // this lane's q row (softmax axis)

  bf16x8 aq[2];
#pragma unroll
  for (int c = 0; c < 2; ++c)
    aq[c] = *(const bf16x8*)&qb[(size_t)(q0 + r16) * DIM + hoff + c * 32 + h * 8];

  f32x4 o[4] = {};
  float mrun = -1e30f, lrun = 0.f;

  const int kend = qt * 64 + 63;
  for (int k0 = 0; k0 <= kend; k0 += 64) {
    // ---- cooperative stage: K direct, V transposed ----
#pragma unroll
    for (int it = 0; it < 2; ++it) {
      bf16x8 kv = *(const bf16x8*)&kb[(size_t)(k0 + srow) * DIM + hoff + ssg + it * 32];
      *(bf16x8*)&Ks[srow][ssg + it * 32] = kv;
    }
#pragma unroll
    for (int it = 0; it < 2; ++it) {
      bf16x8 vv = *(const bf16x8*)&vb[(size_t)(k0 + srow) * DIM + hoff + ssg + it * 32];
#pragma unroll
      for (int j = 0; j < 8; ++j) Vt[ssg + it * 32 + j][srow] = vv[j];
    }
    __syncthreads();

    if (k0 <= q0 + 15) {              // wave-uniform: skip fully-masked chunks
      // ---- scores transposed: D[key][q] ----
      f32x4 sc[4];
      __builtin_amdgcn_s_setprio(1);
#pragma unroll
      for (int tc = 0; tc < 4; ++tc) {
        f32x4 z = {};
        bf16x8 a0 = *(const bf16x8*)&Ks[tc * 16 + r16][h * 8];
        bf16x8 a1 = *(const bf16x8*)&Ks[tc * 16 + r16][32 + h * 8];
        z = __builtin_amdgcn_mfma_f32_16x16x32_bf16(a0, aq[0], z, 0, 0, 0);
        z = __builtin_amdgcn_mfma_f32_16x16x32_bf16(a1, aq[1], z, 0, 0, 0);
        sc[tc] = z;
      }
      __builtin_amdgcn_s_setprio(0);
      // ---- mask + scale; per-lane max over 16 keys ----
      float pmax = -1e30f;
#pragma unroll
      for (int tc = 0; tc < 4; ++tc)
#pragma unroll
        for (int r = 0; r < 4; ++r) {
          int key = k0 + tc * 16 + h * 4 + r;
          float v = sc[tc][r] * 0.125f;
          if (key > q_abs) v = -1e30f;
          sc[tc][r] = v;
          pmax = fmaxf(pmax, v);
        }
      pmax = fmaxf(pmax, __shfl_xor(pmax, 16));
      pmax = fmaxf(pmax, __shfl_xor(pmax, 32));
      float mnew = fmaxf(mrun, pmax);
      float alpha = expf(mrun - mnew);
      mrun = mnew;
      float ssum = 0.f;
#pragma unroll
      for (int tc = 0; tc < 4; ++tc)
#pragma unroll
        for (int r = 0; r < 4; ++r) {
          float pv = expf(sc[tc][r] - mnew);
          sc[tc][r] = pv;
          ssum += pv;
        }
      ssum += __shfl_xor(ssum, 16);
      ssum += __shfl_xor(ssum, 32);
      lrun = lrun * alpha + ssum;
      // ---- write P^T to LDS: Pl[q][key] ----
#pragma unroll
      for (int tc = 0; tc < 4; ++tc)
#pragma unroll
        for (int r = 0; r < 4; ++r)
          Pl[w][r16][tc * 16 + h * 4 + r] = (bf16_t)sc[tc][r];
      // ---- rescale o: alpha for o-row q=h*4+r lives in lane h*4+r ----
      float ar[4];
#pragma unroll
      for (int r = 0; r < 4; ++r) ar[r] = __shfl(alpha, h * 4 + r);
#pragma unroll
      for (int cti = 0; cti < 4; ++cti)
#pragma unroll
        for (int r = 0; r < 4; ++r) o[cti][r] *= ar[r];
      // ---- PV ----
      bf16x8 pa0 = *(const bf16x8*)&Pl[w][r16][h * 8];
      bf16x8 pa1 = *(const bf16x8*)&Pl[w][r16][32 + h * 8];
      __builtin_amdgcn_s_setprio(1);
#pragma unroll
      for (int cti = 0; cti < 4; ++cti) {
        bf16x8 v0 = *(const bf16x8*)&Vt[cti * 16 + r16][h * 8];
        bf16x8 v1 = *(const bf16x8*)&Vt[cti * 16 + r16][32 + h * 8];
        o[cti] = __builtin_amdgcn_mfma_f32_16x16x32_bf16(pa0, v0, o[cti], 0, 0, 0);
        o[cti] = __builtin_amdgcn_mfma_f32_16x16x32_bf16(pa1, v1, o[cti], 0, 0, 0);
      }
      __builtin_amdgcn_s_setprio(0);
    }
    __syncthreads();
  }
  float lr[4];
#pragma unroll
  for (int r = 0; r < 4; ++r) lr[r] = __shfl(lrun, h * 4 + r);
#pragma unroll
  for (int cti = 0; cti < 4; ++cti)
#pragma unroll
    for (int r = 0; r < 4; ++r) {
      int row = q0 + h * 4 + r;
      ao[(size_t)row * DIM + hoff + cti * 16 + r16] = (bf16_t)(o[cti][r] / lr[r]);
    }
}

extern "C" void kernel_launch(void* const* d_in, const int* in_sizes, int n_in,
                              void* d_out, int out_size, void* d_ws, size_t ws_size,
                              hipStream_t stream) {
  const int*   ids  = (const int*)d_in[0];
  const float* temb = (const float*)d_in[1];
  const float* Wq   = (const float*)d_in[2];
  const float* Wk   = (const float*)d_in[3];
  const float* Wv   = (const float*)d_in[4];
  const float* Wo   = (const float*)d_in[5];
  const float* ln1s = (const float*)d_in[6];
  const float* ln1b = (const float*)d_in[7];
  const float* ln2s = (const float*)d_in[8];
  const float* ln2b = (const float*)d_in[9];
  const float* w1   = (const float*)d_in[10];
  const float* w2   = (const float*)d_in[11];
  const float* w3   = (const float*)d_in[12];
  const float* lnfs = (const float*)d_in[13];
  const float* lnfb = (const float*)d_in[14];
  const float* lmh  = (const float*)d_in[15];
  float* out = (float*)d_out;

  char* p = (char*)d_ws;
  size_t used = 0;
  auto alloc = [&](size_t bytes) {
    void* r = (void*)p;
    size_t a = (bytes + 255) & ~(size_t)255;
    p += a; used += a;
    return r;
  };
  // activations + tables
  float*  x     = (float*)alloc((size_t)SEQ * DIM * 4);
  bf16_t* hb    = (bf16_t*)alloc((size_t)SEQ * DIM * 2);
  bf16_t* qb2   = (bf16_t*)alloc((size_t)SEQ * DIM * 2);
  bf16_t* kb2   = (bf16_t*)alloc((size_t)SEQ * DIM * 2);
  bf16_t* vb2   = (bf16_t*)alloc((size_t)SEQ * DIM * 2);
  bf16_t* aob   = (bf16_t*)alloc((size_t)SEQ * DIM * 2);
  bf16_t* gateb = (bf16_t*)alloc((size_t)SEQ * FF * 2);
  float*  ctab  = (float*)alloc((size_t)SEQ * 32 * 4);
  float*  stab  = (float*)alloc((size_t)SEQ * 32 * 4);

  const size_t szDD = (size_t)DIM * DIM;    // 1M elems
  const size_t szDF = (size_t)DIM * FF;     // 4M elems
  const size_t wt_bytes = ((size_t)NL * (3 * szDD + szDD + 2 * szDF + szDF) + (size_t)VOCP * DIM) * 2;
  const bool bigws = (ws_size >= used + wt_bytes + (1u << 20));

  bf16_t *bQKV, *bWo, *bW13, *bw2, *blm, *wscratch = nullptr;
  if (bigws) {
    bQKV = (bf16_t*)alloc(NL * 3 * szDD * 2);
    bWo  = (bf16_t*)alloc(NL * szDD * 2);
    bW13 = (bf16_t*)alloc(NL * 2 * szDF * 2);
    bw2  = (bf16_t*)alloc(NL * szDF * 2);
    blm  = (bf16_t*)alloc((size_t)VOCP * DIM * 2);
  } else {
    wscratch = (bf16_t*)alloc(2 * szDF * 2);   // enough for fused w13 of one layer
    bQKV = bWo = bW13 = bw2 = blm = wscratch;
  }

  auto cvt = [&](const float* src, bf16_t* dst, int K_, int N_, int Npad_, int nz,
                 size_t dstride, int imode) {
    dim3 g(Npad_ / 64, K_ / 64, nz);
    k_cvt_t<<<g, 256, 0, stream>>>(src, dst, K_, N_, Npad_, dstride, imode);
  };

  if (bigws) {
    cvt(Wq, bQKV,             DIM, DIM, DIM, NL, 3 * szDD, 0);
    cvt(Wk, bQKV + szDD,      DIM, DIM, DIM, NL, 3 * szDD, 0);
    cvt(Wv, bQKV + 2 * szDD,  DIM, DIM, DIM, NL, 3 * szDD, 0);
    cvt(Wo, bWo,              DIM, DIM, DIM, NL, szDD, 0);
    cvt(w1, bW13,             DIM, FF,  FF,  NL, 2 * szDF, 1);   // interleaved even
    cvt(w3, bW13,             DIM, FF,  FF,  NL, 2 * szDF, 2);   // interleaved odd
    cvt(w2, bw2,              FF,  DIM, DIM, NL, szDF, 0);
    cvt(lmh, blm,             DIM, VOC, VOCP, 1, 0, 0);
  }
  auto wpQKV = [&](int lyr) -> bf16_t* {
    if (bigws) return bQKV + (size_t)lyr * 3 * szDD;
    cvt(Wq + (size_t)lyr * szDD, wscratch,            DIM, DIM, DIM, 1, 0, 0);
    cvt(Wk + (size_t)lyr * szDD, wscratch + szDD,     DIM, DIM, DIM, 1, 0, 0);
    cvt(Wv + (size_t)lyr * szDD, wscratch + 2 * szDD, DIM, DIM, DIM, 1, 0, 0);
    return wscratch;
  };
  auto wpW13 = [&](int lyr) -> bf16_t* {
    if (bigws) return bW13 + (size_t)lyr * 2 * szDF;
    cvt(w1 + (size_t)lyr * szDF, wscratch, DIM, FF, FF, 1, 0, 1);
    cvt(w3 + (size_t)lyr * szDF, wscratch, DIM, FF, FF, 1, 0, 2);
    return wscratch;
  };
  auto wp1 = [&](bf16_t* big, const float* src, int lyr, int K_, int N_, int Npad_) -> bf16_t* {
    if (bigws) return big + (size_t)lyr * Npad_ * K_;
    cvt(src + (size_t)lyr * K_ * N_, wscratch, K_, N_, Npad_, 1, 0, 0);
    return wscratch;
  };

  k_rtab<<<(SEQ * 32) / 256, 256, 0, stream>>>(ctab, stab);
  k_embed<<<SEQ, 256, 0, stream>>>(ids, temb, x);

  dim3 gQKV(3 * DIM / 128, SEQ / 128);   // 24 x 16 = 384
  dim3 gDD(DIM / 64, SEQ / 128);         // 16 x 16 = 256
  dim3 gW13(2 * FF / 256, SEQ / 256);    // 32 x 8 = 256 (1/CU, 256^2 pipelined)
  dim3 gLM(VOCP / 64, SEQ / 128);        // 22 x 16 = 352
  dim3 gAt(32, NH);                      // 32 tiles x 16 heads = 512 (2/CU)

  for (int l = 0; l < NL; ++l) {
    k_ln<<<SEQ / 4, 256, 0, stream>>>(x, ln1s + (size_t)l * DIM, ln1b + (size_t)l * DIM, hb);
    k_gemm2<128, 4><<<gQKV, 256, 0, stream>>>(hb, wpQKV(l), nullptr, vb2, qb2, kb2,
                                              ctab, stab, SEQ, 3 * DIM, DIM);
    k_attn4<<<gAt, 256, 0, stream>>>(qb2, kb2, vb2, aob);
    k_gemm2<64, 2><<<gDD, 256, 0, stream>>>(aob, wp1(bWo, Wo, l, DIM, DIM, DIM), x, nullptr,
                                            nullptr, nullptr, nullptr, nullptr, SEQ, DIM, DIM);
    k_ln<<<SEQ / 4, 256, 0, stream>>>(x, ln2s + (size_t)l * DIM, ln2b + (size_t)l * DIM, hb);
    k_gemm256_gate<<<gW13, 512, 0, stream>>>(hb, wpW13(l), gateb, DIM);
    k_gemm2<64, 2><<<gDD, 256, 0, stream>>>(gateb, wp1(bw2, w2, l, FF, DIM, DIM), x, nullptr,
                                            nullptr, nullptr, nullptr, nullptr, SEQ, DIM, FF);
  }
  k_ln<<<SEQ / 4, 256, 0, stream>>>(x, lnfs, lnfb, hb);
  k_gemm2<64, 0><<<gLM, 256, 0, stream>>>(hb, bigws ? blm : wp1(blm, lmh, 0, DIM, VOC, VOCP),
                                          out, nullptr, nullptr, nullptr, nullptr, nullptr,
                                          SEQ, VOC, DIM);
}

// Round 14
// 3259.612 us; speedup vs baseline: 1.0378x; 1.0378x over previous
//
#include <hip/hip_runtime.h>
#include <math.h>

// ---- problem constants ----
constexpr int SEQ = 2048;
constexpr int DIM = 1024;
constexpr int NH  = 16;
constexpr int HD  = 64;
constexpr int FF  = 4096;
constexpr int NL  = 12;
constexpr int VOC = 1400;
constexpr int VOCP = 1408;   // padded to 64

typedef __bf16 bf16_t;
typedef __bf16 bf16x8 __attribute__((ext_vector_type(8)));
typedef float  f32x4  __attribute__((ext_vector_type(4)));

typedef __attribute__((address_space(1))) const void GV;
typedef __attribute__((address_space(3))) void LV;

__device__ __forceinline__ void gll16(const bf16_t* g, bf16_t* l) {
  __builtin_amdgcn_global_load_lds((GV*)g, (LV*)l, 16, 0, 0);
}

// ---------------- embedding gather ----------------
__global__ __launch_bounds__(256) void k_embed(const int* __restrict__ ids,
                                               const float* __restrict__ emb,
                                               float* __restrict__ x) {
  int s = blockIdx.x;
  int d = threadIdx.x * 4;
  const float4 v = *(const float4*)&emb[(size_t)ids[s] * DIM + d];
  *(float4*)&x[(size_t)s * DIM + d] = v;
}

// ---------------- RoPE cos/sin table: [s][i], i = freq idx 0..31 ----------------
__global__ __launch_bounds__(256) void k_rtab(float* __restrict__ ct,
                                              float* __restrict__ st) {
  int id = blockIdx.x * 256 + threadIdx.x;   // SEQ*32
  int i = id & 31;
  int s = id >> 5;
  float ang = (float)s * powf(10000.f, -(float)i * (1.f / 32.f));
  float sn, cs;
  sincosf(ang, &sn, &cs);
  ct[id] = cs;
  st[id] = sn;
}

// ------- layernorm (f32 in -> bf16 out), 4 rows/block, 1 wave per row -------
__global__ __launch_bounds__(256) void k_ln(const float* __restrict__ x,
                                            const float* __restrict__ sc,
                                            const float* __restrict__ bi,
                                            bf16_t* __restrict__ out) {
  int s = blockIdx.x * 4 + (threadIdx.x >> 6);
  int l = threadIdx.x & 63;
  const float* xr = x + (size_t)s * DIM;
  float4 v[4];
  float sum = 0.f, sq = 0.f;
#pragma unroll
  for (int i = 0; i < 4; ++i) {
    v[i] = *(const float4*)&xr[i * 256 + l * 4];
#pragma unroll
    for (int j = 0; j < 4; ++j) { sum += v[i][j]; sq += v[i][j] * v[i][j]; }
  }
#pragma unroll
  for (int d = 1; d < 64; d <<= 1) {
    sum += __shfl_xor(sum, d);
    sq  += __shfl_xor(sq, d);
  }
  float mean = sum * (1.f / DIM);
  float var  = sq * (1.f / DIM) - mean * mean;
  float inv  = rsqrtf(var + 1e-5f);
#pragma unroll
  for (int i = 0; i < 4; ++i) {
    int off = i * 256 + l * 4;
    float4 scv = *(const float4*)&sc[off];
    float4 biv = *(const float4*)&bi[off];
#pragma unroll
    for (int j = 0; j < 4; ++j) {
      float o = (v[i][j] - mean) * inv * scv[j] + biv[j];
      out[(size_t)s * DIM + off + j] = (bf16_t)o;
    }
  }
}

// ------- weight convert + transpose: src[K][N] f32 -> dst[...][K] bf16 -------
// imode 0: dst row = n. imode 1: w1 f -> (f>>4)*32+(f&15). imode 2: w3 -> +16.
__global__ __launch_bounds__(256) void k_cvt_t(const float* __restrict__ src,
                                               bf16_t* __restrict__ dst,
                                               int K_, int N_, int Npad_,
                                               size_t dstride, int imode) {
  __shared__ bf16_t T[64][66];
  const int k0 = blockIdx.y * 64;
  const int n0 = blockIdx.x * 64;
  const size_t so = (size_t)blockIdx.z * K_ * N_;
  const size_t dof = (size_t)blockIdx.z * dstride;
  const int t = threadIdx.x;
  const int kk = t >> 4;
  const int nn = (t & 15) * 4;
#pragma unroll
  for (int it = 0; it < 4; ++it) {
    int krow = kk + it * 16;
    float4 v = {0.f, 0.f, 0.f, 0.f};
    if (n0 + nn < N_) v = *(const float4*)&src[so + (size_t)(k0 + krow) * N_ + n0 + nn];
#pragma unroll
    for (int q = 0; q < 4; ++q) T[nn + q][krow] = (bf16_t)v[q];
  }
  __syncthreads();
#pragma unroll
  for (int it = 0; it < 4; ++it) {
    int c = it * 256 + t;
    int nr = c >> 4;
    int kc = (c & 15) * 4;
    int f = n0 + nr;
    int drow = (imode == 0) ? f : ((f >> 4) * 32 + ((imode == 2) ? 16 : 0) + (f & 15));
    ushort4 o = *(const ushort4*)&T[nr][kc];
    *(ushort4*)&dst[dof + (size_t)drow * K_ + k0 + kc] = o;
  }
}

// ---------------- GEMM: C[M,N] = A[M,K] * Bt[N][K], bf16 MFMA ----------------
// tile 128 x TN, BK=64, 4 waves (2x2). XOR-swizzled staging (round-9 verified).
// OUTMODE 0: f32 store | 2: f32 += | 4: fused QKV(+RoPE) | 6: interleaved silu-gate
template <int TN, int OUTMODE>
__global__ __launch_bounds__(256) void k_gemm2(const bf16_t* __restrict__ A,
                                               const bf16_t* __restrict__ Bt,
                                               float* __restrict__ Cf,
                                               bf16_t* __restrict__ Cb,
                                               bf16_t* __restrict__ aux1,
                                               bf16_t* __restrict__ aux2,
                                               const float* __restrict__ ct,
                                               const float* __restrict__ st,
                                               int M, int N, int K) {
  constexpr int JN = TN / 32;            // B frags per wave
  constexpr int NBI = TN / 32;           // B stage issues (rows/32)
  __shared__ bf16_t As[128 * 64];
  __shared__ bf16_t Bs[TN * 64];
  const int t = threadIdx.x;
  const int w = t >> 6, l = t & 63;
  const int h = l >> 4, r16 = l & 15;
  const int m0 = blockIdx.y * 128, n0 = blockIdx.x * TN;
  const int wr = (w >> 1) * 64;
  const int wc = (w & 1) * (TN / 2);
  const int sr8  = l >> 3;               // 0..7 row within wave-slab
  const int xch  = ((l & 7) ^ sr8) * 8;  // pre-swizzled k-chunk offset (elems)
  const int s7   = r16 & 7;              // reader swizzle key

  f32x4 acc[4][JN] = {};

  const bf16_t* pa = &A[(size_t)(m0 + w * 8 + sr8) * K + xch];
  const bf16_t* pb = &Bt[(size_t)(n0 + w * 8 + sr8) * K + xch];

  for (int k0 = 0; k0 < K; k0 += 64) {
#pragma unroll
    for (int i = 0; i < 4; ++i)
      gll16(pa + (size_t)i * 32 * K + k0, &As[(i * 32 + w * 8) * 64]);
#pragma unroll
    for (int i = 0; i < NBI; ++i)
      gll16(pb + (size_t)i * 32 * K + k0, &Bs[(i * 32 + w * 8) * 64]);
    __syncthreads();
#pragma unroll
    for (int kk = 0; kk < 2; ++kk) {
      const int p = ((kk * 4 + h) ^ s7) * 8;   // swizzled read position (elems)
      bf16x8 af[4], bfr[JN];
#pragma unroll
      for (int i = 0; i < 4; ++i)
        af[i] = *(const bf16x8*)&As[(wr + i * 16 + r16) * 64 + p];
#pragma unroll
      for (int j = 0; j < JN; ++j)
        bfr[j] = *(const bf16x8*)&Bs[(wc + j * 16 + r16) * 64 + p];
#pragma unroll
      for (int i = 0; i < 4; ++i)
#pragma unroll
        for (int j = 0; j < JN; ++j)
          acc[i][j] = __builtin_amdgcn_mfma_f32_16x16x32_bf16(af[i], bfr[j], acc[i][j], 0, 0, 0);
    }
    __syncthreads();
  }

  if constexpr (OUTMODE == 4) {
    const int reg = n0 >> 10;
    const int cbase = (n0 & 1023) + wc;
    if (reg == 2) {
#pragma unroll
      for (int i = 0; i < 4; ++i)
#pragma unroll
        for (int j = 0; j < JN; ++j)
#pragma unroll
          for (int r = 0; r < 4; ++r) {
            int row = m0 + wr + i * 16 + h * 4 + r;
            Cb[(size_t)row * DIM + cbase + j * 16 + r16] = (bf16_t)acc[i][j][r];
          }
    } else {
      bf16_t* dst = reg ? aux2 : aux1;
#pragma unroll
      for (int i = 0; i < 4; ++i)
#pragma unroll
        for (int r = 0; r < 4; ++r) {
          int row = m0 + wr + i * 16 + h * 4 + r;
          float c0 = ct[row * 32 + r16],      s0 = st[row * 32 + r16];
          float c1 = ct[row * 32 + 16 + r16], s1 = st[row * 32 + 16 + r16];
          float lo0 = acc[i][0][r], hi0 = acc[i][2][r];
          float lo1 = acc[i][1][r], hi1 = acc[i][3][r];
          size_t rb = (size_t)row * DIM + cbase;
          dst[rb + r16]      = (bf16_t)(lo0 * c0 - hi0 * s0);
          dst[rb + 32 + r16] = (bf16_t)(hi0 * c0 + lo0 * s0);
          dst[rb + 16 + r16] = (bf16_t)(lo1 * c1 - hi1 * s1);
          dst[rb + 48 + r16] = (bf16_t)(hi1 * c1 + lo1 * s1);
        }
    }
  } else if constexpr (OUTMODE == 6) {
    const int fbase = ((n0 + wc) >> 5) * 16;
#pragma unroll
    for (int i = 0; i < 4; ++i)
#pragma unroll
      for (int r = 0; r < 4; ++r) {
        int row = m0 + wr + i * 16 + h * 4 + r;
        float a0 = acc[i][0][r], b0 = acc[i][1][r];
        float a1 = acc[i][2][r], b1 = acc[i][3][r];
        float g0 = a0 / (1.f + expf(-a0)) * b0;
        float g1v = a1 / (1.f + expf(-a1)) * b1;
        size_t rb = (size_t)row * FF + fbase;
        aux1[rb + r16]      = (bf16_t)g0;
        aux1[rb + 16 + r16] = (bf16_t)g1v;
      }
  } else {
#pragma unroll
    for (int i = 0; i < 4; ++i)
#pragma unroll
      for (int j = 0; j < JN; ++j)
#pragma unroll
        for (int r = 0; r < 4; ++r) {
          int row = m0 + wr + i * 16 + h * 4 + r;
          int col = n0 + wc + j * 16 + r16;
          if (col < N) {
            float vv = acc[i][j][r];
            size_t idx = (size_t)row * N + col;
            if (OUTMODE == 0) Cf[idx] = vv;
            else Cf[idx] += vv;
          }
        }
  }
}

// ------- w13 GEMM: 256x256 tile, BK=64, 8 waves (2M x 4N), double-buffered LDS ----
// (round-12 version — best measured). Issue next K-tile's global_load_lds before
// compute; raw s_barrier + inline vmcnt(0).
// Interleaved w1/w3 silu-gate epilogue (same math/order as k_gemm2<128,6>).
__global__ __launch_bounds__(512, 1) void k_gemm256_gate(const bf16_t* __restrict__ A,
                                                         const bf16_t* __restrict__ Bt,
                                                         bf16_t* __restrict__ gate,
                                                         int K) {
  __shared__ bf16_t As[2][256 * 64];
  __shared__ bf16_t Bs[2][256 * 64];
  const int t = threadIdx.x;
  const int w = t >> 6, l = t & 63;
  const int h = l >> 4, r16 = l & 15;
  const int m0 = blockIdx.y * 256, n0 = blockIdx.x * 256;
  const int wr = (w >> 2) * 128;       // wave M offset: 0 or 128
  const int wc = (w & 3) * 64;         // wave N offset: 0,64,128,192
  const int sr = t >> 3;               // staging row within 64-row slab (0..63)
  const int xch = ((t & 7) ^ (sr & 7)) * 8;   // pre-swizzled k-chunk (elems)
  const int s7 = r16 & 7;

  f32x4 acc[8][4] = {};

  const bf16_t* pa = &A[(size_t)(m0 + sr) * K + xch];
  const bf16_t* pb = &Bt[(size_t)(n0 + sr) * K + xch];
  const int NT = K >> 6;

  auto STAGE = [&](int kt, int b) {
    const int k0 = kt << 6;
    bf16_t* baseA = &As[b][(w * 8) * 64];   // wave-uniform LDS base (+lane*16B)
    bf16_t* baseB = &Bs[b][(w * 8) * 64];
#pragma unroll
    for (int i = 0; i < 4; ++i) {
      gll16(pa + (size_t)(i * 64) * K + k0, baseA + i * 64 * 64);
      gll16(pb + (size_t)(i * 64) * K + k0, baseB + i * 64 * 64);
    }
  };

  STAGE(0, 0);
  asm volatile("s_waitcnt vmcnt(0)" ::: "memory");
  __builtin_amdgcn_s_barrier();
  __builtin_amdgcn_sched_barrier(0);

  int cur = 0;
  for (int tt = 0; tt < NT; ++tt) {
    if (tt + 1 < NT) STAGE(tt + 1, cur ^ 1);   // overlap with compute below
#pragma unroll
    for (int kk = 0; kk < 2; ++kk) {
      const int p = ((kk * 4 + h) ^ s7) * 8;
      bf16x8 af[8], bfr[4];
#pragma unroll
      for (int i = 0; i < 8; ++i)
        af[i] = *(const bf16x8*)&As[cur][(wr + i * 16 + r16) * 64 + p];
#pragma unroll
      for (int j = 0; j < 4; ++j)
        bfr[j] = *(const bf16x8*)&Bs[cur][(wc + j * 16 + r16) * 64 + p];
#pragma unroll
      for (int i = 0; i < 8; ++i)
#pragma unroll
        for (int j = 0; j < 4; ++j)
          acc[i][j] = __builtin_amdgcn_mfma_f32_16x16x32_bf16(af[i], bfr[j], acc[i][j], 0, 0, 0);
    }
    asm volatile("s_waitcnt vmcnt(0)" ::: "memory");   // next tile landed
    __builtin_amdgcn_s_barrier();
    __builtin_amdgcn_sched_barrier(0);
    cur ^= 1;
  }

  // interleaved silu-gate epilogue: j even = w1, j odd = w3 (same features)
  const int fbase = ((n0 + wc) >> 5) * 16;
#pragma unroll
  for (int i = 0; i < 8; ++i)
#pragma unroll
    for (int r = 0; r < 4; ++r) {
      int row = m0 + wr + i * 16 + h * 4 + r;
      float a0 = acc[i][0][r], b0 = acc[i][1][r];
      float a1 = acc[i][2][r], b1 = acc[i][3][r];
      float g0 = a0 / (1.f + expf(-a0)) * b0;
      float g1v = a1 / (1.f + expf(-a1)) * b1;
      size_t rb = (size_t)row * FF + fbase;
      gate[rb + r16]      = (bf16_t)g0;
      gate[rb + 16 + r16] = (bf16_t)g1v;
    }
}

// ------- flash attention: 4 waves/block, swapped-QK, one 64-row tile/block -------
// 512 blocks (2/CU). Complementary pairing via grid map: qt = head<8 ? raw : 31-raw.
__global__ __launch_bounds__(256) void k_attn4(const bf16_t* __restrict__ qb,
                                               const bf16_t* __restrict__ kb,
                                               const bf16_t* __restrict__ vb,
                                               bf16_t* __restrict__ ao) {
  __shared__ bf16_t Ks[64][72];       // K chunk: [key][dh]
  __shared__ bf16_t Vt[64][72];       // V chunk transposed: [dh][key]
  __shared__ bf16_t Pl[4][16][72];    // per-wave P: [qrow][key]
  const int raw = blockIdx.x;         // 0..31
  const int head = blockIdx.y;        // 0..15
  const int qt = (head < 8) ? raw : (31 - raw);   // complementary per-CU pairing
  const int t = threadIdx.x;
  const int w = t >> 6, l = t & 63;
  const int h = l >> 4, r16 = l & 15;
  const size_t hoff = (size_t)head * HD;
  const int srow = t >> 2;            // 0..63 staging row
  const int ssg  = (t & 3) * 8;       // 0,8,16,24

  const int q0 = qt * 64 + w * 16;    // this wave's first q row
  const int q_abs = q0 + r16;         // this lane's q row (softmax axis)

  bf16x8 aq[2];
#pragma unroll
  for (int c = 0; c < 2; ++c)
    aq[c] = *(const bf16x8*)&qb[(size_t)(q0 + r16) * DIM + hoff + c * 32 + h * 8];

  f32x4 o[4] = {};
  float mrun = -1e30f, lrun = 0.f;

  const int kend = qt * 64 + 63;
  for (int k0 = 0; k0 <= kend; k0 += 64) {
    // ---- cooperative stage: K direct, V transposed ----
#pragma unroll
    for (int it = 0; it < 2; ++it) {
      bf16x8 kv = *(const bf16x8*)&kb[(size_t)(k0 + srow) * DIM + hoff + ssg + it * 32];
      *(bf16x8*)&Ks[srow][ssg + it * 32] = kv;
    }
#pragma unroll
    for (int it = 0; it < 2; ++it) {
      bf16x8 vv = *(const bf16x8*)&vb[(size_t)(k0 + srow) * DIM + hoff + ssg + it * 32];
#pragma unroll
      for (int j = 0; j < 8; ++j) Vt[ssg + it * 32 + j][srow] = vv[j];
    }
    __syncthreads();

    if (k0 <= q0 + 15) {              // wave-uniform: skip fully-masked chunks
      // ---- scores transposed: D[key][q] ----
      f32x4 sc[4];
      __builtin_amdgcn_s_setprio(1);
#pragma unroll
      for (int tc = 0; tc < 4; ++tc) {
        f32x4 z = {};
        bf16x8 a0 = *(const bf16x8*)&Ks[tc * 16 + r16][h * 8];
        bf16x8 a1 = *(const bf16x8*)&Ks[tc * 16 + r16][32 + h * 8];
        z = __builtin_amdgcn_mfma_f32_16x16x32_bf16(a0, aq[0], z, 0, 0, 0);
        z = __builtin_amdgcn_mfma_f32_16x16x32_bf16(a1, aq[1], z, 0, 0, 0);
        sc[tc] = z;
      }
      __builtin_amdgcn_s_setprio(0);
      // ---- mask + scale; per-lane max over 16 keys ----
      float pmax = -1e30f;
#pragma unroll
      for (int tc = 0; tc < 4; ++tc)
#pragma unroll
        for (int r = 0; r < 4; ++r) {
          int key = k0 + tc * 16 + h * 4 + r;
          float v = sc[tc][r] * 0.125f;
          if (key > q_abs) v = -1e30f;
          sc[tc][r] = v;
          pmax = fmaxf(pmax, v);
        }
      pmax = fmaxf(pmax, __shfl_xor(pmax, 16));
      pmax = fmaxf(pmax, __shfl_xor(pmax, 32));
      float mnew = fmaxf(mrun, pmax);
      float alpha = expf(mrun - mnew);
      mrun = mnew;
      float ssum = 0.f;
#pragma unroll
      for (int tc = 0; tc < 4; ++tc)
#pragma unroll
        for (int r = 0; r < 4; ++r) {
          float pv = expf(sc[tc][r] - mnew);
          sc[tc][r] = pv;
          ssum += pv;
        }
      ssum += __shfl_xor(ssum, 16);
      ssum += __shfl_xor(ssum, 32);
      lrun = lrun * alpha + ssum;
      // ---- write P^T to LDS: Pl[q][key] ----
#pragma unroll
      for (int tc = 0; tc < 4; ++tc)
#pragma unroll
        for (int r = 0; r < 4; ++r)
          Pl[w][r16][tc * 16 + h * 4 + r] = (bf16_t)sc[tc][r];
      // ---- rescale o: alpha for o-row q=h*4+r lives in lane h*4+r ----
      float ar[4];
#pragma unroll
      for (int r = 0; r < 4; ++r) ar[r] = __shfl(alpha, h * 4 + r);
#pragma unroll
      for (int cti = 0; cti < 4; ++cti)
#pragma unroll
        for (int r = 0; r < 4; ++r) o[cti][r] *= ar[r];
      // ---- PV ----
      bf16x8 pa0 = *(const bf16x8*)&Pl[w][r16][h * 8];
      bf16x8 pa1 = *(const bf16x8*)&Pl[w][r16][32 + h * 8];
      __builtin_amdgcn_s_setprio(1);
#pragma unroll
      for (int cti = 0; cti < 4; ++cti) {
        bf16x8 v0 = *(const bf16x8*)&Vt[cti * 16 + r16][h * 8];
        bf16x8 v1 = *(const bf16x8*)&Vt[cti * 16 + r16][32 + h * 8];
        o[cti] = __builtin_amdgcn_mfma_f32_16x16x32_bf16(pa0, v0, o[cti], 0, 0, 0);
        o[cti] = __builtin_amdgcn_mfma_f32_16x16x32_bf16(pa1, v1, o[cti], 0, 0, 0);
      }
      __builtin_amdgcn_s_setprio(0);
    }
    __syncthreads();
  }
  float lr[4];
#pragma unroll
  for (int r = 0; r < 4; ++r) lr[r] = __shfl(lrun, h * 4 + r);
#pragma unroll
  for (int cti = 0; cti < 4; ++cti)
#pragma unroll
    for (int r = 0; r < 4; ++r) {
      int row = q0 + h * 4 + r;
      ao[(size_t)row * DIM + hoff + cti * 16 + r16] = (bf16_t)(o[cti][r] / lr[r]);
    }
}

extern "C" void kernel_launch(void* const* d_in, const int* in_sizes, int n_in,
                              void* d_out, int out_size, void* d_ws, size_t ws_size,
                              hipStream_t stream) {
  const int*   ids  = (const int*)d_in[0];
  const float* temb = (const float*)d_in[1];
  const float* Wq   = (const float*)d_in[2];
  const float* Wk   = (const float*)d_in[3];
  const float* Wv   = (const float*)d_in[4];
  const float* Wo   = (const float*)d_in[5];
  const float* ln1s = (const float*)d_in[6];
  const float* ln1b = (const float*)d_in[7];
  const float* ln2s = (const float*)d_in[8];
  const float* ln2b = (const float*)d_in[9];
  const float* w1   = (const float*)d_in[10];
  const float* w2   = (const float*)d_in[11];
  const float* w3   = (const float*)d_in[12];
  const float* lnfs = (const float*)d_in[13];
  const float* lnfb = (const float*)d_in[14];
  const float* lmh  = (const float*)d_in[15];
  float* out = (float*)d_out;

  char* p = (char*)d_ws;
  size_t used = 0;
  auto alloc = [&](size_t bytes) {
    void* r = (void*)p;
    size_t a = (bytes + 255) & ~(size_t)255;
    p += a; used += a;
    return r;
  };
  // activations + tables
  float*  x     = (float*)alloc((size_t)SEQ * DIM * 4);
  bf16_t* hb    = (bf16_t*)alloc((size_t)SEQ * DIM * 2);
  bf16_t* qb2   = (bf16_t*)alloc((size_t)SEQ * DIM * 2);
  bf16_t* kb2   = (bf16_t*)alloc((size_t)SEQ * DIM * 2);
  bf16_t* vb2   = (bf16_t*)alloc((size_t)SEQ * DIM * 2);
  bf16_t* aob   = (bf16_t*)alloc((size_t)SEQ * DIM * 2);
  bf16_t* gateb = (bf16_t*)alloc((size_t)SEQ * FF * 2);
  float*  ctab  = (float*)alloc((size_t)SEQ * 32 * 4);
  float*  stab  = (float*)alloc((size_t)SEQ * 32 * 4);

  const size_t szDD = (size_t)DIM * DIM;    // 1M elems
  const size_t szDF = (size_t)DIM * FF;     // 4M elems
  const size_t wt_bytes = ((size_t)NL * (3 * szDD + szDD + 2 * szDF + szDF) + (size_t)VOCP * DIM) * 2;
  const bool bigws = (ws_size >= used + wt_bytes + (1u << 20));

  bf16_t *bQKV, *bWo, *bW13, *bw2, *blm, *wscratch = nullptr;
  if (bigws) {
    bQKV = (bf16_t*)alloc(NL * 3 * szDD * 2);
    bWo  = (bf16_t*)alloc(NL * szDD * 2);
    bW13 = (bf16_t*)alloc(NL * 2 * szDF * 2);
    bw2  = (bf16_t*)alloc(NL * szDF * 2);
    blm  = (bf16_t*)alloc((size_t)VOCP * DIM * 2);
  } else {
    wscratch = (bf16_t*)alloc(2 * szDF * 2);   // enough for fused w13 of one layer
    bQKV = bWo = bW13 = bw2 = blm = wscratch;
  }

  auto cvt = [&](const float* src, bf16_t* dst, int K_, int N_, int Npad_, int nz,
                 size_t dstride, int imode) {
    dim3 g(Npad_ / 64, K_ / 64, nz);
    k_cvt_t<<<g, 256, 0, stream>>>(src, dst, K_, N_, Npad_, dstride, imode);
  };

  if (bigws) {
    cvt(Wq, bQKV,             DIM, DIM, DIM, NL, 3 * szDD, 0);
    cvt(Wk, bQKV + szDD,      DIM, DIM, DIM, NL, 3 * szDD, 0);
    cvt(Wv, bQKV + 2 * szDD,  DIM, DIM, DIM, NL, 3 * szDD, 0);
    cvt(Wo, bWo,              DIM, DIM, DIM, NL, szDD, 0);
    cvt(w1, bW13,             DIM, FF,  FF,  NL, 2 * szDF, 1);   // interleaved even
    cvt(w3, bW13,             DIM, FF,  FF,  NL, 2 * szDF, 2);   // interleaved odd
    cvt(w2, bw2,              FF,  DIM, DIM, NL, szDF, 0);
    cvt(lmh, blm,             DIM, VOC, VOCP, 1, 0, 0);
  }
  auto wpQKV = [&](int lyr) -> bf16_t* {
    if (bigws) return bQKV + (size_t)lyr * 3 * szDD;
    cvt(Wq + (size_t)lyr * szDD, wscratch,            DIM, DIM, DIM, 1, 0, 0);
    cvt(Wk + (size_t)lyr * szDD, wscratch + szDD,     DIM, DIM, DIM, 1, 0, 0);
    cvt(Wv + (size_t)lyr * szDD, wscratch + 2 * szDD, DIM, DIM, DIM, 1, 0, 0);
    return wscratch;
  };
  auto wpW13 = [&](int lyr) -> bf16_t* {
    if (bigws) return bW13 + (size_t)lyr * 2 * szDF;
    cvt(w1 + (size_t)lyr * szDF, wscratch, DIM, FF, FF, 1, 0, 1);
    cvt(w3 + (size_t)lyr * szDF, wscratch, DIM, FF, FF, 1, 0, 2);
    return wscratch;
  };
  auto wp1 = [&](bf16_t* big, const float* src, int lyr, int K_, int N_, int Npad_) -> bf16_t* {
    if (bigws) return big + (size_t)lyr * Npad_ * K_;
    cvt(src + (size_t)lyr * K_ * N_, wscratch, K_, N_, Npad_, 1, 0, 0);
    return wscratch;
  };

  k_rtab<<<(SEQ * 32) / 256, 256, 0, stream>>>(ctab, stab);
  k_embed<<<SEQ, 256, 0, stream>>>(ids, temb, x);

  dim3 gQKV(3 * DIM / 128, SEQ / 128);   // 24 x 16 = 384
  dim3 gDD(DIM / 64, SEQ / 128);         // 16 x 16 = 256
  dim3 gW13(2 * FF / 256, SEQ / 256);    // 32 x 8 = 256 (1/CU, 256^2 dbuf kernel)
  dim3 gLM(VOCP / 64, SEQ / 128);        // 22 x 16 = 352
  dim3 gAt(32, NH);                      // 32 tiles x 16 heads = 512 (2/CU)

  for (int l = 0; l < NL; ++l) {
    k_ln<<<SEQ / 4, 256, 0, stream>>>(x, ln1s + (size_t)l * DIM, ln1b + (size_t)l * DIM, hb);
    k_gemm2<128, 4><<<gQKV, 256, 0, stream>>>(hb, wpQKV(l), nullptr, vb2, qb2, kb2,
                                              ctab, stab, SEQ, 3 * DIM, DIM);
    k_attn4<<<gAt, 256, 0, stream>>>(qb2, kb2, vb2, aob);
    k_gemm2<64, 2><<<gDD, 256, 0, stream>>>(aob, wp1(bWo, Wo, l, DIM, DIM, DIM), x, nullptr,
                                            nullptr, nullptr, nullptr, nullptr, SEQ, DIM, DIM);
    k_ln<<<SEQ / 4, 256, 0, stream>>>(x, ln2s + (size_t)l * DIM, ln2b + (size_t)l * DIM, hb);
    k_gemm256_gate<<<gW13, 512, 0, stream>>>(hb, wpW13(l), gateb, DIM);
    k_gemm2<64, 2><<<gDD, 256, 0, stream>>>(gateb, wp1(bw2, w2, l, FF, DIM, DIM), x, nullptr,
                                            nullptr, nullptr, nullptr, nullptr, SEQ, DIM, FF);
  }
  k_ln<<<SEQ / 4, 256, 0, stream>>>(x, lnfs, lnfb, hb);
  k_gemm2<64, 0><<<gLM, 256, 0, stream>>>(hb, bigws ? blm : wp1(blm, lmh, 0, DIM, VOC, VOCP),
                                          out, nullptr, nullptr, nullptr, nullptr, nullptr,
                                          SEQ, VOC, DIM);
}

// Round 15
// 2963.398 us; speedup vs baseline: 1.1416x; 1.1000x over previous
//
#include <hip/hip_runtime.h>
#include <math.h>

// ---- problem constants ----
constexpr int SEQ = 2048;
constexpr int DIM = 1024;
constexpr int NH  = 16;
constexpr int HD  = 64;
constexpr int FF  = 4096;
constexpr int NL  = 12;
constexpr int VOC = 1400;
constexpr int VOCP = 1408;   // padded to 64

typedef __bf16 bf16_t;
typedef __bf16 bf16x8 __attribute__((ext_vector_type(8)));
typedef float  f32x4  __attribute__((ext_vector_type(4)));

typedef __attribute__((address_space(1))) const void GV;
typedef __attribute__((address_space(3))) void LV;

__device__ __forceinline__ void gll16(const bf16_t* g, bf16_t* l) {
  __builtin_amdgcn_global_load_lds((GV*)g, (LV*)l, 16, 0, 0);
}

// ---------------- embedding gather ----------------
__global__ __launch_bounds__(256) void k_embed(const int* __restrict__ ids,
                                               const float* __restrict__ emb,
                                               float* __restrict__ x) {
  int s = blockIdx.x;
  int d = threadIdx.x * 4;
  const float4 v = *(const float4*)&emb[(size_t)ids[s] * DIM + d];
  *(float4*)&x[(size_t)s * DIM + d] = v;
}

// ---------------- RoPE cos/sin table: [s][i], i = freq idx 0..31 ----------------
__global__ __launch_bounds__(256) void k_rtab(float* __restrict__ ct,
                                              float* __restrict__ st) {
  int id = blockIdx.x * 256 + threadIdx.x;   // SEQ*32
  int i = id & 31;
  int s = id >> 5;
  float ang = (float)s * powf(10000.f, -(float)i * (1.f / 32.f));
  float sn, cs;
  sincosf(ang, &sn, &cs);
  ct[id] = cs;
  st[id] = sn;
}

// ------- layernorm (f32 in -> bf16 out), 4 rows/block, 1 wave per row -------
__global__ __launch_bounds__(256) void k_ln(const float* __restrict__ x,
                                            const float* __restrict__ sc,
                                            const float* __restrict__ bi,
                                            bf16_t* __restrict__ out) {
  int s = blockIdx.x * 4 + (threadIdx.x >> 6);
  int l = threadIdx.x & 63;
  const float* xr = x + (size_t)s * DIM;
  float4 v[4];
  float sum = 0.f, sq = 0.f;
#pragma unroll
  for (int i = 0; i < 4; ++i) {
    v[i] = *(const float4*)&xr[i * 256 + l * 4];
#pragma unroll
    for (int j = 0; j < 4; ++j) { sum += v[i][j]; sq += v[i][j] * v[i][j]; }
  }
#pragma unroll
  for (int d = 1; d < 64; d <<= 1) {
    sum += __shfl_xor(sum, d);
    sq  += __shfl_xor(sq, d);
  }
  float mean = sum * (1.f / DIM);
  float var  = sq * (1.f / DIM) - mean * mean;
  float inv  = rsqrtf(var + 1e-5f);
#pragma unroll
  for (int i = 0; i < 4; ++i) {
    int off = i * 256 + l * 4;
    float4 scv = *(const float4*)&sc[off];
    float4 biv = *(const float4*)&bi[off];
#pragma unroll
    for (int j = 0; j < 4; ++j) {
      float o = (v[i][j] - mean) * inv * scv[j] + biv[j];
      out[(size_t)s * DIM + off + j] = (bf16_t)o;
    }
  }
}

// ------- weight convert + transpose: src[K][N] f32 -> dst[...][K] bf16 -------
// imode 0: dst row = n. imode 1: w1 f -> (f>>4)*32+(f&15). imode 2: w3 -> +16.
__global__ __launch_bounds__(256) void k_cvt_t(const float* __restrict__ src,
                                               bf16_t* __restrict__ dst,
                                               int K_, int N_, int Npad_,
                                               size_t dstride, int imode) {
  __shared__ bf16_t T[64][66];
  const int k0 = blockIdx.y * 64;
  const int n0 = blockIdx.x * 64;
  const size_t so = (size_t)blockIdx.z * K_ * N_;
  const size_t dof = (size_t)blockIdx.z * dstride;
  const int t = threadIdx.x;
  const int kk = t >> 4;
  const int nn = (t & 15) * 4;
#pragma unroll
  for (int it = 0; it < 4; ++it) {
    int krow = kk + it * 16;
    float4 v = {0.f, 0.f, 0.f, 0.f};
    if (n0 + nn < N_) v = *(const float4*)&src[so + (size_t)(k0 + krow) * N_ + n0 + nn];
#pragma unroll
    for (int q = 0; q < 4; ++q) T[nn + q][krow] = (bf16_t)v[q];
  }
  __syncthreads();
#pragma unroll
  for (int it = 0; it < 4; ++it) {
    int c = it * 256 + t;
    int nr = c >> 4;
    int kc = (c & 15) * 4;
    int f = n0 + nr;
    int drow = (imode == 0) ? f : ((f >> 4) * 32 + ((imode == 2) ? 16 : 0) + (f & 15));
    ushort4 o = *(const ushort4*)&T[nr][kc];
    *(ushort4*)&dst[dof + (size_t)drow * K_ + k0 + kc] = o;
  }
}

// ---------------- GEMM: C[M,N] = A[M,K] * Bt[N][K], bf16 MFMA ----------------
// tile TM x TN, BK=64, 4 waves (2x2; each wave TM/2 x TN/2). XOR-swizzled
// staging (round-9 verified; row offsets all multiples of 8 so rA&7 == r16&7).
// OUTMODE 0: f32 store | 2: f32 += | 4: fused QKV(+RoPE) | 6: interleaved silu-gate
template <int TM, int TN, int OUTMODE>
__global__ __launch_bounds__(256) void k_gemm2(const bf16_t* __restrict__ A,
                                               const bf16_t* __restrict__ Bt,
                                               float* __restrict__ Cf,
                                               bf16_t* __restrict__ Cb,
                                               bf16_t* __restrict__ aux1,
                                               bf16_t* __restrict__ aux2,
                                               const float* __restrict__ ct,
                                               const float* __restrict__ st,
                                               int M, int N, int K) {
  constexpr int MI = TM / 32;            // A frags per wave (and A stage issues)
  constexpr int JN = TN / 32;            // B frags per wave (and B stage issues)
  __shared__ bf16_t As[TM * 64];
  __shared__ bf16_t Bs[TN * 64];
  const int t = threadIdx.x;
  const int w = t >> 6, l = t & 63;
  const int h = l >> 4, r16 = l & 15;
  const int m0 = blockIdx.y * TM, n0 = blockIdx.x * TN;
  const int wr = (w >> 1) * (TM / 2);
  const int wc = (w & 1) * (TN / 2);
  const int sr8  = l >> 3;               // 0..7 row within wave-slab
  const int xch  = ((l & 7) ^ sr8) * 8;  // pre-swizzled k-chunk offset (elems)
  const int s7   = r16 & 7;              // reader swizzle key

  f32x4 acc[MI][JN] = {};

  const bf16_t* pa = &A[(size_t)(m0 + w * 8 + sr8) * K + xch];
  const bf16_t* pb = &Bt[(size_t)(n0 + w * 8 + sr8) * K + xch];

  for (int k0 = 0; k0 < K; k0 += 64) {
#pragma unroll
    for (int i = 0; i < MI; ++i)
      gll16(pa + (size_t)i * 32 * K + k0, &As[(i * 32 + w * 8) * 64]);
#pragma unroll
    for (int i = 0; i < JN; ++i)
      gll16(pb + (size_t)i * 32 * K + k0, &Bs[(i * 32 + w * 8) * 64]);
    __syncthreads();
#pragma unroll
    for (int kk = 0; kk < 2; ++kk) {
      const int p = ((kk * 4 + h) ^ s7) * 8;   // swizzled read position (elems)
      bf16x8 af[MI], bfr[JN];
#pragma unroll
      for (int i = 0; i < MI; ++i)
        af[i] = *(const bf16x8*)&As[(wr + i * 16 + r16) * 64 + p];
#pragma unroll
      for (int j = 0; j < JN; ++j)
        bfr[j] = *(const bf16x8*)&Bs[(wc + j * 16 + r16) * 64 + p];
#pragma unroll
      for (int i = 0; i < MI; ++i)
#pragma unroll
        for (int j = 0; j < JN; ++j)
          acc[i][j] = __builtin_amdgcn_mfma_f32_16x16x32_bf16(af[i], bfr[j], acc[i][j], 0, 0, 0);
    }
    __syncthreads();
  }

  if constexpr (OUTMODE == 4) {
    const int reg = n0 >> 10;
    const int cbase = (n0 & 1023) + wc;
    if (reg == 2) {
#pragma unroll
      for (int i = 0; i < MI; ++i)
#pragma unroll
        for (int j = 0; j < JN; ++j)
#pragma unroll
          for (int r = 0; r < 4; ++r) {
            int row = m0 + wr + i * 16 + h * 4 + r;
            Cb[(size_t)row * DIM + cbase + j * 16 + r16] = (bf16_t)acc[i][j][r];
          }
    } else {
      bf16_t* dst = reg ? aux2 : aux1;
#pragma unroll
      for (int i = 0; i < MI; ++i)
#pragma unroll
        for (int r = 0; r < 4; ++r) {
          int row = m0 + wr + i * 16 + h * 4 + r;
          float c0 = ct[row * 32 + r16],      s0 = st[row * 32 + r16];
          float c1 = ct[row * 32 + 16 + r16], s1 = st[row * 32 + 16 + r16];
          float lo0 = acc[i][0][r], hi0 = acc[i][2][r];
          float lo1 = acc[i][1][r], hi1 = acc[i][3][r];
          size_t rb = (size_t)row * DIM + cbase;
          dst[rb + r16]      = (bf16_t)(lo0 * c0 - hi0 * s0);
          dst[rb + 32 + r16] = (bf16_t)(hi0 * c0 + lo0 * s0);
          dst[rb + 16 + r16] = (bf16_t)(lo1 * c1 - hi1 * s1);
          dst[rb + 48 + r16] = (bf16_t)(hi1 * c1 + lo1 * s1);
        }
    }
  } else if constexpr (OUTMODE == 6) {
    const int fbase = ((n0 + wc) >> 5) * 16;
#pragma unroll
    for (int i = 0; i < MI; ++i)
#pragma unroll
      for (int r = 0; r < 4; ++r) {
        int row = m0 + wr + i * 16 + h * 4 + r;
        float a0 = acc[i][0][r], b0 = acc[i][1][r];
        float a1 = acc[i][2][r], b1 = acc[i][3][r];
        float g0 = a0 / (1.f + expf(-a0)) * b0;
        float g1v = a1 / (1.f + expf(-a1)) * b1;
        size_t rb = (size_t)row * FF + fbase;
        aux1[rb + r16]      = (bf16_t)g0;
        aux1[rb + 16 + r16] = (bf16_t)g1v;
      }
  } else {
#pragma unroll
    for (int i = 0; i < MI; ++i)
#pragma unroll
      for (int j = 0; j < JN; ++j)
#pragma unroll
        for (int r = 0; r < 4; ++r) {
          int row = m0 + wr + i * 16 + h * 4 + r;
          int col = n0 + wc + j * 16 + r16;
          if (col < N) {
            float vv = acc[i][j][r];
            size_t idx = (size_t)row * N + col;
            if (OUTMODE == 0) Cf[idx] = vv;
            else Cf[idx] += vv;
          }
        }
  }
}

// ------- w13 GEMM: 256x256 tile, BK=64, 8 waves (2M x 4N), double-buffered LDS ----
// (round-12 version — best measured). Interleaved w1/w3 silu-gate epilogue.
__global__ __launch_bounds__(512, 1) void k_gemm256_gate(const bf16_t* __restrict__ A,
                                                         const bf16_t* __restrict__ Bt,
                                                         bf16_t* __restrict__ gate,
                                                         int K) {
  __shared__ bf16_t As[2][256 * 64];
  __shared__ bf16_t Bs[2][256 * 64];
  const int t = threadIdx.x;
  const int w = t >> 6, l = t & 63;
  const int h = l >> 4, r16 = l & 15;
  const int m0 = blockIdx.y * 256, n0 = blockIdx.x * 256;
  const int wr = (w >> 2) * 128;       // wave M offset: 0 or 128
  const int wc = (w & 3) * 64;         // wave N offset: 0,64,128,192
  const int sr = t >> 3;               // staging row within 64-row slab (0..63)
  const int xch = ((t & 7) ^ (sr & 7)) * 8;   // pre-swizzled k-chunk (elems)
  const int s7 = r16 & 7;

  f32x4 acc[8][4] = {};

  const bf16_t* pa = &A[(size_t)(m0 + sr) * K + xch];
  const bf16_t* pb = &Bt[(size_t)(n0 + sr) * K + xch];
  const int NT = K >> 6;

  auto STAGE = [&](int kt, int b) {
    const int k0 = kt << 6;
    bf16_t* baseA = &As[b][(w * 8) * 64];   // wave-uniform LDS base (+lane*16B)
    bf16_t* baseB = &Bs[b][(w * 8) * 64];
#pragma unroll
    for (int i = 0; i < 4; ++i) {
      gll16(pa + (size_t)(i * 64) * K + k0, baseA + i * 64 * 64);
      gll16(pb + (size_t)(i * 64) * K + k0, baseB + i * 64 * 64);
    }
  };

  STAGE(0, 0);
  asm volatile("s_waitcnt vmcnt(0)" ::: "memory");
  __builtin_amdgcn_s_barrier();
  __builtin_amdgcn_sched_barrier(0);

  int cur = 0;
  for (int tt = 0; tt < NT; ++tt) {
    if (tt + 1 < NT) STAGE(tt + 1, cur ^ 1);   // overlap with compute below
#pragma unroll
    for (int kk = 0; kk < 2; ++kk) {
      const int p = ((kk * 4 + h) ^ s7) * 8;
      bf16x8 af[8], bfr[4];
#pragma unroll
      for (int i = 0; i < 8; ++i)
        af[i] = *(const bf16x8*)&As[cur][(wr + i * 16 + r16) * 64 + p];
#pragma unroll
      for (int j = 0; j < 4; ++j)
        bfr[j] = *(const bf16x8*)&Bs[cur][(wc + j * 16 + r16) * 64 + p];
#pragma unroll
      for (int i = 0; i < 8; ++i)
#pragma unroll
        for (int j = 0; j < 4; ++j)
          acc[i][j] = __builtin_amdgcn_mfma_f32_16x16x32_bf16(af[i], bfr[j], acc[i][j], 0, 0, 0);
    }
    asm volatile("s_waitcnt vmcnt(0)" ::: "memory");   // next tile landed
    __builtin_amdgcn_s_barrier();
    __builtin_amdgcn_sched_barrier(0);
    cur ^= 1;
  }

  // interleaved silu-gate epilogue: j even = w1, j odd = w3 (same features)
  const int fbase = ((n0 + wc) >> 5) * 16;
#pragma unroll
  for (int i = 0; i < 8; ++i)
#pragma unroll
    for (int r = 0; r < 4; ++r) {
      int row = m0 + wr + i * 16 + h * 4 + r;
      float a0 = acc[i][0][r], b0 = acc[i][1][r];
      float a1 = acc[i][2][r], b1 = acc[i][3][r];
      float g0 = a0 / (1.f + expf(-a0)) * b0;
      float g1v = a1 / (1.f + expf(-a1)) * b1;
      size_t rb = (size_t)row * FF + fbase;
      gate[rb + r16]      = (bf16_t)g0;
      gate[rb + 16 + r16] = (bf16_t)g1v;
    }
}

// ------- flash attention: 4 waves/block, swapped-QK, one 64-row tile/block -------
// 512 blocks (2/CU). Complementary pairing via grid map: qt = head<8 ? raw : 31-raw.
__global__ __launch_bounds__(256) void k_attn4(const bf16_t* __restrict__ qb,
                                               const bf16_t* __restrict__ kb,
                                               const bf16_t* __restrict__ vb,
                                               bf16_t* __restrict__ ao) {
  __shared__ bf16_t Ks[64][72];       // K chunk: [key][dh]
  __shared__ bf16_t Vt[64][72];       // V chunk transposed: [dh][key]
  __shared__ bf16_t Pl[4][16][72];    // per-wave P: [qrow][key]
  const int raw = blockIdx.x;         // 0..31
  const int head = blockIdx.y;        // 0..15
  const int qt = (head < 8) ? raw : (31 - raw);   // complementary per-CU pairing
  const int t = threadIdx.x;
  const int w = t >> 6, l = t & 63;
  const int h = l >> 4, r16 = l & 15;
  const size_t hoff = (size_t)head * HD;
  const int srow = t >> 2;            // 0..63 staging row
  const int ssg  = (t & 3) * 8;       // 0,8,16,24

  const int q0 = qt * 64 + w * 16;    // this wave's first q row
  const int q_abs = q0 + r16;         // this lane's q row (softmax axis)

  bf16x8 aq[2];
#pragma unroll
  for (int c = 0; c < 2; ++c)
    aq[c] = *(const bf16x8*)&qb[(size_t)(q0 + r16) * DIM + hoff + c * 32 + h * 8];

  f32x4 o[4] = {};
  float mrun = -1e30f, lrun = 0.f;

  const int kend = qt * 64 + 63;
  for (int k0 = 0; k0 <= kend; k0 += 64) {
    // ---- cooperative stage: K direct, V transposed ----
#pragma unroll
    for (int it = 0; it < 2; ++it) {
      bf16x8 kv = *(const bf16x8*)&kb[(size_t)(k0 + srow) * DIM + hoff + ssg + it * 32];
      *(bf16x8*)&Ks[srow][ssg + it * 32] = kv;
    }
#pragma unroll
    for (int it = 0; it < 2; ++it) {
      bf16x8 vv = *(const bf16x8*)&vb[(size_t)(k0 + srow) * DIM + hoff + ssg + it * 32];
#pragma unroll
      for (int j = 0; j < 8; ++j) Vt[ssg + it * 32 + j][srow] = vv[j];
    }
    __syncthreads();

    if (k0 <= q0 + 15) {              // wave-uniform: skip fully-masked chunks
      // ---- scores transposed: D[key][q] ----
      f32x4 sc[4];
      __builtin_amdgcn_s_setprio(1);
#pragma unroll
      for (int tc = 0; tc < 4; ++tc) {
        f32x4 z = {};
        bf16x8 a0 = *(const bf16x8*)&Ks[tc * 16 + r16][h * 8];
        bf16x8 a1 = *(const bf16x8*)&Ks[tc * 16 + r16][32 + h * 8];
        z = __builtin_amdgcn_mfma_f32_16x16x32_bf16(a0, aq[0], z, 0, 0, 0);
        z = __builtin_amdgcn_mfma_f32_16x16x32_bf16(a1, aq[1], z, 0, 0, 0);
        sc[tc] = z;
      }
      __builtin_amdgcn_s_setprio(0);
      // ---- mask + scale; per-lane max over 16 keys ----
      float pmax = -1e30f;
#pragma unroll
      for (int tc = 0; tc < 4; ++tc)
#pragma unroll
        for (int r = 0; r < 4; ++r) {
          int key = k0 + tc * 16 + h * 4 + r;
          float v = sc[tc][r] * 0.125f;
          if (key > q_abs) v = -1e30f;
          sc[tc][r] = v;
          pmax = fmaxf(pmax, v);
        }
      pmax = fmaxf(pmax, __shfl_xor(pmax, 16));
      pmax = fmaxf(pmax, __shfl_xor(pmax, 32));
      float mnew = fmaxf(mrun, pmax);
      float alpha = expf(mrun - mnew);
      mrun = mnew;
      float ssum = 0.f;
#pragma unroll
      for (int tc = 0; tc < 4; ++tc)
#pragma unroll
        for (int r = 0; r < 4; ++r) {
          float pv = expf(sc[tc][r] - mnew);
          sc[tc][r] = pv;
          ssum += pv;
        }
      ssum += __shfl_xor(ssum, 16);
      ssum += __shfl_xor(ssum, 32);
      lrun = lrun * alpha + ssum;
      // ---- write P^T to LDS: Pl[q][key] ----
#pragma unroll
      for (int tc = 0; tc < 4; ++tc)
#pragma unroll
        for (int r = 0; r < 4; ++r)
          Pl[w][r16][tc * 16 + h * 4 + r] = (bf16_t)sc[tc][r];
      // ---- rescale o: alpha for o-row q=h*4+r lives in lane h*4+r ----
      float ar[4];
#pragma unroll
      for (int r = 0; r < 4; ++r) ar[r] = __shfl(alpha, h * 4 + r);
#pragma unroll
      for (int cti = 0; cti < 4; ++cti)
#pragma unroll
        for (int r = 0; r < 4; ++r) o[cti][r] *= ar[r];
      // ---- PV ----
      bf16x8 pa0 = *(const bf16x8*)&Pl[w][r16][h * 8];
      bf16x8 pa1 = *(const bf16x8*)&Pl[w][r16][32 + h * 8];
      __builtin_amdgcn_s_setprio(1);
#pragma unroll
      for (int cti = 0; cti < 4; ++cti) {
        bf16x8 v0 = *(const bf16x8*)&Vt[cti * 16 + r16][h * 8];
        bf16x8 v1 = *(const bf16x8*)&Vt[cti * 16 + r16][32 + h * 8];
        o[cti] = __builtin_amdgcn_mfma_f32_16x16x32_bf16(pa0, v0, o[cti], 0, 0, 0);
        o[cti] = __builtin_amdgcn_mfma_f32_16x16x32_bf16(pa1, v1, o[cti], 0, 0, 0);
      }
      __builtin_amdgcn_s_setprio(0);
    }
    __syncthreads();
  }
  float lr[4];
#pragma unroll
  for (int r = 0; r < 4; ++r) lr[r] = __shfl(lrun, h * 4 + r);
#pragma unroll
  for (int cti = 0; cti < 4; ++cti)
#pragma unroll
    for (int r = 0; r < 4; ++r) {
      int row = q0 + h * 4 + r;
      ao[(size_t)row * DIM + hoff + cti * 16 + r16] = (bf16_t)(o[cti][r] / lr[r]);
    }
}

extern "C" void kernel_launch(void* const* d_in, const int* in_sizes, int n_in,
                              void* d_out, int out_size, void* d_ws, size_t ws_size,
                              hipStream_t stream) {
  const int*   ids  = (const int*)d_in[0];
  const float* temb = (const float*)d_in[1];
  const float* Wq   = (const float*)d_in[2];
  const float* Wk   = (const float*)d_in[3];
  const float* Wv   = (const float*)d_in[4];
  const float* Wo   = (const float*)d_in[5];
  const float* ln1s = (const float*)d_in[6];
  const float* ln1b = (const float*)d_in[7];
  const float* ln2s = (const float*)d_in[8];
  const float* ln2b = (const float*)d_in[9];
  const float* w1   = (const float*)d_in[10];
  const float* w2   = (const float*)d_in[11];
  const float* w3   = (const float*)d_in[12];
  const float* lnfs = (const float*)d_in[13];
  const float* lnfb = (const float*)d_in[14];
  const float* lmh  = (const float*)d_in[15];
  float* out = (float*)d_out;

  char* p = (char*)d_ws;
  size_t used = 0;
  auto alloc = [&](size_t bytes) {
    void* r = (void*)p;
    size_t a = (bytes + 255) & ~(size_t)255;
    p += a; used += a;
    return r;
  };
  // activations + tables
  float*  x     = (float*)alloc((size_t)SEQ * DIM * 4);
  bf16_t* hb    = (bf16_t*)alloc((size_t)SEQ * DIM * 2);
  bf16_t* qb2   = (bf16_t*)alloc((size_t)SEQ * DIM * 2);
  bf16_t* kb2   = (bf16_t*)alloc((size_t)SEQ * DIM * 2);
  bf16_t* vb2   = (bf16_t*)alloc((size_t)SEQ * DIM * 2);
  bf16_t* aob   = (bf16_t*)alloc((size_t)SEQ * DIM * 2);
  bf16_t* gateb = (bf16_t*)alloc((size_t)SEQ * FF * 2);
  float*  ctab  = (float*)alloc((size_t)SEQ * 32 * 4);
  float*  stab  = (float*)alloc((size_t)SEQ * 32 * 4);

  const size_t szDD = (size_t)DIM * DIM;    // 1M elems
  const size_t szDF = (size_t)DIM * FF;     // 4M elems
  const size_t wt_bytes = ((size_t)NL * (3 * szDD + szDD + 2 * szDF + szDF) + (size_t)VOCP * DIM) * 2;
  const bool bigws = (ws_size >= used + wt_bytes + (1u << 20));

  bf16_t *bQKV, *bWo, *bW13, *bw2, *blm, *wscratch = nullptr;
  if (bigws) {
    bQKV = (bf16_t*)alloc(NL * 3 * szDD * 2);
    bWo  = (bf16_t*)alloc(NL * szDD * 2);
    bW13 = (bf16_t*)alloc(NL * 2 * szDF * 2);
    bw2  = (bf16_t*)alloc(NL * szDF * 2);
    blm  = (bf16_t*)alloc((size_t)VOCP * DIM * 2);
  } else {
    wscratch = (bf16_t*)alloc(2 * szDF * 2);   // enough for fused w13 of one layer
    bQKV = bWo = bW13 = bw2 = blm = wscratch;
  }

  auto cvt = [&](const float* src, bf16_t* dst, int K_, int N_, int Npad_, int nz,
                 size_t dstride, int imode) {
    dim3 g(Npad_ / 64, K_ / 64, nz);
    k_cvt_t<<<g, 256, 0, stream>>>(src, dst, K_, N_, Npad_, dstride, imode);
  };

  if (bigws) {
    cvt(Wq, bQKV,             DIM, DIM, DIM, NL, 3 * szDD, 0);
    cvt(Wk, bQKV + szDD,      DIM, DIM, DIM, NL, 3 * szDD, 0);
    cvt(Wv, bQKV + 2 * szDD,  DIM, DIM, DIM, NL, 3 * szDD, 0);
    cvt(Wo, bWo,              DIM, DIM, DIM, NL, szDD, 0);
    cvt(w1, bW13,             DIM, FF,  FF,  NL, 2 * szDF, 1);   // interleaved even
    cvt(w3, bW13,             DIM, FF,  FF,  NL, 2 * szDF, 2);   // interleaved odd
    cvt(w2, bw2,              FF,  DIM, DIM, NL, szDF, 0);
    cvt(lmh, blm,             DIM, VOC, VOCP, 1, 0, 0);
  }
  auto wpQKV = [&](int lyr) -> bf16_t* {
    if (bigws) return bQKV + (size_t)lyr * 3 * szDD;
    cvt(Wq + (size_t)lyr * szDD, wscratch,            DIM, DIM, DIM, 1, 0, 0);
    cvt(Wk + (size_t)lyr * szDD, wscratch + szDD,     DIM, DIM, DIM, 1, 0, 0);
    cvt(Wv + (size_t)lyr * szDD, wscratch + 2 * szDD, DIM, DIM, DIM, 1, 0, 0);
    return wscratch;
  };
  auto wpW13 = [&](int lyr) -> bf16_t* {
    if (bigws) return bW13 + (size_t)lyr * 2 * szDF;
    cvt(w1 + (size_t)lyr * szDF, wscratch, DIM, FF, FF, 1, 0, 1);
    cvt(w3 + (size_t)lyr * szDF, wscratch, DIM, FF, FF, 1, 0, 2);
    return wscratch;
  };
  auto wp1 = [&](bf16_t* big, const float* src, int lyr, int K_, int N_, int Npad_) -> bf16_t* {
    if (bigws) return big + (size_t)lyr * Npad_ * K_;
    cvt(src + (size_t)lyr * K_ * N_, wscratch, K_, N_, Npad_, 1, 0, 0);
    return wscratch;
  };

  k_rtab<<<(SEQ * 32) / 256, 256, 0, stream>>>(ctab, stab);
  k_embed<<<SEQ, 256, 0, stream>>>(ids, temb, x);

  dim3 gQKV(3 * DIM / 128, SEQ / 128);   // 24 x 16 = 384
  dim3 gDD(DIM / 64, SEQ / 64);          // 16 x 32 = 512 (2/CU, 64x64 tiles)
  dim3 gW13(2 * FF / 256, SEQ / 256);    // 32 x 8 = 256 (1/CU, 256^2 dbuf kernel)
  dim3 gLM(VOCP / 64, SEQ / 64);         // 22 x 32 = 704
  dim3 gAt(32, NH);                      // 32 tiles x 16 heads = 512 (2/CU)

  for (int l = 0; l < NL; ++l) {
    k_ln<<<SEQ / 4, 256, 0, stream>>>(x, ln1s + (size_t)l * DIM, ln1b + (size_t)l * DIM, hb);
    k_gemm2<128, 128, 4><<<gQKV, 256, 0, stream>>>(hb, wpQKV(l), nullptr, vb2, qb2, kb2,
                                                   ctab, stab, SEQ, 3 * DIM, DIM);
    k_attn4<<<gAt, 256, 0, stream>>>(qb2, kb2, vb2, aob);
    k_gemm2<64, 64, 2><<<gDD, 256, 0, stream>>>(aob, wp1(bWo, Wo, l, DIM, DIM, DIM), x, nullptr,
                                                nullptr, nullptr, nullptr, nullptr, SEQ, DIM, DIM);
    k_ln<<<SEQ / 4, 256, 0, stream>>>(x, ln2s + (size_t)l * DIM, ln2b + (size_t)l * DIM, hb);
    k_gemm256_gate<<<gW13, 512, 0, stream>>>(hb, wpW13(l), gateb, DIM);
    k_gemm2<64, 64, 2><<<gDD, 256, 0, stream>>>(gateb, wp1(bw2, w2, l, FF, DIM, DIM), x, nullptr,
                                                nullptr, nullptr, nullptr, nullptr, SEQ, DIM, FF);
  }
  k_ln<<<SEQ / 4, 256, 0, stream>>>(x, lnfs, lnfb, hb);
  k_gemm2<64, 64, 0><<<gLM, 256, 0, stream>>>(hb, bigws ? blm : wp1(blm, lmh, 0, DIM, VOC, VOCP),
                                              out, nullptr, nullptr, nullptr, nullptr, nullptr,
                                              SEQ, VOC, DIM);
}

// Round 16
// 2892.216 us; speedup vs baseline: 1.1696x; 1.0246x over previous
//
#include <hip/hip_runtime.h>
#include <math.h>

// ---- problem constants ----
constexpr int SEQ = 2048;
constexpr int DIM = 1024;
constexpr int NH  = 16;
constexpr int HD  = 64;
constexpr int FF  = 4096;
constexpr int NL  = 12;
constexpr int VOC = 1400;
constexpr int VOCP = 1408;   // padded to 64

typedef __bf16 bf16_t;
typedef __bf16 bf16x8 __attribute__((ext_vector_type(8)));
typedef float  f32x4  __attribute__((ext_vector_type(4)));

typedef __attribute__((address_space(1))) const void GV;
typedef __attribute__((address_space(3))) void LV;

__device__ __forceinline__ void gll16(const bf16_t* g, bf16_t* l) {
  __builtin_amdgcn_global_load_lds((GV*)g, (LV*)l, 16, 0, 0);
}

// ---------------- embedding gather ----------------
__global__ __launch_bounds__(256) void k_embed(const int* __restrict__ ids,
                                               const float* __restrict__ emb,
                                               float* __restrict__ x) {
  int s = blockIdx.x;
  int d = threadIdx.x * 4;
  const float4 v = *(const float4*)&emb[(size_t)ids[s] * DIM + d];
  *(float4*)&x[(size_t)s * DIM + d] = v;
}

// ---------------- RoPE cos/sin table: [s][i], i = freq idx 0..31 ----------------
__global__ __launch_bounds__(256) void k_rtab(float* __restrict__ ct,
                                              float* __restrict__ st) {
  int id = blockIdx.x * 256 + threadIdx.x;   // SEQ*32
  int i = id & 31;
  int s = id >> 5;
  float ang = (float)s * powf(10000.f, -(float)i * (1.f / 32.f));
  float sn, cs;
  sincosf(ang, &sn, &cs);
  ct[id] = cs;
  st[id] = sn;
}

// ------- layernorm (f32 in -> bf16 out), 4 rows/block, 1 wave per row -------
__global__ __launch_bounds__(256) void k_ln(const float* __restrict__ x,
                                            const float* __restrict__ sc,
                                            const float* __restrict__ bi,
                                            bf16_t* __restrict__ out) {
  int s = blockIdx.x * 4 + (threadIdx.x >> 6);
  int l = threadIdx.x & 63;
  const float* xr = x + (size_t)s * DIM;
  float4 v[4];
  float sum = 0.f, sq = 0.f;
#pragma unroll
  for (int i = 0; i < 4; ++i) {
    v[i] = *(const float4*)&xr[i * 256 + l * 4];
#pragma unroll
    for (int j = 0; j < 4; ++j) { sum += v[i][j]; sq += v[i][j] * v[i][j]; }
  }
#pragma unroll
  for (int d = 1; d < 64; d <<= 1) {
    sum += __shfl_xor(sum, d);
    sq  += __shfl_xor(sq, d);
  }
  float mean = sum * (1.f / DIM);
  float var  = sq * (1.f / DIM) - mean * mean;
  float inv  = rsqrtf(var + 1e-5f);
#pragma unroll
  for (int i = 0; i < 4; ++i) {
    int off = i * 256 + l * 4;
    float4 scv = *(const float4*)&sc[off];
    float4 biv = *(const float4*)&bi[off];
#pragma unroll
    for (int j = 0; j < 4; ++j) {
      float o = (v[i][j] - mean) * inv * scv[j] + biv[j];
      out[(size_t)s * DIM + off + j] = (bf16_t)o;
    }
  }
}

// ------- weight convert + transpose: src[K][N] f32 -> dst[...][K] bf16 -------
// imode 0: dst row = n. imode 1: w1 f -> (f>>4)*32+(f&15). imode 2: w3 -> +16.
__global__ __launch_bounds__(256) void k_cvt_t(const float* __restrict__ src,
                                               bf16_t* __restrict__ dst,
                                               int K_, int N_, int Npad_,
                                               size_t dstride, int imode) {
  __shared__ bf16_t T[64][66];
  const int k0 = blockIdx.y * 64;
  const int n0 = blockIdx.x * 64;
  const size_t so = (size_t)blockIdx.z * K_ * N_;
  const size_t dof = (size_t)blockIdx.z * dstride;
  const int t = threadIdx.x;
  const int kk = t >> 4;
  const int nn = (t & 15) * 4;
#pragma unroll
  for (int it = 0; it < 4; ++it) {
    int krow = kk + it * 16;
    float4 v = {0.f, 0.f, 0.f, 0.f};
    if (n0 + nn < N_) v = *(const float4*)&src[so + (size_t)(k0 + krow) * N_ + n0 + nn];
#pragma unroll
    for (int q = 0; q < 4; ++q) T[nn + q][krow] = (bf16_t)v[q];
  }
  __syncthreads();
#pragma unroll
  for (int it = 0; it < 4; ++it) {
    int c = it * 256 + t;
    int nr = c >> 4;
    int kc = (c & 15) * 4;
    int f = n0 + nr;
    int drow = (imode == 0) ? f : ((f >> 4) * 32 + ((imode == 2) ? 16 : 0) + (f & 15));
    ushort4 o = *(const ushort4*)&T[nr][kc];
    *(ushort4*)&dst[dof + (size_t)drow * K_ + k0 + kc] = o;
  }
}

// ---------------- GEMM: C[M,N] = A[M,K] * Bt[N][K], bf16 MFMA ----------------
// tile TM x TN, BK=64, 4 waves (2x2; each wave TM/2 x TN/2). XOR-swizzled
// staging (round-9 verified; row offsets all multiples of 8 so rA&7 == r16&7).
// OUTMODE 0: f32 store | 2: f32 += | 4: fused QKV(+RoPE) | 6: interleaved silu-gate
template <int TM, int TN, int OUTMODE>
__global__ __launch_bounds__(256) void k_gemm2(const bf16_t* __restrict__ A,
                                               const bf16_t* __restrict__ Bt,
                                               float* __restrict__ Cf,
                                               bf16_t* __restrict__ Cb,
                                               bf16_t* __restrict__ aux1,
                                               bf16_t* __restrict__ aux2,
                                               const float* __restrict__ ct,
                                               const float* __restrict__ st,
                                               int M, int N, int K) {
  constexpr int MI = TM / 32;            // A frags per wave (and A stage issues)
  constexpr int JN = TN / 32;            // B frags per wave (and B stage issues)
  __shared__ bf16_t As[TM * 64];
  __shared__ bf16_t Bs[TN * 64];
  const int t = threadIdx.x;
  const int w = t >> 6, l = t & 63;
  const int h = l >> 4, r16 = l & 15;
  const int m0 = blockIdx.y * TM, n0 = blockIdx.x * TN;
  const int wr = (w >> 1) * (TM / 2);
  const int wc = (w & 1) * (TN / 2);
  const int sr8  = l >> 3;               // 0..7 row within wave-slab
  const int xch  = ((l & 7) ^ sr8) * 8;  // pre-swizzled k-chunk offset (elems)
  const int s7   = r16 & 7;              // reader swizzle key

  f32x4 acc[MI][JN] = {};

  const bf16_t* pa = &A[(size_t)(m0 + w * 8 + sr8) * K + xch];
  const bf16_t* pb = &Bt[(size_t)(n0 + w * 8 + sr8) * K + xch];

  for (int k0 = 0; k0 < K; k0 += 64) {
#pragma unroll
    for (int i = 0; i < MI; ++i)
      gll16(pa + (size_t)i * 32 * K + k0, &As[(i * 32 + w * 8) * 64]);
#pragma unroll
    for (int i = 0; i < JN; ++i)
      gll16(pb + (size_t)i * 32 * K + k0, &Bs[(i * 32 + w * 8) * 64]);
    __syncthreads();
#pragma unroll
    for (int kk = 0; kk < 2; ++kk) {
      const int p = ((kk * 4 + h) ^ s7) * 8;   // swizzled read position (elems)
      bf16x8 af[MI], bfr[JN];
#pragma unroll
      for (int i = 0; i < MI; ++i)
        af[i] = *(const bf16x8*)&As[(wr + i * 16 + r16) * 64 + p];
#pragma unroll
      for (int j = 0; j < JN; ++j)
        bfr[j] = *(const bf16x8*)&Bs[(wc + j * 16 + r16) * 64 + p];
#pragma unroll
      for (int i = 0; i < MI; ++i)
#pragma unroll
        for (int j = 0; j < JN; ++j)
          acc[i][j] = __builtin_amdgcn_mfma_f32_16x16x32_bf16(af[i], bfr[j], acc[i][j], 0, 0, 0);
    }
    __syncthreads();
  }

  if constexpr (OUTMODE == 4) {
    const int reg = n0 >> 10;
    const int cbase = (n0 & 1023) + wc;
    if (reg == 2) {
#pragma unroll
      for (int i = 0; i < MI; ++i)
#pragma unroll
        for (int j = 0; j < JN; ++j)
#pragma unroll
          for (int r = 0; r < 4; ++r) {
            int row = m0 + wr + i * 16 + h * 4 + r;
            Cb[(size_t)row * DIM + cbase + j * 16 + r16] = (bf16_t)acc[i][j][r];
          }
    } else {
      bf16_t* dst = reg ? aux2 : aux1;
#pragma unroll
      for (int i = 0; i < MI; ++i)
#pragma unroll
        for (int r = 0; r < 4; ++r) {
          int row = m0 + wr + i * 16 + h * 4 + r;
          float c0 = ct[row * 32 + r16],      s0 = st[row * 32 + r16];
          float c1 = ct[row * 32 + 16 + r16], s1 = st[row * 32 + 16 + r16];
          float lo0 = acc[i][0][r], hi0 = acc[i][2][r];
          float lo1 = acc[i][1][r], hi1 = acc[i][3][r];
          size_t rb = (size_t)row * DIM + cbase;
          dst[rb + r16]      = (bf16_t)(lo0 * c0 - hi0 * s0);
          dst[rb + 32 + r16] = (bf16_t)(hi0 * c0 + lo0 * s0);
          dst[rb + 16 + r16] = (bf16_t)(lo1 * c1 - hi1 * s1);
          dst[rb + 48 + r16] = (bf16_t)(hi1 * c1 + lo1 * s1);
        }
    }
  } else if constexpr (OUTMODE == 6) {
    const int fbase = ((n0 + wc) >> 5) * 16;
#pragma unroll
    for (int i = 0; i < MI; ++i)
#pragma unroll
      for (int r = 0; r < 4; ++r) {
        int row = m0 + wr + i * 16 + h * 4 + r;
        float a0 = acc[i][0][r], b0 = acc[i][1][r];
        float a1 = acc[i][2][r], b1 = acc[i][3][r];
        float g0 = a0 / (1.f + expf(-a0)) * b0;
        float g1v = a1 / (1.f + expf(-a1)) * b1;
        size_t rb = (size_t)row * FF + fbase;
        aux1[rb + r16]      = (bf16_t)g0;
        aux1[rb + 16 + r16] = (bf16_t)g1v;
      }
  } else {
#pragma unroll
    for (int i = 0; i < MI; ++i)
#pragma unroll
      for (int j = 0; j < JN; ++j)
#pragma unroll
        for (int r = 0; r < 4; ++r) {
          int row = m0 + wr + i * 16 + h * 4 + r;
          int col = n0 + wc + j * 16 + r16;
          if (col < N) {
            float vv = acc[i][j][r];
            size_t idx = (size_t)row * N + col;
            if (OUTMODE == 0) Cf[idx] = vv;
            else Cf[idx] += vv;
          }
        }
  }
}

// ------- w13 GEMM: 256x256 tile, BK=64, 8 waves (2M x 4N), double-buffered LDS ----
// (round-12 version — best measured). Interleaved w1/w3 silu-gate epilogue.
__global__ __launch_bounds__(512, 1) void k_gemm256_gate(const bf16_t* __restrict__ A,
                                                         const bf16_t* __restrict__ Bt,
                                                         bf16_t* __restrict__ gate,
                                                         int K) {
  __shared__ bf16_t As[2][256 * 64];
  __shared__ bf16_t Bs[2][256 * 64];
  const int t = threadIdx.x;
  const int w = t >> 6, l = t & 63;
  const int h = l >> 4, r16 = l & 15;
  const int m0 = blockIdx.y * 256, n0 = blockIdx.x * 256;
  const int wr = (w >> 2) * 128;       // wave M offset: 0 or 128
  const int wc = (w & 3) * 64;         // wave N offset: 0,64,128,192
  const int sr = t >> 3;               // staging row within 64-row slab (0..63)
  const int xch = ((t & 7) ^ (sr & 7)) * 8;   // pre-swizzled k-chunk (elems)
  const int s7 = r16 & 7;

  f32x4 acc[8][4] = {};

  const bf16_t* pa = &A[(size_t)(m0 + sr) * K + xch];
  const bf16_t* pb = &Bt[(size_t)(n0 + sr) * K + xch];
  const int NT = K >> 6;

  auto STAGE = [&](int kt, int b) {
    const int k0 = kt << 6;
    bf16_t* baseA = &As[b][(w * 8) * 64];   // wave-uniform LDS base (+lane*16B)
    bf16_t* baseB = &Bs[b][(w * 8) * 64];
#pragma unroll
    for (int i = 0; i < 4; ++i) {
      gll16(pa + (size_t)(i * 64) * K + k0, baseA + i * 64 * 64);
      gll16(pb + (size_t)(i * 64) * K + k0, baseB + i * 64 * 64);
    }
  };

  STAGE(0, 0);
  asm volatile("s_waitcnt vmcnt(0)" ::: "memory");
  __builtin_amdgcn_s_barrier();
  __builtin_amdgcn_sched_barrier(0);

  int cur = 0;
  for (int tt = 0; tt < NT; ++tt) {
    if (tt + 1 < NT) STAGE(tt + 1, cur ^ 1);   // overlap with compute below
#pragma unroll
    for (int kk = 0; kk < 2; ++kk) {
      const int p = ((kk * 4 + h) ^ s7) * 8;
      bf16x8 af[8], bfr[4];
#pragma unroll
      for (int i = 0; i < 8; ++i)
        af[i] = *(const bf16x8*)&As[cur][(wr + i * 16 + r16) * 64 + p];
#pragma unroll
      for (int j = 0; j < 4; ++j)
        bfr[j] = *(const bf16x8*)&Bs[cur][(wc + j * 16 + r16) * 64 + p];
#pragma unroll
      for (int i = 0; i < 8; ++i)
#pragma unroll
        for (int j = 0; j < 4; ++j)
          acc[i][j] = __builtin_amdgcn_mfma_f32_16x16x32_bf16(af[i], bfr[j], acc[i][j], 0, 0, 0);
    }
    asm volatile("s_waitcnt vmcnt(0)" ::: "memory");   // next tile landed
    __builtin_amdgcn_s_barrier();
    __builtin_amdgcn_sched_barrier(0);
    cur ^= 1;
  }

  // interleaved silu-gate epilogue: j even = w1, j odd = w3 (same features)
  const int fbase = ((n0 + wc) >> 5) * 16;
#pragma unroll
  for (int i = 0; i < 8; ++i)
#pragma unroll
    for (int r = 0; r < 4; ++r) {
      int row = m0 + wr + i * 16 + h * 4 + r;
      float a0 = acc[i][0][r], b0 = acc[i][1][r];
      float a1 = acc[i][2][r], b1 = acc[i][3][r];
      float g0 = a0 / (1.f + expf(-a0)) * b0;
      float g1v = a1 / (1.f + expf(-a1)) * b1;
      size_t rb = (size_t)row * FF + fbase;
      gate[rb + r16]      = (bf16_t)g0;
      gate[rb + 16 + r16] = (bf16_t)g1v;
    }
}

// ------- flash attention: 4 waves/block, swapped-QK, one 64-row tile/block -------
// 512 blocks (2/CU). Complementary pairing via grid map: qt = head<8 ? raw : 31-raw.
__global__ __launch_bounds__(256) void k_attn4(const bf16_t* __restrict__ qb,
                                               const bf16_t* __restrict__ kb,
                                               const bf16_t* __restrict__ vb,
                                               bf16_t* __restrict__ ao) {
  __shared__ bf16_t Ks[64][72];       // K chunk: [key][dh]
  __shared__ bf16_t Vt[64][72];       // V chunk transposed: [dh][key]
  __shared__ bf16_t Pl[4][16][72];    // per-wave P: [qrow][key]
  const int raw = blockIdx.x;         // 0..31
  const int head = blockIdx.y;        // 0..15
  const int qt = (head < 8) ? raw : (31 - raw);   // complementary per-CU pairing
  const int t = threadIdx.x;
  const int w = t >> 6, l = t & 63;
  const int h = l >> 4, r16 = l & 15;
  const size_t hoff = (size_t)head * HD;
  const int srow = t >> 2;            // 0..63 staging row
  const int ssg  = (t & 3) * 8;       // 0,8,16,24

  const int q0 = qt * 64 + w * 16;    // this wave's first q row
  const int q_abs = q0 + r16;         // this lane's q row (softmax axis)

  bf16x8 aq[2];
#pragma unroll
  for (int c = 0; c < 2; ++c)
    aq[c] = *(const bf16x8*)&qb[(size_t)(q0 + r16) * DIM + hoff + c * 32 + h * 8];

  f32x4 o[4] = {};
  float mrun = -1e30f, lrun = 0.f;

  const int kend = qt * 64 + 63;
  for (int k0 = 0; k0 <= kend; k0 += 64) {
    // ---- cooperative stage: K direct, V transposed ----
#pragma unroll
    for (int it = 0; it < 2; ++it) {
      bf16x8 kv = *(const bf16x8*)&kb[(size_t)(k0 + srow) * DIM + hoff + ssg + it * 32];
      *(bf16x8*)&Ks[srow][ssg + it * 32] = kv;
    }
#pragma unroll
    for (int it = 0; it < 2; ++it) {
      bf16x8 vv = *(const bf16x8*)&vb[(size_t)(k0 + srow) * DIM + hoff + ssg + it * 32];
#pragma unroll
      for (int j = 0; j < 8; ++j) Vt[ssg + it * 32 + j][srow] = vv[j];
    }
    __syncthreads();

    if (k0 <= q0 + 15) {              // wave-uniform: skip fully-masked chunks
      // ---- scores transposed: D[key][q] ----
      f32x4 sc[4];
      __builtin_amdgcn_s_setprio(1);
#pragma unroll
      for (int tc = 0; tc < 4; ++tc) {
        f32x4 z = {};
        bf16x8 a0 = *(const bf16x8*)&Ks[tc * 16 + r16][h * 8];
        bf16x8 a1 = *(const bf16x8*)&Ks[tc * 16 + r16][32 + h * 8];
        z = __builtin_amdgcn_mfma_f32_16x16x32_bf16(a0, aq[0], z, 0, 0, 0);
        z = __builtin_amdgcn_mfma_f32_16x16x32_bf16(a1, aq[1], z, 0, 0, 0);
        sc[tc] = z;
      }
      __builtin_amdgcn_s_setprio(0);
      // ---- mask + scale; per-lane max over 16 keys ----
      float pmax = -1e30f;
#pragma unroll
      for (int tc = 0; tc < 4; ++tc)
#pragma unroll
        for (int r = 0; r < 4; ++r) {
          int key = k0 + tc * 16 + h * 4 + r;
          float v = sc[tc][r] * 0.125f;
          if (key > q_abs) v = -1e30f;
          sc[tc][r] = v;
          pmax = fmaxf(pmax, v);
        }
      pmax = fmaxf(pmax, __shfl_xor(pmax, 16));
      pmax = fmaxf(pmax, __shfl_xor(pmax, 32));
      float mnew = fmaxf(mrun, pmax);
      float alpha = expf(mrun - mnew);
      mrun = mnew;
      float ssum = 0.f;
#pragma unroll
      for (int tc = 0; tc < 4; ++tc)
#pragma unroll
        for (int r = 0; r < 4; ++r) {
          float pv = expf(sc[tc][r] - mnew);
          sc[tc][r] = pv;
          ssum += pv;
        }
      ssum += __shfl_xor(ssum, 16);
      ssum += __shfl_xor(ssum, 32);
      lrun = lrun * alpha + ssum;
      // ---- write P^T to LDS: Pl[q][key] ----
#pragma unroll
      for (int tc = 0; tc < 4; ++tc)
#pragma unroll
        for (int r = 0; r < 4; ++r)
          Pl[w][r16][tc * 16 + h * 4 + r] = (bf16_t)sc[tc][r];
      // ---- rescale o: alpha for o-row q=h*4+r lives in lane h*4+r ----
      float ar[4];
#pragma unroll
      for (int r = 0; r < 4; ++r) ar[r] = __shfl(alpha, h * 4 + r);
#pragma unroll
      for (int cti = 0; cti < 4; ++cti)
#pragma unroll
        for (int r = 0; r < 4; ++r) o[cti][r] *= ar[r];
      // ---- PV ----
      bf16x8 pa0 = *(const bf16x8*)&Pl[w][r16][h * 8];
      bf16x8 pa1 = *(const bf16x8*)&Pl[w][r16][32 + h * 8];
      __builtin_amdgcn_s_setprio(1);
#pragma unroll
      for (int cti = 0; cti < 4; ++cti) {
        bf16x8 v0 = *(const bf16x8*)&Vt[cti * 16 + r16][h * 8];
        bf16x8 v1 = *(const bf16x8*)&Vt[cti * 16 + r16][32 + h * 8];
        o[cti] = __builtin_amdgcn_mfma_f32_16x16x32_bf16(pa0, v0, o[cti], 0, 0, 0);
        o[cti] = __builtin_amdgcn_mfma_f32_16x16x32_bf16(pa1, v1, o[cti], 0, 0, 0);
      }
      __builtin_amdgcn_s_setprio(0);
    }
    __syncthreads();
  }
  float lr[4];
#pragma unroll
  for (int r = 0; r < 4; ++r) lr[r] = __shfl(lrun, h * 4 + r);
#pragma unroll
  for (int cti = 0; cti < 4; ++cti)
#pragma unroll
    for (int r = 0; r < 4; ++r) {
      int row = q0 + h * 4 + r;
      ao[(size_t)row * DIM + hoff + cti * 16 + r16] = (bf16_t)(o[cti][r] / lr[r]);
    }
}

extern "C" void kernel_launch(void* const* d_in, const int* in_sizes, int n_in,
                              void* d_out, int out_size, void* d_ws, size_t ws_size,
                              hipStream_t stream) {
  const int*   ids  = (const int*)d_in[0];
  const float* temb = (const float*)d_in[1];
  const float* Wq   = (const float*)d_in[2];
  const float* Wk   = (const float*)d_in[3];
  const float* Wv   = (const float*)d_in[4];
  const float* Wo   = (const float*)d_in[5];
  const float* ln1s = (const float*)d_in[6];
  const float* ln1b = (const float*)d_in[7];
  const float* ln2s = (const float*)d_in[8];
  const float* ln2b = (const float*)d_in[9];
  const float* w1   = (const float*)d_in[10];
  const float* w2   = (const float*)d_in[11];
  const float* w3   = (const float*)d_in[12];
  const float* lnfs = (const float*)d_in[13];
  const float* lnfb = (const float*)d_in[14];
  const float* lmh  = (const float*)d_in[15];
  float* out = (float*)d_out;

  char* p = (char*)d_ws;
  size_t used = 0;
  auto alloc = [&](size_t bytes) {
    void* r = (void*)p;
    size_t a = (bytes + 255) & ~(size_t)255;
    p += a; used += a;
    return r;
  };
  // activations + tables
  float*  x     = (float*)alloc((size_t)SEQ * DIM * 4);
  bf16_t* hb    = (bf16_t*)alloc((size_t)SEQ * DIM * 2);
  bf16_t* qb2   = (bf16_t*)alloc((size_t)SEQ * DIM * 2);
  bf16_t* kb2   = (bf16_t*)alloc((size_t)SEQ * DIM * 2);
  bf16_t* vb2   = (bf16_t*)alloc((size_t)SEQ * DIM * 2);
  bf16_t* aob   = (bf16_t*)alloc((size_t)SEQ * DIM * 2);
  bf16_t* gateb = (bf16_t*)alloc((size_t)SEQ * FF * 2);
  float*  ctab  = (float*)alloc((size_t)SEQ * 32 * 4);
  float*  stab  = (float*)alloc((size_t)SEQ * 32 * 4);

  const size_t szDD = (size_t)DIM * DIM;    // 1M elems
  const size_t szDF = (size_t)DIM * FF;     // 4M elems
  const size_t wt_bytes = ((size_t)NL * (3 * szDD + szDD + 2 * szDF + szDF) + (size_t)VOCP * DIM) * 2;
  const bool bigws = (ws_size >= used + wt_bytes + (1u << 20));

  bf16_t *bQKV, *bWo, *bW13, *bw2, *blm, *wscratch = nullptr;
  if (bigws) {
    bQKV = (bf16_t*)alloc(NL * 3 * szDD * 2);
    bWo  = (bf16_t*)alloc(NL * szDD * 2);
    bW13 = (bf16_t*)alloc(NL * 2 * szDF * 2);
    bw2  = (bf16_t*)alloc(NL * szDF * 2);
    blm  = (bf16_t*)alloc((size_t)VOCP * DIM * 2);
  } else {
    wscratch = (bf16_t*)alloc(2 * szDF * 2);   // enough for fused w13 of one layer
    bQKV = bWo = bW13 = bw2 = blm = wscratch;
  }

  auto cvt = [&](const float* src, bf16_t* dst, int K_, int N_, int Npad_, int nz,
                 size_t dstride, int imode) {
    dim3 g(Npad_ / 64, K_ / 64, nz);
    k_cvt_t<<<g, 256, 0, stream>>>(src, dst, K_, N_, Npad_, dstride, imode);
  };

  if (bigws) {
    cvt(Wq, bQKV,             DIM, DIM, DIM, NL, 3 * szDD, 0);
    cvt(Wk, bQKV + szDD,      DIM, DIM, DIM, NL, 3 * szDD, 0);
    cvt(Wv, bQKV + 2 * szDD,  DIM, DIM, DIM, NL, 3 * szDD, 0);
    cvt(Wo, bWo,              DIM, DIM, DIM, NL, szDD, 0);
    cvt(w1, bW13,             DIM, FF,  FF,  NL, 2 * szDF, 1);   // interleaved even
    cvt(w3, bW13,             DIM, FF,  FF,  NL, 2 * szDF, 2);   // interleaved odd
    cvt(w2, bw2,              FF,  DIM, DIM, NL, szDF, 0);
    cvt(lmh, blm,             DIM, VOC, VOCP, 1, 0, 0);
  }
  auto wpQKV = [&](int lyr) -> bf16_t* {
    if (bigws) return bQKV + (size_t)lyr * 3 * szDD;
    cvt(Wq + (size_t)lyr * szDD, wscratch,            DIM, DIM, DIM, 1, 0, 0);
    cvt(Wk + (size_t)lyr * szDD, wscratch + szDD,     DIM, DIM, DIM, 1, 0, 0);
    cvt(Wv + (size_t)lyr * szDD, wscratch + 2 * szDD, DIM, DIM, DIM, 1, 0, 0);
    return wscratch;
  };
  auto wpW13 = [&](int lyr) -> bf16_t* {
    if (bigws) return bW13 + (size_t)lyr * 2 * szDF;
    cvt(w1 + (size_t)lyr * szDF, wscratch, DIM, FF, FF, 1, 0, 1);
    cvt(w3 + (size_t)lyr * szDF, wscratch, DIM, FF, FF, 1, 0, 2);
    return wscratch;
  };
  auto wp1 = [&](bf16_t* big, const float* src, int lyr, int K_, int N_, int Npad_) -> bf16_t* {
    if (bigws) return big + (size_t)lyr * Npad_ * K_;
    cvt(src + (size_t)lyr * K_ * N_, wscratch, K_, N_, Npad_, 1, 0, 0);
    return wscratch;
  };

  k_rtab<<<(SEQ * 32) / 256, 256, 0, stream>>>(ctab, stab);
  k_embed<<<SEQ, 256, 0, stream>>>(ids, temb, x);

  dim3 gQKV(3 * DIM / 128, SEQ / 64);    // 24 x 32 = 768 (3/CU, 64x128 tiles)
  dim3 gDD(DIM / 64, SEQ / 64);          // 16 x 32 = 512 (2/CU, 64x64 tiles)
  dim3 gW13(2 * FF / 256, SEQ / 256);    // 32 x 8 = 256 (1/CU, 256^2 dbuf kernel)
  dim3 gLM(VOCP / 64, SEQ / 64);         // 22 x 32 = 704
  dim3 gAt(32, NH);                      // 32 tiles x 16 heads = 512 (2/CU)

  for (int l = 0; l < NL; ++l) {
    k_ln<<<SEQ / 4, 256, 0, stream>>>(x, ln1s + (size_t)l * DIM, ln1b + (size_t)l * DIM, hb);
    k_gemm2<64, 128, 4><<<gQKV, 256, 0, stream>>>(hb, wpQKV(l), nullptr, vb2, qb2, kb2,
                                                  ctab, stab, SEQ, 3 * DIM, DIM);
    k_attn4<<<gAt, 256, 0, stream>>>(qb2, kb2, vb2, aob);
    k_gemm2<64, 64, 2><<<gDD, 256, 0, stream>>>(aob, wp1(bWo, Wo, l, DIM, DIM, DIM), x, nullptr,
                                                nullptr, nullptr, nullptr, nullptr, SEQ, DIM, DIM);
    k_ln<<<SEQ / 4, 256, 0, stream>>>(x, ln2s + (size_t)l * DIM, ln2b + (size_t)l * DIM, hb);
    k_gemm256_gate<<<gW13, 512, 0, stream>>>(hb, wpW13(l), gateb, DIM);
    k_gemm2<64, 64, 2><<<gDD, 256, 0, stream>>>(gateb, wp1(bw2, w2, l, FF, DIM, DIM), x, nullptr,
                                                nullptr, nullptr, nullptr, nullptr, SEQ, DIM, FF);
  }
  k_ln<<<SEQ / 4, 256, 0, stream>>>(x, lnfs, lnfb, hb);
  k_gemm2<64, 64, 0><<<gLM, 256, 0, stream>>>(hb, bigws ? blm : wp1(blm, lmh, 0, DIM, VOC, VOCP),
                                              out, nullptr, nullptr, nullptr, nullptr, nullptr,
                                              SEQ, VOC, DIM);
}

// Round 17
// 2824.889 us; speedup vs baseline: 1.1975x; 1.0238x over previous
//
#include <hip/hip_runtime.h>
#include <math.h>

// ---- problem constants ----
constexpr int SEQ = 2048;
constexpr int DIM = 1024;
constexpr int NH  = 16;
constexpr int HD  = 64;
constexpr int FF  = 4096;
constexpr int NL  = 12;
constexpr int VOC = 1400;
constexpr int VOCP = 1408;   // padded to 64

typedef __bf16 bf16_t;
typedef __bf16 bf16x8 __attribute__((ext_vector_type(8)));
typedef float  f32x4  __attribute__((ext_vector_type(4)));

typedef __attribute__((address_space(1))) const void GV;
typedef __attribute__((address_space(3))) void LV;

__device__ __forceinline__ void gll16(const bf16_t* g, bf16_t* l) {
  __builtin_amdgcn_global_load_lds((GV*)g, (LV*)l, 16, 0, 0);
}

// ---------------- embedding gather ----------------
__global__ __launch_bounds__(256) void k_embed(const int* __restrict__ ids,
                                               const float* __restrict__ emb,
                                               float* __restrict__ x) {
  int s = blockIdx.x;
  int d = threadIdx.x * 4;
  const float4 v = *(const float4*)&emb[(size_t)ids[s] * DIM + d];
  *(float4*)&x[(size_t)s * DIM + d] = v;
}

// ---------------- RoPE cos/sin table: [s][i], i = freq idx 0..31 ----------------
__global__ __launch_bounds__(256) void k_rtab(float* __restrict__ ct,
                                              float* __restrict__ st) {
  int id = blockIdx.x * 256 + threadIdx.x;   // SEQ*32
  int i = id & 31;
  int s = id >> 5;
  float ang = (float)s * powf(10000.f, -(float)i * (1.f / 32.f));
  float sn, cs;
  sincosf(ang, &sn, &cs);
  ct[id] = cs;
  st[id] = sn;
}

// ------- layernorm (f32 in -> bf16 out), 4 rows/block, 1 wave per row -------
__global__ __launch_bounds__(256) void k_ln(const float* __restrict__ x,
                                            const float* __restrict__ sc,
                                            const float* __restrict__ bi,
                                            bf16_t* __restrict__ out) {
  int s = blockIdx.x * 4 + (threadIdx.x >> 6);
  int l = threadIdx.x & 63;
  const float* xr = x + (size_t)s * DIM;
  float4 v[4];
  float sum = 0.f, sq = 0.f;
#pragma unroll
  for (int i = 0; i < 4; ++i) {
    v[i] = *(const float4*)&xr[i * 256 + l * 4];
#pragma unroll
    for (int j = 0; j < 4; ++j) { sum += v[i][j]; sq += v[i][j] * v[i][j]; }
  }
#pragma unroll
  for (int d = 1; d < 64; d <<= 1) {
    sum += __shfl_xor(sum, d);
    sq  += __shfl_xor(sq, d);
  }
  float mean = sum * (1.f / DIM);
  float var  = sq * (1.f / DIM) - mean * mean;
  float inv  = rsqrtf(var + 1e-5f);
#pragma unroll
  for (int i = 0; i < 4; ++i) {
    int off = i * 256 + l * 4;
    float4 scv = *(const float4*)&sc[off];
    float4 biv = *(const float4*)&bi[off];
#pragma unroll
    for (int j = 0; j < 4; ++j) {
      float o = (v[i][j] - mean) * inv * scv[j] + biv[j];
      out[(size_t)s * DIM + off + j] = (bf16_t)o;
    }
  }
}

// ------- weight convert + transpose: src[K][N] f32 -> dst[...][K] bf16 -------
// imode 0: dst row = n. imode 1: w1 f -> (f>>4)*32+(f&15). imode 2: w3 -> +16.
__global__ __launch_bounds__(256) void k_cvt_t(const float* __restrict__ src,
                                               bf16_t* __restrict__ dst,
                                               int K_, int N_, int Npad_,
                                               size_t dstride, int imode) {
  __shared__ bf16_t T[64][66];
  const int k0 = blockIdx.y * 64;
  const int n0 = blockIdx.x * 64;
  const size_t so = (size_t)blockIdx.z * K_ * N_;
  const size_t dof = (size_t)blockIdx.z * dstride;
  const int t = threadIdx.x;
  const int kk = t >> 4;
  const int nn = (t & 15) * 4;
#pragma unroll
  for (int it = 0; it < 4; ++it) {
    int krow = kk + it * 16;
    float4 v = {0.f, 0.f, 0.f, 0.f};
    if (n0 + nn < N_) v = *(const float4*)&src[so + (size_t)(k0 + krow) * N_ + n0 + nn];
#pragma unroll
    for (int q = 0; q < 4; ++q) T[nn + q][krow] = (bf16_t)v[q];
  }
  __syncthreads();
#pragma unroll
  for (int it = 0; it < 4; ++it) {
    int c = it * 256 + t;
    int nr = c >> 4;
    int kc = (c & 15) * 4;
    int f = n0 + nr;
    int drow = (imode == 0) ? f : ((f >> 4) * 32 + ((imode == 2) ? 16 : 0) + (f & 15));
    ushort4 o = *(const ushort4*)&T[nr][kc];
    *(ushort4*)&dst[dof + (size_t)drow * K_ + k0 + kc] = o;
  }
}

// ---------------- GEMM: C[M,N] = A[M,K] * Bt[N][K], bf16 MFMA ----------------
// tile TM x TN, BK=64, 4 waves (2x2; each wave TM/2 x TN/2). XOR-swizzled
// staging (round-9 verified; row offsets all multiples of 8 so rA&7 == r16&7).
// OUTMODE 0: f32 store | 2: f32 += | 4: fused QKV(+RoPE) | 6: interleaved silu-gate
template <int TM, int TN, int OUTMODE>
__global__ __launch_bounds__(256) void k_gemm2(const bf16_t* __restrict__ A,
                                               const bf16_t* __restrict__ Bt,
                                               float* __restrict__ Cf,
                                               bf16_t* __restrict__ Cb,
                                               bf16_t* __restrict__ aux1,
                                               bf16_t* __restrict__ aux2,
                                               const float* __restrict__ ct,
                                               const float* __restrict__ st,
                                               int M, int N, int K) {
  constexpr int MI = TM / 32;            // A frags per wave (and A stage issues)
  constexpr int JN = TN / 32;            // B frags per wave (and B stage issues)
  __shared__ bf16_t As[TM * 64];
  __shared__ bf16_t Bs[TN * 64];
  const int t = threadIdx.x;
  const int w = t >> 6, l = t & 63;
  const int h = l >> 4, r16 = l & 15;
  const int m0 = blockIdx.y * TM, n0 = blockIdx.x * TN;
  const int wr = (w >> 1) * (TM / 2);
  const int wc = (w & 1) * (TN / 2);
  const int sr8  = l >> 3;               // 0..7 row within wave-slab
  const int xch  = ((l & 7) ^ sr8) * 8;  // pre-swizzled k-chunk offset (elems)
  const int s7   = r16 & 7;              // reader swizzle key

  f32x4 acc[MI][JN] = {};

  const bf16_t* pa = &A[(size_t)(m0 + w * 8 + sr8) * K + xch];
  const bf16_t* pb = &Bt[(size_t)(n0 + w * 8 + sr8) * K + xch];

  for (int k0 = 0; k0 < K; k0 += 64) {
#pragma unroll
    for (int i = 0; i < MI; ++i)
      gll16(pa + (size_t)i * 32 * K + k0, &As[(i * 32 + w * 8) * 64]);
#pragma unroll
    for (int i = 0; i < JN; ++i)
      gll16(pb + (size_t)i * 32 * K + k0, &Bs[(i * 32 + w * 8) * 64]);
    __syncthreads();
#pragma unroll
    for (int kk = 0; kk < 2; ++kk) {
      const int p = ((kk * 4 + h) ^ s7) * 8;   // swizzled read position (elems)
      bf16x8 af[MI], bfr[JN];
#pragma unroll
      for (int i = 0; i < MI; ++i)
        af[i] = *(const bf16x8*)&As[(wr + i * 16 + r16) * 64 + p];
#pragma unroll
      for (int j = 0; j < JN; ++j)
        bfr[j] = *(const bf16x8*)&Bs[(wc + j * 16 + r16) * 64 + p];
#pragma unroll
      for (int i = 0; i < MI; ++i)
#pragma unroll
        for (int j = 0; j < JN; ++j)
          acc[i][j] = __builtin_amdgcn_mfma_f32_16x16x32_bf16(af[i], bfr[j], acc[i][j], 0, 0, 0);
    }
    __syncthreads();
  }

  if constexpr (OUTMODE == 4) {
    const int reg = n0 >> 10;
    const int cbase = (n0 & 1023) + wc;
    if (reg == 2) {
#pragma unroll
      for (int i = 0; i < MI; ++i)
#pragma unroll
        for (int j = 0; j < JN; ++j)
#pragma unroll
          for (int r = 0; r < 4; ++r) {
            int row = m0 + wr + i * 16 + h * 4 + r;
            Cb[(size_t)row * DIM + cbase + j * 16 + r16] = (bf16_t)acc[i][j][r];
          }
    } else {
      bf16_t* dst = reg ? aux2 : aux1;
#pragma unroll
      for (int i = 0; i < MI; ++i)
#pragma unroll
        for (int r = 0; r < 4; ++r) {
          int row = m0 + wr + i * 16 + h * 4 + r;
          float c0 = ct[row * 32 + r16],      s0 = st[row * 32 + r16];
          float c1 = ct[row * 32 + 16 + r16], s1 = st[row * 32 + 16 + r16];
          float lo0 = acc[i][0][r], hi0 = acc[i][2][r];
          float lo1 = acc[i][1][r], hi1 = acc[i][3][r];
          size_t rb = (size_t)row * DIM + cbase;
          dst[rb + r16]      = (bf16_t)(lo0 * c0 - hi0 * s0);
          dst[rb + 32 + r16] = (bf16_t)(hi0 * c0 + lo0 * s0);
          dst[rb + 16 + r16] = (bf16_t)(lo1 * c1 - hi1 * s1);
          dst[rb + 48 + r16] = (bf16_t)(hi1 * c1 + lo1 * s1);
        }
    }
  } else if constexpr (OUTMODE == 6) {
    const int fbase = ((n0 + wc) >> 5) * 16;
#pragma unroll
    for (int i = 0; i < MI; ++i)
#pragma unroll
      for (int r = 0; r < 4; ++r) {
        int row = m0 + wr + i * 16 + h * 4 + r;
        float a0 = acc[i][0][r], b0 = acc[i][1][r];
        float a1 = acc[i][2][r], b1 = acc[i][3][r];
        float g0 = a0 / (1.f + expf(-a0)) * b0;
        float g1v = a1 / (1.f + expf(-a1)) * b1;
        size_t rb = (size_t)row * FF + fbase;
        aux1[rb + r16]      = (bf16_t)g0;
        aux1[rb + 16 + r16] = (bf16_t)g1v;
      }
  } else {
#pragma unroll
    for (int i = 0; i < MI; ++i)
#pragma unroll
      for (int j = 0; j < JN; ++j)
#pragma unroll
        for (int r = 0; r < 4; ++r) {
          int row = m0 + wr + i * 16 + h * 4 + r;
          int col = n0 + wc + j * 16 + r16;
          if (col < N) {
            float vv = acc[i][j][r];
            size_t idx = (size_t)row * N + col;
            if (OUTMODE == 0) Cf[idx] = vv;
            else Cf[idx] += vv;
          }
        }
  }
}

// ------- w13 GEMM: 256x256 tile, BK=64, 8 waves (2M x 4N), double-buffered LDS ----
// (round-12 version — best measured). Interleaved w1/w3 silu-gate epilogue.
__global__ __launch_bounds__(512, 1) void k_gemm256_gate(const bf16_t* __restrict__ A,
                                                         const bf16_t* __restrict__ Bt,
                                                         bf16_t* __restrict__ gate,
                                                         int K) {
  __shared__ bf16_t As[2][256 * 64];
  __shared__ bf16_t Bs[2][256 * 64];
  const int t = threadIdx.x;
  const int w = t >> 6, l = t & 63;
  const int h = l >> 4, r16 = l & 15;
  const int m0 = blockIdx.y * 256, n0 = blockIdx.x * 256;
  const int wr = (w >> 2) * 128;       // wave M offset: 0 or 128
  const int wc = (w & 3) * 64;         // wave N offset: 0,64,128,192
  const int sr = t >> 3;               // staging row within 64-row slab (0..63)
  const int xch = ((t & 7) ^ (sr & 7)) * 8;   // pre-swizzled k-chunk (elems)
  const int s7 = r16 & 7;

  f32x4 acc[8][4] = {};

  const bf16_t* pa = &A[(size_t)(m0 + sr) * K + xch];
  const bf16_t* pb = &Bt[(size_t)(n0 + sr) * K + xch];
  const int NT = K >> 6;

  auto STAGE = [&](int kt, int b) {
    const int k0 = kt << 6;
    bf16_t* baseA = &As[b][(w * 8) * 64];   // wave-uniform LDS base (+lane*16B)
    bf16_t* baseB = &Bs[b][(w * 8) * 64];
#pragma unroll
    for (int i = 0; i < 4; ++i) {
      gll16(pa + (size_t)(i * 64) * K + k0, baseA + i * 64 * 64);
      gll16(pb + (size_t)(i * 64) * K + k0, baseB + i * 64 * 64);
    }
  };

  STAGE(0, 0);
  asm volatile("s_waitcnt vmcnt(0)" ::: "memory");
  __builtin_amdgcn_s_barrier();
  __builtin_amdgcn_sched_barrier(0);

  int cur = 0;
  for (int tt = 0; tt < NT; ++tt) {
    if (tt + 1 < NT) STAGE(tt + 1, cur ^ 1);   // overlap with compute below
#pragma unroll
    for (int kk = 0; kk < 2; ++kk) {
      const int p = ((kk * 4 + h) ^ s7) * 8;
      bf16x8 af[8], bfr[4];
#pragma unroll
      for (int i = 0; i < 8; ++i)
        af[i] = *(const bf16x8*)&As[cur][(wr + i * 16 + r16) * 64 + p];
#pragma unroll
      for (int j = 0; j < 4; ++j)
        bfr[j] = *(const bf16x8*)&Bs[cur][(wc + j * 16 + r16) * 64 + p];
#pragma unroll
      for (int i = 0; i < 8; ++i)
#pragma unroll
        for (int j = 0; j < 4; ++j)
          acc[i][j] = __builtin_amdgcn_mfma_f32_16x16x32_bf16(af[i], bfr[j], acc[i][j], 0, 0, 0);
    }
    asm volatile("s_waitcnt vmcnt(0)" ::: "memory");   // next tile landed
    __builtin_amdgcn_s_barrier();
    __builtin_amdgcn_sched_barrier(0);
    cur ^= 1;
  }

  // interleaved silu-gate epilogue: j even = w1, j odd = w3 (same features)
  const int fbase = ((n0 + wc) >> 5) * 16;
#pragma unroll
  for (int i = 0; i < 8; ++i)
#pragma unroll
    for (int r = 0; r < 4; ++r) {
      int row = m0 + wr + i * 16 + h * 4 + r;
      float a0 = acc[i][0][r], b0 = acc[i][1][r];
      float a1 = acc[i][2][r], b1 = acc[i][3][r];
      float g0 = a0 / (1.f + expf(-a0)) * b0;
      float g1v = a1 / (1.f + expf(-a1)) * b1;
      size_t rb = (size_t)row * FF + fbase;
      gate[rb + r16]      = (bf16_t)g0;
      gate[rb + 16 + r16] = (bf16_t)g1v;
    }
}

// ------- flash attention: 4 waves/block, swapped-QK, one 64-row tile/block -------
// 512 blocks (2/CU). Complementary pairing via grid map: qt = head<8 ? raw : 31-raw.
// T14 async-STAGE split: chunk t+1's global loads issue into regs BEFORE chunk t's
// compute (latency hides under MFMA/softmax); regs written to LDS after the barrier.
__global__ __launch_bounds__(256) void k_attn4(const bf16_t* __restrict__ qb,
                                               const bf16_t* __restrict__ kb,
                                               const bf16_t* __restrict__ vb,
                                               bf16_t* __restrict__ ao) {
  __shared__ bf16_t Ks[64][72];       // K chunk: [key][dh]
  __shared__ bf16_t Vt[64][72];       // V chunk transposed: [dh][key]
  __shared__ bf16_t Pl[4][16][72];    // per-wave P: [qrow][key]
  const int raw = blockIdx.x;         // 0..31
  const int head = blockIdx.y;        // 0..15
  const int qt = (head < 8) ? raw : (31 - raw);   // complementary per-CU pairing
  const int t = threadIdx.x;
  const int w = t >> 6, l = t & 63;
  const int h = l >> 4, r16 = l & 15;
  const size_t hoff = (size_t)head * HD;
  const int srow = t >> 2;            // 0..63 staging row
  const int ssg  = (t & 3) * 8;       // 0,8,16,24

  const int q0 = qt * 64 + w * 16;    // this wave's first q row
  const int q_abs = q0 + r16;         // this lane's q row (softmax axis)

  bf16x8 aq[2];
#pragma unroll
  for (int c = 0; c < 2; ++c)
    aq[c] = *(const bf16x8*)&qb[(size_t)(q0 + r16) * DIM + hoff + c * 32 + h * 8];

  f32x4 o[4] = {};
  float mrun = -1e30f, lrun = 0.f;

  const int kend = qt * 64 + 63;

  // ---- preload chunk 0 into regs ----
  bf16x8 kreg[2], vreg[2];
#pragma unroll
  for (int it = 0; it < 2; ++it) {
    kreg[it] = *(const bf16x8*)&kb[(size_t)srow * DIM + hoff + ssg + it * 32];
    vreg[it] = *(const bf16x8*)&vb[(size_t)srow * DIM + hoff + ssg + it * 32];
  }

  for (int k0 = 0; k0 <= kend; k0 += 64) {
    // ---- write staged regs to LDS: K direct, V transposed ----
#pragma unroll
    for (int it = 0; it < 2; ++it)
      *(bf16x8*)&Ks[srow][ssg + it * 32] = kreg[it];
#pragma unroll
    for (int it = 0; it < 2; ++it)
#pragma unroll
      for (int j = 0; j < 8; ++j) Vt[ssg + it * 32 + j][srow] = vreg[it][j];
    __syncthreads();

    // ---- issue next chunk's global loads (overlap with compute below) ----
    if (k0 + 64 <= kend) {
      const size_t nb = (size_t)(k0 + 64 + srow) * DIM + hoff + ssg;
#pragma unroll
      for (int it = 0; it < 2; ++it) {
        kreg[it] = *(const bf16x8*)&kb[nb + it * 32];
        vreg[it] = *(const bf16x8*)&vb[nb + it * 32];
      }
    }

    if (k0 <= q0 + 15) {              // wave-uniform: skip fully-masked chunks
      // ---- scores transposed: D[key][q] ----
      f32x4 sc[4];
      __builtin_amdgcn_s_setprio(1);
#pragma unroll
      for (int tc = 0; tc < 4; ++tc) {
        f32x4 z = {};
        bf16x8 a0 = *(const bf16x8*)&Ks[tc * 16 + r16][h * 8];
        bf16x8 a1 = *(const bf16x8*)&Ks[tc * 16 + r16][32 + h * 8];
        z = __builtin_amdgcn_mfma_f32_16x16x32_bf16(a0, aq[0], z, 0, 0, 0);
        z = __builtin_amdgcn_mfma_f32_16x16x32_bf16(a1, aq[1], z, 0, 0, 0);
        sc[tc] = z;
      }
      __builtin_amdgcn_s_setprio(0);
      // ---- mask + scale; per-lane max over 16 keys ----
      float pmax = -1e30f;
#pragma unroll
      for (int tc = 0; tc < 4; ++tc)
#pragma unroll
        for (int r = 0; r < 4; ++r) {
          int key = k0 + tc * 16 + h * 4 + r;
          float v = sc[tc][r] * 0.125f;
          if (key > q_abs) v = -1e30f;
          sc[tc][r] = v;
          pmax = fmaxf(pmax, v);
        }
      pmax = fmaxf(pmax, __shfl_xor(pmax, 16));
      pmax = fmaxf(pmax, __shfl_xor(pmax, 32));
      float mnew = fmaxf(mrun, pmax);
      float alpha = expf(mrun - mnew);
      mrun = mnew;
      float ssum = 0.f;
#pragma unroll
      for (int tc = 0; tc < 4; ++tc)
#pragma unroll
        for (int r = 0; r < 4; ++r) {
          float pv = expf(sc[tc][r] - mnew);
          sc[tc][r] = pv;
          ssum += pv;
        }
      ssum += __shfl_xor(ssum, 16);
      ssum += __shfl_xor(ssum, 32);
      lrun = lrun * alpha + ssum;
      // ---- write P^T to LDS: Pl[q][key] ----
#pragma unroll
      for (int tc = 0; tc < 4; ++tc)
#pragma unroll
        for (int r = 0; r < 4; ++r)
          Pl[w][r16][tc * 16 + h * 4 + r] = (bf16_t)sc[tc][r];
      // ---- rescale o: alpha for o-row q=h*4+r lives in lane h*4+r ----
      float ar[4];
#pragma unroll
      for (int r = 0; r < 4; ++r) ar[r] = __shfl(alpha, h * 4 + r);
#pragma unroll
      for (int cti = 0; cti < 4; ++cti)
#pragma unroll
        for (int r = 0; r < 4; ++r) o[cti][r] *= ar[r];
      // ---- PV ----
      bf16x8 pa0 = *(const bf16x8*)&Pl[w][r16][h * 8];
      bf16x8 pa1 = *(const bf16x8*)&Pl[w][r16][32 + h * 8];
      __builtin_amdgcn_s_setprio(1);
#pragma unroll
      for (int cti = 0; cti < 4; ++cti) {
        bf16x8 v0 = *(const bf16x8*)&Vt[cti * 16 + r16][h * 8];
        bf16x8 v1 = *(const bf16x8*)&Vt[cti * 16 + r16][32 + h * 8];
        o[cti] = __builtin_amdgcn_mfma_f32_16x16x32_bf16(pa0, v0, o[cti], 0, 0, 0);
        o[cti] = __builtin_amdgcn_mfma_f32_16x16x32_bf16(pa1, v1, o[cti], 0, 0, 0);
      }
      __builtin_amdgcn_s_setprio(0);
    }
    __syncthreads();
  }
  float lr[4];
#pragma unroll
  for (int r = 0; r < 4; ++r) lr[r] = __shfl(lrun, h * 4 + r);
#pragma unroll
  for (int cti = 0; cti < 4; ++cti)
#pragma unroll
    for (int r = 0; r < 4; ++r) {
      int row = q0 + h * 4 + r;
      ao[(size_t)row * DIM + hoff + cti * 16 + r16] = (bf16_t)(o[cti][r] / lr[r]);
    }
}

extern "C" void kernel_launch(void* const* d_in, const int* in_sizes, int n_in,
                              void* d_out, int out_size, void* d_ws, size_t ws_size,
                              hipStream_t stream) {
  const int*   ids  = (const int*)d_in[0];
  const float* temb = (const float*)d_in[1];
  const float* Wq   = (const float*)d_in[2];
  const float* Wk   = (const float*)d_in[3];
  const float* Wv   = (const float*)d_in[4];
  const float* Wo   = (const float*)d_in[5];
  const float* ln1s = (const float*)d_in[6];
  const float* ln1b = (const float*)d_in[7];
  const float* ln2s = (const float*)d_in[8];
  const float* ln2b = (const float*)d_in[9];
  const float* w1   = (const float*)d_in[10];
  const float* w2   = (const float*)d_in[11];
  const float* w3   = (const float*)d_in[12];
  const float* lnfs = (const float*)d_in[13];
  const float* lnfb = (const float*)d_in[14];
  const float* lmh  = (const float*)d_in[15];
  float* out = (float*)d_out;

  char* p = (char*)d_ws;
  size_t used = 0;
  auto alloc = [&](size_t bytes) {
    void* r = (void*)p;
    size_t a = (bytes + 255) & ~(size_t)255;
    p += a; used += a;
    return r;
  };
  // activations + tables
  float*  x     = (float*)alloc((size_t)SEQ * DIM * 4);
  bf16_t* hb    = (bf16_t*)alloc((size_t)SEQ * DIM * 2);
  bf16_t* qb2   = (bf16_t*)alloc((size_t)SEQ * DIM * 2);
  bf16_t* kb2   = (bf16_t*)alloc((size_t)SEQ * DIM * 2);
  bf16_t* vb2   = (bf16_t*)alloc((size_t)SEQ * DIM * 2);
  bf16_t* aob   = (bf16_t*)alloc((size_t)SEQ * DIM * 2);
  bf16_t* gateb = (bf16_t*)alloc((size_t)SEQ * FF * 2);
  float*  ctab  = (float*)alloc((size_t)SEQ * 32 * 4);
  float*  stab  = (float*)alloc((size_t)SEQ * 32 * 4);

  const size_t szDD = (size_t)DIM * DIM;    // 1M elems
  const size_t szDF = (size_t)DIM * FF;     // 4M elems
  const size_t wt_bytes = ((size_t)NL * (3 * szDD + szDD + 2 * szDF + szDF) + (size_t)VOCP * DIM) * 2;
  const bool bigws = (ws_size >= used + wt_bytes + (1u << 20));

  bf16_t *bQKV, *bWo, *bW13, *bw2, *blm, *wscratch = nullptr;
  if (bigws) {
    bQKV = (bf16_t*)alloc(NL * 3 * szDD * 2);
    bWo  = (bf16_t*)alloc(NL * szDD * 2);
    bW13 = (bf16_t*)alloc(NL * 2 * szDF * 2);
    bw2  = (bf16_t*)alloc(NL * szDF * 2);
    blm  = (bf16_t*)alloc((size_t)VOCP * DIM * 2);
  } else {
    wscratch = (bf16_t*)alloc(2 * szDF * 2);   // enough for fused w13 of one layer
    bQKV = bWo = bW13 = bw2 = blm = wscratch;
  }

  auto cvt = [&](const float* src, bf16_t* dst, int K_, int N_, int Npad_, int nz,
                 size_t dstride, int imode) {
    dim3 g(Npad_ / 64, K_ / 64, nz);
    k_cvt_t<<<g, 256, 0, stream>>>(src, dst, K_, N_, Npad_, dstride, imode);
  };

  if (bigws) {
    cvt(Wq, bQKV,             DIM, DIM, DIM, NL, 3 * szDD, 0);
    cvt(Wk, bQKV + szDD,      DIM, DIM, DIM, NL, 3 * szDD, 0);
    cvt(Wv, bQKV + 2 * szDD,  DIM, DIM, DIM, NL, 3 * szDD, 0);
    cvt(Wo, bWo,              DIM, DIM, DIM, NL, szDD, 0);
    cvt(w1, bW13,             DIM, FF,  FF,  NL, 2 * szDF, 1);   // interleaved even
    cvt(w3, bW13,             DIM, FF,  FF,  NL, 2 * szDF, 2);   // interleaved odd
    cvt(w2, bw2,              FF,  DIM, DIM, NL, szDF, 0);
    cvt(lmh, blm,             DIM, VOC, VOCP, 1, 0, 0);
  }
  auto wpQKV = [&](int lyr) -> bf16_t* {
    if (bigws) return bQKV + (size_t)lyr * 3 * szDD;
    cvt(Wq + (size_t)lyr * szDD, wscratch,            DIM, DIM, DIM, 1, 0, 0);
    cvt(Wk + (size_t)lyr * szDD, wscratch + szDD,     DIM, DIM, DIM, 1, 0, 0);
    cvt(Wv + (size_t)lyr * szDD, wscratch + 2 * szDD, DIM, DIM, DIM, 1, 0, 0);
    return wscratch;
  };
  auto wpW13 = [&](int lyr) -> bf16_t* {
    if (bigws) return bW13 + (size_t)lyr * 2 * szDF;
    cvt(w1 + (size_t)lyr * szDF, wscratch, DIM, FF, FF, 1, 0, 1);
    cvt(w3 + (size_t)lyr * szDF, wscratch, DIM, FF, FF, 1, 0, 2);
    return wscratch;
  };
  auto wp1 = [&](bf16_t* big, const float* src, int lyr, int K_, int N_, int Npad_) -> bf16_t* {
    if (bigws) return big + (size_t)lyr * Npad_ * K_;
    cvt(src + (size_t)lyr * K_ * N_, wscratch, K_, N_, Npad_, 1, 0, 0);
    return wscratch;
  };

  k_rtab<<<(SEQ * 32) / 256, 256, 0, stream>>>(ctab, stab);
  k_embed<<<SEQ, 256, 0, stream>>>(ids, temb, x);

  dim3 gQKV(3 * DIM / 128, SEQ / 64);    // 24 x 32 = 768 (3/CU, 64x128 tiles)
  dim3 gDD(DIM / 64, SEQ / 64);          // 16 x 32 = 512 (2/CU, 64x64 tiles)
  dim3 gW13(2 * FF / 256, SEQ / 256);    // 32 x 8 = 256 (1/CU, 256^2 dbuf kernel)
  dim3 gLM(VOCP / 64, SEQ / 64);         // 22 x 32 = 704
  dim3 gAt(32, NH);                      // 32 tiles x 16 heads = 512 (2/CU)

  for (int l = 0; l < NL; ++l) {
    k_ln<<<SEQ / 4, 256, 0, stream>>>(x, ln1s + (size_t)l * DIM, ln1b + (size_t)l * DIM, hb);
    k_gemm2<64, 128, 4><<<gQKV, 256, 0, stream>>>(hb, wpQKV(l), nullptr, vb2, qb2, kb2,
                                                  ctab, stab, SEQ, 3 * DIM, DIM);
    k_attn4<<<gAt, 256, 0, stream>>>(qb2, kb2, vb2, aob);
    k_gemm2<64, 64, 2><<<gDD, 256, 0, stream>>>(aob, wp1(bWo, Wo, l, DIM, DIM, DIM), x, nullptr,
                                                nullptr, nullptr, nullptr, nullptr, SEQ, DIM, DIM);
    k_ln<<<SEQ / 4, 256, 0, stream>>>(x, ln2s + (size_t)l * DIM, ln2b + (size_t)l * DIM, hb);
    k_gemm256_gate<<<gW13, 512, 0, stream>>>(hb, wpW13(l), gateb, DIM);
    k_gemm2<64, 64, 2><<<gDD, 256, 0, stream>>>(gateb, wp1(bw2, w2, l, FF, DIM, DIM), x, nullptr,
                                                nullptr, nullptr, nullptr, nullptr, SEQ, DIM, FF);
  }
  k_ln<<<SEQ / 4, 256, 0, stream>>>(x, lnfs, lnfb, hb);
  k_gemm2<64, 64, 0><<<gLM, 256, 0, stream>>>(hb, bigws ? blm : wp1(blm, lmh, 0, DIM, VOC, VOCP),
                                              out, nullptr, nullptr, nullptr, nullptr, nullptr,
                                              SEQ, VOC, DIM);
}

// Round 18
// 2724.315 us; speedup vs baseline: 1.2417x; 1.0369x over previous
//
#include <hip/hip_runtime.h>
#include <math.h>

// ---- problem constants ----
constexpr int SEQ = 2048;
constexpr int DIM = 1024;
constexpr int NH  = 16;
constexpr int HD  = 64;
constexpr int FF  = 4096;
constexpr int NL  = 12;
constexpr int VOC = 1400;
constexpr int VOCP = 1408;   // padded to 64

typedef __bf16 bf16_t;
typedef __bf16 bf16x8 __attribute__((ext_vector_type(8)));
typedef float  f32x4  __attribute__((ext_vector_type(4)));

typedef __attribute__((address_space(1))) const void GV;
typedef __attribute__((address_space(3))) void LV;

__device__ __forceinline__ void gll16(const bf16_t* g, bf16_t* l) {
  __builtin_amdgcn_global_load_lds((GV*)g, (LV*)l, 16, 0, 0);
}

// ---------------- embedding gather ----------------
__global__ __launch_bounds__(256) void k_embed(const int* __restrict__ ids,
                                               const float* __restrict__ emb,
                                               float* __restrict__ x) {
  int s = blockIdx.x;
  int d = threadIdx.x * 4;
  const float4 v = *(const float4*)&emb[(size_t)ids[s] * DIM + d];
  *(float4*)&x[(size_t)s * DIM + d] = v;
}

// ---------------- RoPE cos/sin table: [s][i], i = freq idx 0..31 ----------------
__global__ __launch_bounds__(256) void k_rtab(float* __restrict__ ct,
                                              float* __restrict__ st) {
  int id = blockIdx.x * 256 + threadIdx.x;   // SEQ*32
  int i = id & 31;
  int s = id >> 5;
  float ang = (float)s * powf(10000.f, -(float)i * (1.f / 32.f));
  float sn, cs;
  sincosf(ang, &sn, &cs);
  ct[id] = cs;
  st[id] = sn;
}

// ------- layernorm (f32 in -> bf16 out), 4 rows/block, 1 wave per row -------
__global__ __launch_bounds__(256) void k_ln(const float* __restrict__ x,
                                            const float* __restrict__ sc,
                                            const float* __restrict__ bi,
                                            bf16_t* __restrict__ out) {
  int s = blockIdx.x * 4 + (threadIdx.x >> 6);
  int l = threadIdx.x & 63;
  const float* xr = x + (size_t)s * DIM;
  float4 v[4];
  float sum = 0.f, sq = 0.f;
#pragma unroll
  for (int i = 0; i < 4; ++i) {
    v[i] = *(const float4*)&xr[i * 256 + l * 4];
#pragma unroll
    for (int j = 0; j < 4; ++j) { sum += v[i][j]; sq += v[i][j] * v[i][j]; }
  }
#pragma unroll
  for (int d = 1; d < 64; d <<= 1) {
    sum += __shfl_xor(sum, d);
    sq  += __shfl_xor(sq, d);
  }
  float mean = sum * (1.f / DIM);
  float var  = sq * (1.f / DIM) - mean * mean;
  float inv  = rsqrtf(var + 1e-5f);
#pragma unroll
  for (int i = 0; i < 4; ++i) {
    int off = i * 256 + l * 4;
    float4 scv = *(const float4*)&sc[off];
    float4 biv = *(const float4*)&bi[off];
#pragma unroll
    for (int j = 0; j < 4; ++j) {
      float o = (v[i][j] - mean) * inv * scv[j] + biv[j];
      out[(size_t)s * DIM + off + j] = (bf16_t)o;
    }
  }
}

// ------- weight convert + transpose: src[K][N] f32 -> dst[...][K] bf16 -------
// imode 0: dst row = n. imode 1: w1 f -> (f>>4)*32+(f&15). imode 2: w3 -> +16.
__global__ __launch_bounds__(256) void k_cvt_t(const float* __restrict__ src,
                                               bf16_t* __restrict__ dst,
                                               int K_, int N_, int Npad_,
                                               size_t dstride, int imode) {
  __shared__ bf16_t T[64][66];
  const int k0 = blockIdx.y * 64;
  const int n0 = blockIdx.x * 64;
  const size_t so = (size_t)blockIdx.z * K_ * N_;
  const size_t dof = (size_t)blockIdx.z * dstride;
  const int t = threadIdx.x;
  const int kk = t >> 4;
  const int nn = (t & 15) * 4;
#pragma unroll
  for (int it = 0; it < 4; ++it) {
    int krow = kk + it * 16;
    float4 v = {0.f, 0.f, 0.f, 0.f};
    if (n0 + nn < N_) v = *(const float4*)&src[so + (size_t)(k0 + krow) * N_ + n0 + nn];
#pragma unroll
    for (int q = 0; q < 4; ++q) T[nn + q][krow] = (bf16_t)v[q];
  }
  __syncthreads();
#pragma unroll
  for (int it = 0; it < 4; ++it) {
    int c = it * 256 + t;
    int nr = c >> 4;
    int kc = (c & 15) * 4;
    int f = n0 + nr;
    int drow = (imode == 0) ? f : ((f >> 4) * 32 + ((imode == 2) ? 16 : 0) + (f & 15));
    ushort4 o = *(const ushort4*)&T[nr][kc];
    *(ushort4*)&dst[dof + (size_t)drow * K_ + k0 + kc] = o;
  }
}

// ---------------- GEMM: C[M,N] = A[M,K] * Bt[N][K], bf16 MFMA ----------------
// tile TM x TN, BK=64, 4 waves (2x2; each wave TM/2 x TN/2). XOR-swizzled
// staging (round-9 verified; row offsets all multiples of 8 so rA&7 == r16&7).
// OUTMODE 0: f32 store | 2: f32 += | 4: fused QKV(+RoPE) | 6: interleaved silu-gate
template <int TM, int TN, int OUTMODE>
__global__ __launch_bounds__(256) void k_gemm2(const bf16_t* __restrict__ A,
                                               const bf16_t* __restrict__ Bt,
                                               float* __restrict__ Cf,
                                               bf16_t* __restrict__ Cb,
                                               bf16_t* __restrict__ aux1,
                                               bf16_t* __restrict__ aux2,
                                               const float* __restrict__ ct,
                                               const float* __restrict__ st,
                                               int M, int N, int K) {
  constexpr int MI = TM / 32;            // A frags per wave (and A stage issues)
  constexpr int JN = TN / 32;            // B frags per wave (and B stage issues)
  __shared__ bf16_t As[TM * 64];
  __shared__ bf16_t Bs[TN * 64];
  const int t = threadIdx.x;
  const int w = t >> 6, l = t & 63;
  const int h = l >> 4, r16 = l & 15;
  const int m0 = blockIdx.y * TM, n0 = blockIdx.x * TN;
  const int wr = (w >> 1) * (TM / 2);
  const int wc = (w & 1) * (TN / 2);
  const int sr8  = l >> 3;               // 0..7 row within wave-slab
  const int xch  = ((l & 7) ^ sr8) * 8;  // pre-swizzled k-chunk offset (elems)
  const int s7   = r16 & 7;              // reader swizzle key

  f32x4 acc[MI][JN] = {};

  const bf16_t* pa = &A[(size_t)(m0 + w * 8 + sr8) * K + xch];
  const bf16_t* pb = &Bt[(size_t)(n0 + w * 8 + sr8) * K + xch];

  for (int k0 = 0; k0 < K; k0 += 64) {
#pragma unroll
    for (int i = 0; i < MI; ++i)
      gll16(pa + (size_t)i * 32 * K + k0, &As[(i * 32 + w * 8) * 64]);
#pragma unroll
    for (int i = 0; i < JN; ++i)
      gll16(pb + (size_t)i * 32 * K + k0, &Bs[(i * 32 + w * 8) * 64]);
    __syncthreads();
#pragma unroll
    for (int kk = 0; kk < 2; ++kk) {
      const int p = ((kk * 4 + h) ^ s7) * 8;   // swizzled read position (elems)
      bf16x8 af[MI], bfr[JN];
#pragma unroll
      for (int i = 0; i < MI; ++i)
        af[i] = *(const bf16x8*)&As[(wr + i * 16 + r16) * 64 + p];
#pragma unroll
      for (int j = 0; j < JN; ++j)
        bfr[j] = *(const bf16x8*)&Bs[(wc + j * 16 + r16) * 64 + p];
#pragma unroll
      for (int i = 0; i < MI; ++i)
#pragma unroll
        for (int j = 0; j < JN; ++j)
          acc[i][j] = __builtin_amdgcn_mfma_f32_16x16x32_bf16(af[i], bfr[j], acc[i][j], 0, 0, 0);
    }
    __syncthreads();
  }

  if constexpr (OUTMODE == 4) {
    const int reg = n0 >> 10;
    const int cbase = (n0 & 1023) + wc;
    if (reg == 2) {
#pragma unroll
      for (int i = 0; i < MI; ++i)
#pragma unroll
        for (int j = 0; j < JN; ++j)
#pragma unroll
          for (int r = 0; r < 4; ++r) {
            int row = m0 + wr + i * 16 + h * 4 + r;
            Cb[(size_t)row * DIM + cbase + j * 16 + r16] = (bf16_t)acc[i][j][r];
          }
    } else {
      bf16_t* dst = reg ? aux2 : aux1;
#pragma unroll
      for (int i = 0; i < MI; ++i)
#pragma unroll
        for (int r = 0; r < 4; ++r) {
          int row = m0 + wr + i * 16 + h * 4 + r;
          float c0 = ct[row * 32 + r16],      s0 = st[row * 32 + r16];
          float c1 = ct[row * 32 + 16 + r16], s1 = st[row * 32 + 16 + r16];
          float lo0 = acc[i][0][r], hi0 = acc[i][2][r];
          float lo1 = acc[i][1][r], hi1 = acc[i][3][r];
          size_t rb = (size_t)row * DIM + cbase;
          dst[rb + r16]      = (bf16_t)(lo0 * c0 - hi0 * s0);
          dst[rb + 32 + r16] = (bf16_t)(hi0 * c0 + lo0 * s0);
          dst[rb + 16 + r16] = (bf16_t)(lo1 * c1 - hi1 * s1);
          dst[rb + 48 + r16] = (bf16_t)(hi1 * c1 + lo1 * s1);
        }
    }
  } else if constexpr (OUTMODE == 6) {
    const int fbase = ((n0 + wc) >> 5) * 16;
#pragma unroll
    for (int i = 0; i < MI; ++i)
#pragma unroll
      for (int r = 0; r < 4; ++r) {
        int row = m0 + wr + i * 16 + h * 4 + r;
        float a0 = acc[i][0][r], b0 = acc[i][1][r];
        float a1 = acc[i][2][r], b1 = acc[i][3][r];
        float g0 = a0 / (1.f + expf(-a0)) * b0;
        float g1v = a1 / (1.f + expf(-a1)) * b1;
        size_t rb = (size_t)row * FF + fbase;
        aux1[rb + r16]      = (bf16_t)g0;
        aux1[rb + 16 + r16] = (bf16_t)g1v;
      }
  } else {
#pragma unroll
    for (int i = 0; i < MI; ++i)
#pragma unroll
      for (int j = 0; j < JN; ++j)
#pragma unroll
        for (int r = 0; r < 4; ++r) {
          int row = m0 + wr + i * 16 + h * 4 + r;
          int col = n0 + wc + j * 16 + r16;
          if (col < N) {
            float vv = acc[i][j][r];
            size_t idx = (size_t)row * N + col;
            if (OUTMODE == 0) Cf[idx] = vv;
            else Cf[idx] += vv;
          }
        }
  }
}

// ------- w13 GEMM: 256x256 tile, BK=64, 8 waves (2M x 4N), double-buffered LDS ----
// (round-12 version — best measured). Interleaved w1/w3 silu-gate epilogue.
__global__ __launch_bounds__(512, 1) void k_gemm256_gate(const bf16_t* __restrict__ A,
                                                         const bf16_t* __restrict__ Bt,
                                                         bf16_t* __restrict__ gate,
                                                         int K) {
  __shared__ bf16_t As[2][256 * 64];
  __shared__ bf16_t Bs[2][256 * 64];
  const int t = threadIdx.x;
  const int w = t >> 6, l = t & 63;
  const int h = l >> 4, r16 = l & 15;
  const int m0 = blockIdx.y * 256, n0 = blockIdx.x * 256;
  const int wr = (w >> 2) * 128;       // wave M offset: 0 or 128
  const int wc = (w & 3) * 64;         // wave N offset: 0,64,128,192
  const int sr = t >> 3;               // staging row within 64-row slab (0..63)
  const int xch = ((t & 7) ^ (sr & 7)) * 8;   // pre-swizzled k-chunk (elems)
  const int s7 = r16 & 7;

  f32x4 acc[8][4] = {};

  const bf16_t* pa = &A[(size_t)(m0 + sr) * K + xch];
  const bf16_t* pb = &Bt[(size_t)(n0 + sr) * K + xch];
  const int NT = K >> 6;

  auto STAGE = [&](int kt, int b) {
    const int k0 = kt << 6;
    bf16_t* baseA = &As[b][(w * 8) * 64];   // wave-uniform LDS base (+lane*16B)
    bf16_t* baseB = &Bs[b][(w * 8) * 64];
#pragma unroll
    for (int i = 0; i < 4; ++i) {
      gll16(pa + (size_t)(i * 64) * K + k0, baseA + i * 64 * 64);
      gll16(pb + (size_t)(i * 64) * K + k0, baseB + i * 64 * 64);
    }
  };

  STAGE(0, 0);
  asm volatile("s_waitcnt vmcnt(0)" ::: "memory");
  __builtin_amdgcn_s_barrier();
  __builtin_amdgcn_sched_barrier(0);

  int cur = 0;
  for (int tt = 0; tt < NT; ++tt) {
    if (tt + 1 < NT) STAGE(tt + 1, cur ^ 1);   // overlap with compute below
#pragma unroll
    for (int kk = 0; kk < 2; ++kk) {
      const int p = ((kk * 4 + h) ^ s7) * 8;
      bf16x8 af[8], bfr[4];
#pragma unroll
      for (int i = 0; i < 8; ++i)
        af[i] = *(const bf16x8*)&As[cur][(wr + i * 16 + r16) * 64 + p];
#pragma unroll
      for (int j = 0; j < 4; ++j)
        bfr[j] = *(const bf16x8*)&Bs[cur][(wc + j * 16 + r16) * 64 + p];
#pragma unroll
      for (int i = 0; i < 8; ++i)
#pragma unroll
        for (int j = 0; j < 4; ++j)
          acc[i][j] = __builtin_amdgcn_mfma_f32_16x16x32_bf16(af[i], bfr[j], acc[i][j], 0, 0, 0);
    }
    asm volatile("s_waitcnt vmcnt(0)" ::: "memory");   // next tile landed
    __builtin_amdgcn_s_barrier();
    __builtin_amdgcn_sched_barrier(0);
    cur ^= 1;
  }

  // interleaved silu-gate epilogue: j even = w1, j odd = w3 (same features)
  const int fbase = ((n0 + wc) >> 5) * 16;
#pragma unroll
  for (int i = 0; i < 8; ++i)
#pragma unroll
    for (int r = 0; r < 4; ++r) {
      int row = m0 + wr + i * 16 + h * 4 + r;
      float a0 = acc[i][0][r], b0 = acc[i][1][r];
      float a1 = acc[i][2][r], b1 = acc[i][3][r];
      float g0 = a0 / (1.f + expf(-a0)) * b0;
      float g1v = a1 / (1.f + expf(-a1)) * b1;
      size_t rb = (size_t)row * FF + fbase;
      gate[rb + r16]      = (bf16_t)g0;
      gate[rb + 16 + r16] = (bf16_t)g1v;
    }
}

// ------- flash attention: 4 waves/block, swapped-QK, one 64-row tile/block -------
// KVBLK=128: half the chunk count / barrier pairs vs 64 (latency-bound regime).
// 512 blocks (2/CU). Complementary pairing: qt = head<8 ? raw : 31-raw gives a
// uniform 17 staged chunks per CU. T14 async-STAGE: next chunk's loads issue into
// regs before chunk-t compute; regs written to LDS after the barrier.
__global__ __launch_bounds__(256) void k_attn4(const bf16_t* __restrict__ qb,
                                               const bf16_t* __restrict__ kb,
                                               const bf16_t* __restrict__ vb,
                                               bf16_t* __restrict__ ao) {
  __shared__ bf16_t Ks[128][72];      // K chunk: [key][dh]
  __shared__ bf16_t Vt[64][136];      // V chunk transposed: [dh][key]
  __shared__ bf16_t Pl[4][16][136];   // per-wave P: [qrow][key]
  const int raw = blockIdx.x;         // 0..31
  const int head = blockIdx.y;        // 0..15
  const int qt = (head < 8) ? raw : (31 - raw);   // complementary per-CU pairing
  const int t = threadIdx.x;
  const int w = t >> 6, l = t & 63;
  const int h = l >> 4, r16 = l & 15;
  const size_t hoff = (size_t)head * HD;
  const int srow = t >> 1;            // 0..127 staging row (key)
  const int sc4  = (t & 1) * 4;       // which 4 of 8 dh-vectors

  const int q0 = qt * 64 + w * 16;    // this wave's first q row
  const int q_abs = q0 + r16;         // this lane's q row (softmax axis)

  bf16x8 aq[2];
#pragma unroll
  for (int c = 0; c < 2; ++c)
    aq[c] = *(const bf16x8*)&qb[(size_t)(q0 + r16) * DIM + hoff + c * 32 + h * 8];

  f32x4 o[4] = {};
  float mrun = -1e30f, lrun = 0.f;

  const int kend = qt * 64 + 63;

  // ---- preload chunk 0 into regs ----
  bf16x8 kreg[4], vreg[4];
#pragma unroll
  for (int it = 0; it < 4; ++it) {
    kreg[it] = *(const bf16x8*)&kb[(size_t)srow * DIM + hoff + (sc4 + it) * 8];
    vreg[it] = *(const bf16x8*)&vb[(size_t)srow * DIM + hoff + (sc4 + it) * 8];
  }

  for (int k0 = 0; k0 <= kend; k0 += 128) {
    // ---- write staged regs to LDS: K direct, V transposed ----
#pragma unroll
    for (int it = 0; it < 4; ++it)
      *(bf16x8*)&Ks[srow][(sc4 + it) * 8] = kreg[it];
#pragma unroll
    for (int it = 0; it < 4; ++it)
#pragma unroll
      for (int j = 0; j < 8; ++j) Vt[(sc4 + it) * 8 + j][srow] = vreg[it][j];
    __syncthreads();

    // ---- issue next chunk's global loads (overlap with compute below) ----
    if (k0 + 128 <= kend) {
      const size_t nb = (size_t)(k0 + 128 + srow) * DIM + hoff;
#pragma unroll
      for (int it = 0; it < 4; ++it) {
        kreg[it] = *(const bf16x8*)&kb[nb + (sc4 + it) * 8];
        vreg[it] = *(const bf16x8*)&vb[nb + (sc4 + it) * 8];
      }
    }

    if (k0 <= q0 + 15) {              // wave-uniform: skip fully-masked chunks
      // ---- scores transposed: D[key][q], 8 col-tiles of 16 keys ----
      f32x4 sc[8];
      __builtin_amdgcn_s_setprio(1);
#pragma unroll
      for (int tc = 0; tc < 8; ++tc) {
        f32x4 z = {};
        bf16x8 a0 = *(const bf16x8*)&Ks[tc * 16 + r16][h * 8];
        bf16x8 a1 = *(const bf16x8*)&Ks[tc * 16 + r16][32 + h * 8];
        z = __builtin_amdgcn_mfma_f32_16x16x32_bf16(a0, aq[0], z, 0, 0, 0);
        z = __builtin_amdgcn_mfma_f32_16x16x32_bf16(a1, aq[1], z, 0, 0, 0);
        sc[tc] = z;
      }
      __builtin_amdgcn_s_setprio(0);
      // ---- mask + scale; per-lane max over 32 keys ----
      float pmax = -1e30f;
#pragma unroll
      for (int tc = 0; tc < 8; ++tc)
#pragma unroll
        for (int r = 0; r < 4; ++r) {
          int key = k0 + tc * 16 + h * 4 + r;
          float v = sc[tc][r] * 0.125f;
          if (key > q_abs) v = -1e30f;
          sc[tc][r] = v;
          pmax = fmaxf(pmax, v);
        }
      pmax = fmaxf(pmax, __shfl_xor(pmax, 16));
      pmax = fmaxf(pmax, __shfl_xor(pmax, 32));
      float mnew = fmaxf(mrun, pmax);
      float alpha = expf(mrun - mnew);
      mrun = mnew;
      float ssum = 0.f;
#pragma unroll
      for (int tc = 0; tc < 8; ++tc)
#pragma unroll
        for (int r = 0; r < 4; ++r) {
          float pv = expf(sc[tc][r] - mnew);
          sc[tc][r] = pv;
          ssum += pv;
        }
      ssum += __shfl_xor(ssum, 16);
      ssum += __shfl_xor(ssum, 32);
      lrun = lrun * alpha + ssum;
      // ---- write P^T to LDS: Pl[q][key] ----
#pragma unroll
      for (int tc = 0; tc < 8; ++tc)
#pragma unroll
        for (int r = 0; r < 4; ++r)
          Pl[w][r16][tc * 16 + h * 4 + r] = (bf16_t)sc[tc][r];
      // ---- rescale o: alpha for o-row q=h*4+r lives in lane h*4+r ----
      float ar[4];
#pragma unroll
      for (int r = 0; r < 4; ++r) ar[r] = __shfl(alpha, h * 4 + r);
#pragma unroll
      for (int cti = 0; cti < 4; ++cti)
#pragma unroll
        for (int r = 0; r < 4; ++r) o[cti][r] *= ar[r];
      // ---- PV: 4 k-slices of 32 keys ----
      __builtin_amdgcn_s_setprio(1);
#pragma unroll
      for (int ks = 0; ks < 4; ++ks) {
        bf16x8 pk = *(const bf16x8*)&Pl[w][r16][ks * 32 + h * 8];
#pragma unroll
        for (int cti = 0; cti < 4; ++cti) {
          bf16x8 vv = *(const bf16x8*)&Vt[cti * 16 + r16][ks * 32 + h * 8];
          o[cti] = __builtin_amdgcn_mfma_f32_16x16x32_bf16(pk, vv, o[cti], 0, 0, 0);
        }
      }
      __builtin_amdgcn_s_setprio(0);
    }
    __syncthreads();
  }
  float lr[4];
#pragma unroll
  for (int r = 0; r < 4; ++r) lr[r] = __shfl(lrun, h * 4 + r);
#pragma unroll
  for (int cti = 0; cti < 4; ++cti)
#pragma unroll
    for (int r = 0; r < 4; ++r) {
      int row = q0 + h * 4 + r;
      ao[(size_t)row * DIM + hoff + cti * 16 + r16] = (bf16_t)(o[cti][r] / lr[r]);
    }
}

extern "C" void kernel_launch(void* const* d_in, const int* in_sizes, int n_in,
                              void* d_out, int out_size, void* d_ws, size_t ws_size,
                              hipStream_t stream) {
  const int*   ids  = (const int*)d_in[0];
  const float* temb = (const float*)d_in[1];
  const float* Wq   = (const float*)d_in[2];
  const float* Wk   = (const float*)d_in[3];
  const float* Wv   = (const float*)d_in[4];
  const float* Wo   = (const float*)d_in[5];
  const float* ln1s = (const float*)d_in[6];
  const float* ln1b = (const float*)d_in[7];
  const float* ln2s = (const float*)d_in[8];
  const float* ln2b = (const float*)d_in[9];
  const float* w1   = (const float*)d_in[10];
  const float* w2   = (const float*)d_in[11];
  const float* w3   = (const float*)d_in[12];
  const float* lnfs = (const float*)d_in[13];
  const float* lnfb = (const float*)d_in[14];
  const float* lmh  = (const float*)d_in[15];
  float* out = (float*)d_out;

  char* p = (char*)d_ws;
  size_t used = 0;
  auto alloc = [&](size_t bytes) {
    void* r = (void*)p;
    size_t a = (bytes + 255) & ~(size_t)255;
    p += a; used += a;
    return r;
  };
  // activations + tables
  float*  x     = (float*)alloc((size_t)SEQ * DIM * 4);
  bf16_t* hb    = (bf16_t*)alloc((size_t)SEQ * DIM * 2);
  bf16_t* qb2   = (bf16_t*)alloc((size_t)SEQ * DIM * 2);
  bf16_t* kb2   = (bf16_t*)alloc((size_t)SEQ * DIM * 2);
  bf16_t* vb2   = (bf16_t*)alloc((size_t)SEQ * DIM * 2);
  bf16_t* aob   = (bf16_t*)alloc((size_t)SEQ * DIM * 2);
  bf16_t* gateb = (bf16_t*)alloc((size_t)SEQ * FF * 2);
  float*  ctab  = (float*)alloc((size_t)SEQ * 32 * 4);
  float*  stab  = (float*)alloc((size_t)SEQ * 32 * 4);

  const size_t szDD = (size_t)DIM * DIM;    // 1M elems
  const size_t szDF = (size_t)DIM * FF;     // 4M elems
  const size_t wt_bytes = ((size_t)NL * (3 * szDD + szDD + 2 * szDF + szDF) + (size_t)VOCP * DIM) * 2;
  const bool bigws = (ws_size >= used + wt_bytes + (1u << 20));

  bf16_t *bQKV, *bWo, *bW13, *bw2, *blm, *wscratch = nullptr;
  if (bigws) {
    bQKV = (bf16_t*)alloc(NL * 3 * szDD * 2);
    bWo  = (bf16_t*)alloc(NL * szDD * 2);
    bW13 = (bf16_t*)alloc(NL * 2 * szDF * 2);
    bw2  = (bf16_t*)alloc(NL * szDF * 2);
    blm  = (bf16_t*)alloc((size_t)VOCP * DIM * 2);
  } else {
    wscratch = (bf16_t*)alloc(2 * szDF * 2);   // enough for fused w13 of one layer
    bQKV = bWo = bW13 = bw2 = blm = wscratch;
  }

  auto cvt = [&](const float* src, bf16_t* dst, int K_, int N_, int Npad_, int nz,
                 size_t dstride, int imode) {
    dim3 g(Npad_ / 64, K_ / 64, nz);
    k_cvt_t<<<g, 256, 0, stream>>>(src, dst, K_, N_, Npad_, dstride, imode);
  };

  if (bigws) {
    cvt(Wq, bQKV,             DIM, DIM, DIM, NL, 3 * szDD, 0);
    cvt(Wk, bQKV + szDD,      DIM, DIM, DIM, NL, 3 * szDD, 0);
    cvt(Wv, bQKV + 2 * szDD,  DIM, DIM, DIM, NL, 3 * szDD, 0);
    cvt(Wo, bWo,              DIM, DIM, DIM, NL, szDD, 0);
    cvt(w1, bW13,             DIM, FF,  FF,  NL, 2 * szDF, 1);   // interleaved even
    cvt(w3, bW13,             DIM, FF,  FF,  NL, 2 * szDF, 2);   // interleaved odd
    cvt(w2, bw2,              FF,  DIM, DIM, NL, szDF, 0);
    cvt(lmh, blm,             DIM, VOC, VOCP, 1, 0, 0);
  }
  auto wpQKV = [&](int lyr) -> bf16_t* {
    if (bigws) return bQKV + (size_t)lyr * 3 * szDD;
    cvt(Wq + (size_t)lyr * szDD, wscratch,            DIM, DIM, DIM, 1, 0, 0);
    cvt(Wk + (size_t)lyr * szDD, wscratch + szDD,     DIM, DIM, DIM, 1, 0, 0);
    cvt(Wv + (size_t)lyr * szDD, wscratch + 2 * szDD, DIM, DIM, DIM, 1, 0, 0);
    return wscratch;
  };
  auto wpW13 = [&](int lyr) -> bf16_t* {
    if (bigws) return bW13 + (size_t)lyr * 2 * szDF;
    cvt(w1 + (size_t)lyr * szDF, wscratch, DIM, FF, FF, 1, 0, 1);
    cvt(w3 + (size_t)lyr * szDF, wscratch, DIM, FF, FF, 1, 0, 2);
    return wscratch;
  };
  auto wp1 = [&](bf16_t* big, const float* src, int lyr, int K_, int N_, int Npad_) -> bf16_t* {
    if (bigws) return big + (size_t)lyr * Npad_ * K_;
    cvt(src + (size_t)lyr * K_ * N_, wscratch, K_, N_, Npad_, 1, 0, 0);
    return wscratch;
  };

  k_rtab<<<(SEQ * 32) / 256, 256, 0, stream>>>(ctab, stab);
  k_embed<<<SEQ, 256, 0, stream>>>(ids, temb, x);

  dim3 gQKV(3 * DIM / 128, SEQ / 64);    // 24 x 32 = 768 (3/CU, 64x128 tiles)
  dim3 gDD(DIM / 64, SEQ / 64);          // 16 x 32 = 512 (2/CU, 64x64 tiles)
  dim3 gW13(2 * FF / 256, SEQ / 256);    // 32 x 8 = 256 (1/CU, 256^2 dbuf kernel)
  dim3 gLM(VOCP / 64, SEQ / 64);         // 22 x 32 = 704
  dim3 gAt(32, NH);                      // 32 tiles x 16 heads = 512 (2/CU)

  for (int l = 0; l < NL; ++l) {
    k_ln<<<SEQ / 4, 256, 0, stream>>>(x, ln1s + (size_t)l * DIM, ln1b + (size_t)l * DIM, hb);
    k_gemm2<64, 128, 4><<<gQKV, 256, 0, stream>>>(hb, wpQKV(l), nullptr, vb2, qb2, kb2,
                                                  ctab, stab, SEQ, 3 * DIM, DIM);
    k_attn4<<<gAt, 256, 0, stream>>>(qb2, kb2, vb2, aob);
    k_gemm2<64, 64, 2><<<gDD, 256, 0, stream>>>(aob, wp1(bWo, Wo, l, DIM, DIM, DIM), x, nullptr,
                                                nullptr, nullptr, nullptr, nullptr, SEQ, DIM, DIM);
    k_ln<<<SEQ / 4, 256, 0, stream>>>(x, ln2s + (size_t)l * DIM, ln2b + (size_t)l * DIM, hb);
    k_gemm256_gate<<<gW13, 512, 0, stream>>>(hb, wpW13(l), gateb, DIM);
    k_gemm2<64, 64, 2><<<gDD, 256, 0, stream>>>(gateb, wp1(bw2, w2, l, FF, DIM, DIM), x, nullptr,
                                                nullptr, nullptr, nullptr, nullptr, SEQ, DIM, FF);
  }
  k_ln<<<SEQ / 4, 256, 0, stream>>>(x, lnfs, lnfb, hb);
  k_gemm2<64, 64, 0><<<gLM, 256, 0, stream>>>(hb, bigws ? blm : wp1(blm, lmh, 0, DIM, VOC, VOCP),
                                              out, nullptr, nullptr, nullptr, nullptr, nullptr,
                                              SEQ, VOC, DIM);
}

// Round 19
// 2435.795 us; speedup vs baseline: 1.3888x; 1.1184x over previous
//
#include <hip/hip_runtime.h>
#include <math.h>

// ---- problem constants ----
constexpr int SEQ = 2048;
constexpr int DIM = 1024;
constexpr int NH  = 16;
constexpr int HD  = 64;
constexpr int FF  = 4096;
constexpr int NL  = 12;
constexpr int VOC = 1400;
constexpr int VOCP = 1408;   // padded to 64

typedef __bf16 bf16_t;
typedef __bf16 bf16x8 __attribute__((ext_vector_type(8)));
typedef float  f32x4  __attribute__((ext_vector_type(4)));

typedef __attribute__((address_space(1))) const void GV;
typedef __attribute__((address_space(3))) void LV;

__device__ __forceinline__ void gll16(const bf16_t* g, bf16_t* l) {
  __builtin_amdgcn_global_load_lds((GV*)g, (LV*)l, 16, 0, 0);
}

// ---------------- embedding gather ----------------
__global__ __launch_bounds__(256) void k_embed(const int* __restrict__ ids,
                                               const float* __restrict__ emb,
                                               float* __restrict__ x) {
  int s = blockIdx.x;
  int d = threadIdx.x * 4;
  const float4 v = *(const float4*)&emb[(size_t)ids[s] * DIM + d];
  *(float4*)&x[(size_t)s * DIM + d] = v;
}

// ---------------- RoPE cos/sin table: [s][i], i = freq idx 0..31 ----------------
__global__ __launch_bounds__(256) void k_rtab(float* __restrict__ ct,
                                              float* __restrict__ st) {
  int id = blockIdx.x * 256 + threadIdx.x;   // SEQ*32
  int i = id & 31;
  int s = id >> 5;
  float ang = (float)s * powf(10000.f, -(float)i * (1.f / 32.f));
  float sn, cs;
  sincosf(ang, &sn, &cs);
  ct[id] = cs;
  st[id] = sn;
}

// ------- layernorm (f32 in -> bf16 out), 4 rows/block, 1 wave per row -------
__global__ __launch_bounds__(256) void k_ln(const float* __restrict__ x,
                                            const float* __restrict__ sc,
                                            const float* __restrict__ bi,
                                            bf16_t* __restrict__ out) {
  int s = blockIdx.x * 4 + (threadIdx.x >> 6);
  int l = threadIdx.x & 63;
  const float* xr = x + (size_t)s * DIM;
  float4 v[4];
  float sum = 0.f, sq = 0.f;
#pragma unroll
  for (int i = 0; i < 4; ++i) {
    v[i] = *(const float4*)&xr[i * 256 + l * 4];
#pragma unroll
    for (int j = 0; j < 4; ++j) { sum += v[i][j]; sq += v[i][j] * v[i][j]; }
  }
#pragma unroll
  for (int d = 1; d < 64; d <<= 1) {
    sum += __shfl_xor(sum, d);
    sq  += __shfl_xor(sq, d);
  }
  float mean = sum * (1.f / DIM);
  float var  = sq * (1.f / DIM) - mean * mean;
  float inv  = rsqrtf(var + 1e-5f);
#pragma unroll
  for (int i = 0; i < 4; ++i) {
    int off = i * 256 + l * 4;
    float4 scv = *(const float4*)&sc[off];
    float4 biv = *(const float4*)&bi[off];
#pragma unroll
    for (int j = 0; j < 4; ++j) {
      float o = (v[i][j] - mean) * inv * scv[j] + biv[j];
      out[(size_t)s * DIM + off + j] = (bf16_t)o;
    }
  }
}

// ------- weight convert + transpose: src[K][N] f32 -> dst[...][K] bf16 -------
// imode 0: dst row = n. imode 1: w1 f -> (f>>4)*32+(f&15). imode 2: w3 -> +16.
__global__ __launch_bounds__(256) void k_cvt_t(const float* __restrict__ src,
                                               bf16_t* __restrict__ dst,
                                               int K_, int N_, int Npad_,
                                               size_t dstride, int imode) {
  __shared__ bf16_t T[64][66];
  const int k0 = blockIdx.y * 64;
  const int n0 = blockIdx.x * 64;
  const size_t so = (size_t)blockIdx.z * K_ * N_;
  const size_t dof = (size_t)blockIdx.z * dstride;
  const int t = threadIdx.x;
  const int kk = t >> 4;
  const int nn = (t & 15) * 4;
#pragma unroll
  for (int it = 0; it < 4; ++it) {
    int krow = kk + it * 16;
    float4 v = {0.f, 0.f, 0.f, 0.f};
    if (n0 + nn < N_) v = *(const float4*)&src[so + (size_t)(k0 + krow) * N_ + n0 + nn];
#pragma unroll
    for (int q = 0; q < 4; ++q) T[nn + q][krow] = (bf16_t)v[q];
  }
  __syncthreads();
#pragma unroll
  for (int it = 0; it < 4; ++it) {
    int c = it * 256 + t;
    int nr = c >> 4;
    int kc = (c & 15) * 4;
    int f = n0 + nr;
    int drow = (imode == 0) ? f : ((f >> 4) * 32 + ((imode == 2) ? 16 : 0) + (f & 15));
    ushort4 o = *(const ushort4*)&T[nr][kc];
    *(ushort4*)&dst[dof + (size_t)drow * K_ + k0 + kc] = o;
  }
}

// ---------------- GEMM: C[M,N] = A[M,K] * Bt[N][K], bf16 MFMA ----------------
// tile TM x TN, templated BK (64 or 128), 4 waves (2x2; each wave TM/2 x TN/2).
// XOR-swizzled staging generalized: CH=BK/8 chunks/row; stage key (w*RPI+l/CH)&
// (CH-1); reader key r16&(CH-1) (row offsets are multiples of CH so row&(CH-1)
// == r16&(CH-1)). LDS linear dest + pre-swizzled global source (rule-21 pair).
// OUTMODE 0: f32 store | 2: f32 += | 4: fused QKV(+RoPE) | 6: interleaved silu-gate
template <int TM, int TN, int BK, int OUTMODE>
__global__ __launch_bounds__(256) void k_gemm2(const bf16_t* __restrict__ A,
                                               const bf16_t* __restrict__ Bt,
                                               float* __restrict__ Cf,
                                               bf16_t* __restrict__ Cb,
                                               bf16_t* __restrict__ aux1,
                                               bf16_t* __restrict__ aux2,
                                               const float* __restrict__ ct,
                                               const float* __restrict__ st,
                                               int M, int N, int K) {
  constexpr int MI = TM / 32;            // A frags per wave
  constexpr int JN = TN / 32;            // B frags per wave
  constexpr int CH = BK / 8;             // 16B chunks per row
  constexpr int RPI = 64 / CH;           // rows per wave-issue
  constexpr int RPR = 4 * RPI;           // rows per issue-round (4 waves)
  constexpr int KK = BK / 32;            // mfma k-steps per tile
  __shared__ bf16_t As[TM * BK];
  __shared__ bf16_t Bs[TN * BK];
  const int t = threadIdx.x;
  const int w = t >> 6, l = t & 63;
  const int h = l >> 4, r16 = l & 15;
  const int m0 = blockIdx.y * TM, n0 = blockIdx.x * TN;
  const int wr = (w >> 1) * (TM / 2);
  const int wc = (w & 1) * (TN / 2);
  const int srl = l / CH;                // row within wave-issue slab
  const int scc = l % CH;                // chunk within row
  const int xch = (scc ^ ((w * RPI + srl) & (CH - 1))) * 8;   // pre-swizzled chunk
  const int sN  = r16 & (CH - 1);        // reader swizzle key

  f32x4 acc[MI][JN] = {};

  const bf16_t* pa = &A[(size_t)(m0 + w * RPI + srl) * K + xch];
  const bf16_t* pb = &Bt[(size_t)(n0 + w * RPI + srl) * K + xch];

  for (int k0 = 0; k0 < K; k0 += BK) {
#pragma unroll
    for (int i = 0; i < TM / RPR; ++i)
      gll16(pa + (size_t)i * RPR * K + k0, &As[(i * RPR + w * RPI) * BK]);
#pragma unroll
    for (int i = 0; i < TN / RPR; ++i)
      gll16(pb + (size_t)i * RPR * K + k0, &Bs[(i * RPR + w * RPI) * BK]);
    __syncthreads();
#pragma unroll
    for (int kk = 0; kk < KK; ++kk) {
      const int p = ((kk * 4 + h) ^ sN) * 8;   // swizzled read position (elems)
      bf16x8 af[MI], bfr[JN];
#pragma unroll
      for (int i = 0; i < MI; ++i)
        af[i] = *(const bf16x8*)&As[(wr + i * 16 + r16) * BK + p];
#pragma unroll
      for (int j = 0; j < JN; ++j)
        bfr[j] = *(const bf16x8*)&Bs[(wc + j * 16 + r16) * BK + p];
#pragma unroll
      for (int i = 0; i < MI; ++i)
#pragma unroll
        for (int j = 0; j < JN; ++j)
          acc[i][j] = __builtin_amdgcn_mfma_f32_16x16x32_bf16(af[i], bfr[j], acc[i][j], 0, 0, 0);
    }
    __syncthreads();
  }

  if constexpr (OUTMODE == 4) {
    const int reg = n0 >> 10;
    const int cbase = (n0 & 1023) + wc;
    if (reg == 2) {
#pragma unroll
      for (int i = 0; i < MI; ++i)
#pragma unroll
        for (int j = 0; j < JN; ++j)
#pragma unroll
          for (int r = 0; r < 4; ++r) {
            int row = m0 + wr + i * 16 + h * 4 + r;
            Cb[(size_t)row * DIM + cbase + j * 16 + r16] = (bf16_t)acc[i][j][r];
          }
    } else {
      bf16_t* dst = reg ? aux2 : aux1;
#pragma unroll
      for (int i = 0; i < MI; ++i)
#pragma unroll
        for (int r = 0; r < 4; ++r) {
          int row = m0 + wr + i * 16 + h * 4 + r;
          float c0 = ct[row * 32 + r16],      s0 = st[row * 32 + r16];
          float c1 = ct[row * 32 + 16 + r16], s1 = st[row * 32 + 16 + r16];
          float lo0 = acc[i][0][r], hi0 = acc[i][2][r];
          float lo1 = acc[i][1][r], hi1 = acc[i][3][r];
          size_t rb = (size_t)row * DIM + cbase;
          dst[rb + r16]      = (bf16_t)(lo0 * c0 - hi0 * s0);
          dst[rb + 32 + r16] = (bf16_t)(hi0 * c0 + lo0 * s0);
          dst[rb + 16 + r16] = (bf16_t)(lo1 * c1 - hi1 * s1);
          dst[rb + 48 + r16] = (bf16_t)(hi1 * c1 + lo1 * s1);
        }
    }
  } else if constexpr (OUTMODE == 6) {
    const int fbase = ((n0 + wc) >> 5) * 16;
#pragma unroll
    for (int i = 0; i < MI; ++i)
#pragma unroll
      for (int r = 0; r < 4; ++r) {
        int row = m0 + wr + i * 16 + h * 4 + r;
        float a0 = acc[i][0][r], b0 = acc[i][1][r];
        float a1 = acc[i][2][r], b1 = acc[i][3][r];
        float g0 = a0 / (1.f + expf(-a0)) * b0;
        float g1v = a1 / (1.f + expf(-a1)) * b1;
        size_t rb = (size_t)row * FF + fbase;
        aux1[rb + r16]      = (bf16_t)g0;
        aux1[rb + 16 + r16] = (bf16_t)g1v;
      }
  } else {
#pragma unroll
    for (int i = 0; i < MI; ++i)
#pragma unroll
      for (int j = 0; j < JN; ++j)
#pragma unroll
        for (int r = 0; r < 4; ++r) {
          int row = m0 + wr + i * 16 + h * 4 + r;
          int col = n0 + wc + j * 16 + r16;
          if (col < N) {
            float vv = acc[i][j][r];
            size_t idx = (size_t)row * N + col;
            if (OUTMODE == 0) Cf[idx] = vv;
            else Cf[idx] += vv;
          }
        }
  }
}

// ------- w13 GEMM: 256x256 tile, BK=64, 8 waves (2M x 4N), double-buffered LDS ----
// (round-12 version — best measured). Interleaved w1/w3 silu-gate epilogue.
__global__ __launch_bounds__(512, 1) void k_gemm256_gate(const bf16_t* __restrict__ A,
                                                         const bf16_t* __restrict__ Bt,
                                                         bf16_t* __restrict__ gate,
                                                         int K) {
  __shared__ bf16_t As[2][256 * 64];
  __shared__ bf16_t Bs[2][256 * 64];
  const int t = threadIdx.x;
  const int w = t >> 6, l = t & 63;
  const int h = l >> 4, r16 = l & 15;
  const int m0 = blockIdx.y * 256, n0 = blockIdx.x * 256;
  const int wr = (w >> 2) * 128;       // wave M offset: 0 or 128
  const int wc = (w & 3) * 64;         // wave N offset: 0,64,128,192
  const int sr = t >> 3;               // staging row within 64-row slab (0..63)
  const int xch = ((t & 7) ^ (sr & 7)) * 8;   // pre-swizzled k-chunk (elems)
  const int s7 = r16 & 7;

  f32x4 acc[8][4] = {};

  const bf16_t* pa = &A[(size_t)(m0 + sr) * K + xch];
  const bf16_t* pb = &Bt[(size_t)(n0 + sr) * K + xch];
  const int NT = K >> 6;

  auto STAGE = [&](int kt, int b) {
    const int k0 = kt << 6;
    bf16_t* baseA = &As[b][(w * 8) * 64];   // wave-uniform LDS base (+lane*16B)
    bf16_t* baseB = &Bs[b][(w * 8) * 64];
#pragma unroll
    for (int i = 0; i < 4; ++i) {
      gll16(pa + (size_t)(i * 64) * K + k0, baseA + i * 64 * 64);
      gll16(pb + (size_t)(i * 64) * K + k0, baseB + i * 64 * 64);
    }
  };

  STAGE(0, 0);
  asm volatile("s_waitcnt vmcnt(0)" ::: "memory");
  __builtin_amdgcn_s_barrier();
  __builtin_amdgcn_sched_barrier(0);

  int cur = 0;
  for (int tt = 0; tt < NT; ++tt) {
    if (tt + 1 < NT) STAGE(tt + 1, cur ^ 1);   // overlap with compute below
#pragma unroll
    for (int kk = 0; kk < 2; ++kk) {
      const int p = ((kk * 4 + h) ^ s7) * 8;
      bf16x8 af[8], bfr[4];
#pragma unroll
      for (int i = 0; i < 8; ++i)
        af[i] = *(const bf16x8*)&As[cur][(wr + i * 16 + r16) * 64 + p];
#pragma unroll
      for (int j = 0; j < 4; ++j)
        bfr[j] = *(const bf16x8*)&Bs[cur][(wc + j * 16 + r16) * 64 + p];
#pragma unroll
      for (int i = 0; i < 8; ++i)
#pragma unroll
        for (int j = 0; j < 4; ++j)
          acc[i][j] = __builtin_amdgcn_mfma_f32_16x16x32_bf16(af[i], bfr[j], acc[i][j], 0, 0, 0);
    }
    asm volatile("s_waitcnt vmcnt(0)" ::: "memory");   // next tile landed
    __builtin_amdgcn_s_barrier();
    __builtin_amdgcn_sched_barrier(0);
    cur ^= 1;
  }

  // interleaved silu-gate epilogue: j even = w1, j odd = w3 (same features)
  const int fbase = ((n0 + wc) >> 5) * 16;
#pragma unroll
  for (int i = 0; i < 8; ++i)
#pragma unroll
    for (int r = 0; r < 4; ++r) {
      int row = m0 + wr + i * 16 + h * 4 + r;
      float a0 = acc[i][0][r], b0 = acc[i][1][r];
      float a1 = acc[i][2][r], b1 = acc[i][3][r];
      float g0 = a0 / (1.f + expf(-a0)) * b0;
      float g1v = a1 / (1.f + expf(-a1)) * b1;
      size_t rb = (size_t)row * FF + fbase;
      gate[rb + r16]      = (bf16_t)g0;
      gate[rb + 16 + r16] = (bf16_t)g1v;
    }
}

// ------- flash attention: 4 waves/block, swapped-QK, one 64-row tile/block -------
// KVBLK=128 (round-18, best measured). 512 blocks (2/CU), complementary pairing.
// T14 async-STAGE: next chunk's loads issue into regs before chunk-t compute.
__global__ __launch_bounds__(256) void k_attn4(const bf16_t* __restrict__ qb,
                                               const bf16_t* __restrict__ kb,
                                               const bf16_t* __restrict__ vb,
                                               bf16_t* __restrict__ ao) {
  __shared__ bf16_t Ks[128][72];      // K chunk: [key][dh]
  __shared__ bf16_t Vt[64][136];      // V chunk transposed: [dh][key]
  __shared__ bf16_t Pl[4][16][136];   // per-wave P: [qrow][key]
  const int raw = blockIdx.x;         // 0..31
  const int head = blockIdx.y;        // 0..15
  const int qt = (head < 8) ? raw : (31 - raw);   // complementary per-CU pairing
  const int t = threadIdx.x;
  const int w = t >> 6, l = t & 63;
  const int h = l >> 4, r16 = l & 15;
  const size_t hoff = (size_t)head * HD;
  const int srow = t >> 1;            // 0..127 staging row (key)
  const int sc4  = (t & 1) * 4;       // which 4 of 8 dh-vectors

  const int q0 = qt * 64 + w * 16;    // this wave's first q row
  const int q_abs = q0 + r16;         // this lane's q row (softmax axis)

  bf16x8 aq[2];
#pragma unroll
  for (int c = 0; c < 2; ++c)
    aq[c] = *(const bf16x8*)&qb[(size_t)(q0 + r16) * DIM + hoff + c * 32 + h * 8];

  f32x4 o[4] = {};
  float mrun = -1e30f, lrun = 0.f;

  const int kend = qt * 64 + 63;

  // ---- preload chunk 0 into regs ----
  bf16x8 kreg[4], vreg[4];
#pragma unroll
  for (int it = 0; it < 4; ++it) {
    kreg[it] = *(const bf16x8*)&kb[(size_t)srow * DIM + hoff + (sc4 + it) * 8];
    vreg[it] = *(const bf16x8*)&vb[(size_t)srow * DIM + hoff + (sc4 + it) * 8];
  }

  for (int k0 = 0; k0 <= kend; k0 += 128) {
    // ---- write staged regs to LDS: K direct, V transposed ----
#pragma unroll
    for (int it = 0; it < 4; ++it)
      *(bf16x8*)&Ks[srow][(sc4 + it) * 8] = kreg[it];
#pragma unroll
    for (int it = 0; it < 4; ++it)
#pragma unroll
      for (int j = 0; j < 8; ++j) Vt[(sc4 + it) * 8 + j][srow] = vreg[it][j];
    __syncthreads();

    // ---- issue next chunk's global loads (overlap with compute below) ----
    if (k0 + 128 <= kend) {
      const size_t nb = (size_t)(k0 + 128 + srow) * DIM + hoff;
#pragma unroll
      for (int it = 0; it < 4; ++it) {
        kreg[it] = *(const bf16x8*)&kb[nb + (sc4 + it) * 8];
        vreg[it] = *(const bf16x8*)&vb[nb + (sc4 + it) * 8];
      }
    }

    if (k0 <= q0 + 15) {              // wave-uniform: skip fully-masked chunks
      // ---- scores transposed: D[key][q], 8 col-tiles of 16 keys ----
      f32x4 sc[8];
      __builtin_amdgcn_s_setprio(1);
#pragma unroll
      for (int tc = 0; tc < 8; ++tc) {
        f32x4 z = {};
        bf16x8 a0 = *(const bf16x8*)&Ks[tc * 16 + r16][h * 8];
        bf16x8 a1 = *(const bf16x8*)&Ks[tc * 16 + r16][32 + h * 8];
        z = __builtin_amdgcn_mfma_f32_16x16x32_bf16(a0, aq[0], z, 0, 0, 0);
        z = __builtin_amdgcn_mfma_f32_16x16x32_bf16(a1, aq[1], z, 0, 0, 0);
        sc[tc] = z;
      }
      __builtin_amdgcn_s_setprio(0);
      // ---- mask + scale; per-lane max over 32 keys ----
      float pmax = -1e30f;
#pragma unroll
      for (int tc = 0; tc < 8; ++tc)
#pragma unroll
        for (int r = 0; r < 4; ++r) {
          int key = k0 + tc * 16 + h * 4 + r;
          float v = sc[tc][r] * 0.125f;
          if (key > q_abs) v = -1e30f;
          sc[tc][r] = v;
          pmax = fmaxf(pmax, v);
        }
      pmax = fmaxf(pmax, __shfl_xor(pmax, 16));
      pmax = fmaxf(pmax, __shfl_xor(pmax, 32));
      float mnew = fmaxf(mrun, pmax);
      float alpha = expf(mrun - mnew);
      mrun = mnew;
      float ssum = 0.f;
#pragma unroll
      for (int tc = 0; tc < 8; ++tc)
#pragma unroll
        for (int r = 0; r < 4; ++r) {
          float pv = expf(sc[tc][r] - mnew);
          sc[tc][r] = pv;
          ssum += pv;
        }
      ssum += __shfl_xor(ssum, 16);
      ssum += __shfl_xor(ssum, 32);
      lrun = lrun * alpha + ssum;
      // ---- write P^T to LDS: Pl[q][key] ----
#pragma unroll
      for (int tc = 0; tc < 8; ++tc)
#pragma unroll
        for (int r = 0; r < 4; ++r)
          Pl[w][r16][tc * 16 + h * 4 + r] = (bf16_t)sc[tc][r];
      // ---- rescale o: alpha for o-row q=h*4+r lives in lane h*4+r ----
      float ar[4];
#pragma unroll
      for (int r = 0; r < 4; ++r) ar[r] = __shfl(alpha, h * 4 + r);
#pragma unroll
      for (int cti = 0; cti < 4; ++cti)
#pragma unroll
        for (int r = 0; r < 4; ++r) o[cti][r] *= ar[r];
      // ---- PV: 4 k-slices of 32 keys ----
      __builtin_amdgcn_s_setprio(1);
#pragma unroll
      for (int ks = 0; ks < 4; ++ks) {
        bf16x8 pk = *(const bf16x8*)&Pl[w][r16][ks * 32 + h * 8];
#pragma unroll
        for (int cti = 0; cti < 4; ++cti) {
          bf16x8 vv = *(const bf16x8*)&Vt[cti * 16 + r16][ks * 32 + h * 8];
          o[cti] = __builtin_amdgcn_mfma_f32_16x16x32_bf16(pk, vv, o[cti], 0, 0, 0);
        }
      }
      __builtin_amdgcn_s_setprio(0);
    }
    __syncthreads();
  }
  float lr[4];
#pragma unroll
  for (int r = 0; r < 4; ++r) lr[r] = __shfl(lrun, h * 4 + r);
#pragma unroll
  for (int cti = 0; cti < 4; ++cti)
#pragma unroll
    for (int r = 0; r < 4; ++r) {
      int row = q0 + h * 4 + r;
      ao[(size_t)row * DIM + hoff + cti * 16 + r16] = (bf16_t)(o[cti][r] / lr[r]);
    }
}

extern "C" void kernel_launch(void* const* d_in, const int* in_sizes, int n_in,
                              void* d_out, int out_size, void* d_ws, size_t ws_size,
                              hipStream_t stream) {
  const int*   ids  = (const int*)d_in[0];
  const float* temb = (const float*)d_in[1];
  const float* Wq   = (const float*)d_in[2];
  const float* Wk   = (const float*)d_in[3];
  const float* Wv   = (const float*)d_in[4];
  const float* Wo   = (const float*)d_in[5];
  const float* ln1s = (const float*)d_in[6];
  const float* ln1b = (const float*)d_in[7];
  const float* ln2s = (const float*)d_in[8];
  const float* ln2b = (const float*)d_in[9];
  const float* w1   = (const float*)d_in[10];
  const float* w2   = (const float*)d_in[11];
  const float* w3   = (const float*)d_in[12];
  const float* lnfs = (const float*)d_in[13];
  const float* lnfb = (const float*)d_in[14];
  const float* lmh  = (const float*)d_in[15];
  float* out = (float*)d_out;

  char* p = (char*)d_ws;
  size_t used = 0;
  auto alloc = [&](size_t bytes) {
    void* r = (void*)p;
    size_t a = (bytes + 255) & ~(size_t)255;
    p += a; used += a;
    return r;
  };
  // activations + tables
  float*  x     = (float*)alloc((size_t)SEQ * DIM * 4);
  bf16_t* hb    = (bf16_t*)alloc((size_t)SEQ * DIM * 2);
  bf16_t* qb2   = (bf16_t*)alloc((size_t)SEQ * DIM * 2);
  bf16_t* kb2   = (bf16_t*)alloc((size_t)SEQ * DIM * 2);
  bf16_t* vb2   = (bf16_t*)alloc((size_t)SEQ * DIM * 2);
  bf16_t* aob   = (bf16_t*)alloc((size_t)SEQ * DIM * 2);
  bf16_t* gateb = (bf16_t*)alloc((size_t)SEQ * FF * 2);
  float*  ctab  = (float*)alloc((size_t)SEQ * 32 * 4);
  float*  stab  = (float*)alloc((size_t)SEQ * 32 * 4);

  const size_t szDD = (size_t)DIM * DIM;    // 1M elems
  const size_t szDF = (size_t)DIM * FF;     // 4M elems
  const size_t wt_bytes = ((size_t)NL * (3 * szDD + szDD + 2 * szDF + szDF) + (size_t)VOCP * DIM) * 2;
  const bool bigws = (ws_size >= used + wt_bytes + (1u << 20));

  bf16_t *bQKV, *bWo, *bW13, *bw2, *blm, *wscratch = nullptr;
  if (bigws) {
    bQKV = (bf16_t*)alloc(NL * 3 * szDD * 2);
    bWo  = (bf16_t*)alloc(NL * szDD * 2);
    bW13 = (bf16_t*)alloc(NL * 2 * szDF * 2);
    bw2  = (bf16_t*)alloc(NL * szDF * 2);
    blm  = (bf16_t*)alloc((size_t)VOCP * DIM * 2);
  } else {
    wscratch = (bf16_t*)alloc(2 * szDF * 2);   // enough for fused w13 of one layer
    bQKV = bWo = bW13 = bw2 = blm = wscratch;
  }

  auto cvt = [&](const float* src, bf16_t* dst, int K_, int N_, int Npad_, int nz,
                 size_t dstride, int imode) {
    dim3 g(Npad_ / 64, K_ / 64, nz);
    k_cvt_t<<<g, 256, 0, stream>>>(src, dst, K_, N_, Npad_, dstride, imode);
  };

  if (bigws) {
    cvt(Wq, bQKV,             DIM, DIM, DIM, NL, 3 * szDD, 0);
    cvt(Wk, bQKV + szDD,      DIM, DIM, DIM, NL, 3 * szDD, 0);
    cvt(Wv, bQKV + 2 * szDD,  DIM, DIM, DIM, NL, 3 * szDD, 0);
    cvt(Wo, bWo,              DIM, DIM, DIM, NL, szDD, 0);
    cvt(w1, bW13,             DIM, FF,  FF,  NL, 2 * szDF, 1);   // interleaved even
    cvt(w3, bW13,             DIM, FF,  FF,  NL, 2 * szDF, 2);   // interleaved odd
    cvt(w2, bw2,              FF,  DIM, DIM, NL, szDF, 0);
    cvt(lmh, blm,             DIM, VOC, VOCP, 1, 0, 0);
  }
  auto wpQKV = [&](int lyr) -> bf16_t* {
    if (bigws) return bQKV + (size_t)lyr * 3 * szDD;
    cvt(Wq + (size_t)lyr * szDD, wscratch,            DIM, DIM, DIM, 1, 0, 0);
    cvt(Wk + (size_t)lyr * szDD, wscratch + szDD,     DIM, DIM, DIM, 1, 0, 0);
    cvt(Wv + (size_t)lyr * szDD, wscratch + 2 * szDD, DIM, DIM, DIM, 1, 0, 0);
    return wscratch;
  };
  auto wpW13 = [&](int lyr) -> bf16_t* {
    if (bigws) return bW13 + (size_t)lyr * 2 * szDF;
    cvt(w1 + (size_t)lyr * szDF, wscratch, DIM, FF, FF, 1, 0, 1);
    cvt(w3 + (size_t)lyr * szDF, wscratch, DIM, FF, FF, 1, 0, 2);
    return wscratch;
  };
  auto wp1 = [&](bf16_t* big, const float* src, int lyr, int K_, int N_, int Npad_) -> bf16_t* {
    if (bigws) return big + (size_t)lyr * Npad_ * K_;
    cvt(src + (size_t)lyr * K_ * N_, wscratch, K_, N_, Npad_, 1, 0, 0);
    return wscratch;
  };

  k_rtab<<<(SEQ * 32) / 256, 256, 0, stream>>>(ctab, stab);
  k_embed<<<SEQ, 256, 0, stream>>>(ids, temb, x);

  dim3 gQKV(3 * DIM / 128, SEQ / 64);    // 24 x 32 = 768 (3/CU, 64x128 tiles)
  dim3 gDD(DIM / 64, SEQ / 64);          // 16 x 32 = 512 (2/CU, 64x64 tiles)
  dim3 gW13(2 * FF / 256, SEQ / 256);    // 32 x 8 = 256 (1/CU, 256^2 dbuf kernel)
  dim3 gLM(VOCP / 64, SEQ / 64);         // 22 x 32 = 704
  dim3 gAt(32, NH);                      // 32 tiles x 16 heads = 512 (2/CU)

  for (int l = 0; l < NL; ++l) {
    k_ln<<<SEQ / 4, 256, 0, stream>>>(x, ln1s + (size_t)l * DIM, ln1b + (size_t)l * DIM, hb);
    k_gemm2<64, 128, 128, 4><<<gQKV, 256, 0, stream>>>(hb, wpQKV(l), nullptr, vb2, qb2, kb2,
                                                       ctab, stab, SEQ, 3 * DIM, DIM);
    k_attn4<<<gAt, 256, 0, stream>>>(qb2, kb2, vb2, aob);
    k_gemm2<64, 64, 128, 2><<<gDD, 256, 0, stream>>>(aob, wp1(bWo, Wo, l, DIM, DIM, DIM), x, nullptr,
                                                     nullptr, nullptr, nullptr, nullptr, SEQ, DIM, DIM);
    k_ln<<<SEQ / 4, 256, 0, stream>>>(x, ln2s + (size_t)l * DIM, ln2b + (size_t)l * DIM, hb);
    k_gemm256_gate<<<gW13, 512, 0, stream>>>(hb, wpW13(l), gateb, DIM);
    k_gemm2<64, 64, 128, 2><<<gDD, 256, 0, stream>>>(gateb, wp1(bw2, w2, l, FF, DIM, DIM), x, nullptr,
                                                     nullptr, nullptr, nullptr, nullptr, SEQ, DIM, FF);
  }
  k_ln<<<SEQ / 4, 256, 0, stream>>>(x, lnfs, lnfb, hb);
  k_gemm2<64, 64, 128, 0><<<gLM, 256, 0, stream>>>(hb, bigws ? blm : wp1(blm, lmh, 0, DIM, VOC, VOCP),
                                                   out, nullptr, nullptr, nullptr, nullptr, nullptr,
                                                   SEQ, VOC, DIM);
}

// Round 20
// 2431.743 us; speedup vs baseline: 1.3911x; 1.0017x over previous
//
#include <hip/hip_runtime.h>
#include <math.h>

// ---- problem constants ----
constexpr int SEQ = 2048;
constexpr int DIM = 1024;
constexpr int NH  = 16;
constexpr int HD  = 64;
constexpr int FF  = 4096;
constexpr int NL  = 12;
constexpr int VOC = 1400;
constexpr int VOCP = 1408;   // padded to 64

typedef __bf16 bf16_t;
typedef __bf16 bf16x8 __attribute__((ext_vector_type(8)));
typedef float  f32x4  __attribute__((ext_vector_type(4)));

typedef __attribute__((address_space(1))) const void GV;
typedef __attribute__((address_space(3))) void LV;

__device__ __forceinline__ void gll16(const bf16_t* g, bf16_t* l) {
  __builtin_amdgcn_global_load_lds((GV*)g, (LV*)l, 16, 0, 0);
}

// ---------------- embedding gather ----------------
__global__ __launch_bounds__(256) void k_embed(const int* __restrict__ ids,
                                               const float* __restrict__ emb,
                                               float* __restrict__ x) {
  int s = blockIdx.x;
  int d = threadIdx.x * 4;
  const float4 v = *(const float4*)&emb[(size_t)ids[s] * DIM + d];
  *(float4*)&x[(size_t)s * DIM + d] = v;
}

// ---------------- RoPE cos/sin table: [s][i], i = freq idx 0..31 ----------------
__global__ __launch_bounds__(256) void k_rtab(float* __restrict__ ct,
                                              float* __restrict__ st) {
  int id = blockIdx.x * 256 + threadIdx.x;   // SEQ*32
  int i = id & 31;
  int s = id >> 5;
  float ang = (float)s * powf(10000.f, -(float)i * (1.f / 32.f));
  float sn, cs;
  sincosf(ang, &sn, &cs);
  ct[id] = cs;
  st[id] = sn;
}

// ------- layernorm (f32 in -> bf16 out), 4 rows/block, 1 wave per row -------
__global__ __launch_bounds__(256) void k_ln(const float* __restrict__ x,
                                            const float* __restrict__ sc,
                                            const float* __restrict__ bi,
                                            bf16_t* __restrict__ out) {
  int s = blockIdx.x * 4 + (threadIdx.x >> 6);
  int l = threadIdx.x & 63;
  const float* xr = x + (size_t)s * DIM;
  float4 v[4];
  float sum = 0.f, sq = 0.f;
#pragma unroll
  for (int i = 0; i < 4; ++i) {
    v[i] = *(const float4*)&xr[i * 256 + l * 4];
#pragma unroll
    for (int j = 0; j < 4; ++j) { sum += v[i][j]; sq += v[i][j] * v[i][j]; }
  }
#pragma unroll
  for (int d = 1; d < 64; d <<= 1) {
    sum += __shfl_xor(sum, d);
    sq  += __shfl_xor(sq, d);
  }
  float mean = sum * (1.f / DIM);
  float var  = sq * (1.f / DIM) - mean * mean;
  float inv  = rsqrtf(var + 1e-5f);
#pragma unroll
  for (int i = 0; i < 4; ++i) {
    int off = i * 256 + l * 4;
    float4 scv = *(const float4*)&sc[off];
    float4 biv = *(const float4*)&bi[off];
#pragma unroll
    for (int j = 0; j < 4; ++j) {
      float o = (v[i][j] - mean) * inv * scv[j] + biv[j];
      out[(size_t)s * DIM + off + j] = (bf16_t)o;
    }
  }
}

// ------- weight convert + transpose: src[K][N] f32 -> dst[...][K] bf16 -------
// imode 0: dst row = n. imode 1: w1 f -> (f>>4)*32+(f&15). imode 2: w3 -> +16.
__global__ __launch_bounds__(256) void k_cvt_t(const float* __restrict__ src,
                                               bf16_t* __restrict__ dst,
                                               int K_, int N_, int Npad_,
                                               size_t dstride, int imode) {
  __shared__ bf16_t T[64][66];
  const int k0 = blockIdx.y * 64;
  const int n0 = blockIdx.x * 64;
  const size_t so = (size_t)blockIdx.z * K_ * N_;
  const size_t dof = (size_t)blockIdx.z * dstride;
  const int t = threadIdx.x;
  const int kk = t >> 4;
  const int nn = (t & 15) * 4;
#pragma unroll
  for (int it = 0; it < 4; ++it) {
    int krow = kk + it * 16;
    float4 v = {0.f, 0.f, 0.f, 0.f};
    if (n0 + nn < N_) v = *(const float4*)&src[so + (size_t)(k0 + krow) * N_ + n0 + nn];
#pragma unroll
    for (int q = 0; q < 4; ++q) T[nn + q][krow] = (bf16_t)v[q];
  }
  __syncthreads();
#pragma unroll
  for (int it = 0; it < 4; ++it) {
    int c = it * 256 + t;
    int nr = c >> 4;
    int kc = (c & 15) * 4;
    int f = n0 + nr;
    int drow = (imode == 0) ? f : ((f >> 4) * 32 + ((imode == 2) ? 16 : 0) + (f & 15));
    ushort4 o = *(const ushort4*)&T[nr][kc];
    *(ushort4*)&dst[dof + (size_t)drow * K_ + k0 + kc] = o;
  }
}

// ---------------- GEMM: C[M,N] = A[M,K] * Bt[N][K], bf16 MFMA ----------------
// tile TM x TN, templated BK (64 or 128), 4 waves (2x2; each wave TM/2 x TN/2).
// XOR-swizzled staging generalized: CH=BK/8 chunks/row; stage key (w*RPI+l/CH)&
// (CH-1); reader key r16&(CH-1) (row offsets are multiples of CH so row&(CH-1)
// == r16&(CH-1)). LDS linear dest + pre-swizzled global source (rule-21 pair).
// OUTMODE 0: f32 store | 2: f32 += | 4: fused QKV(+RoPE) | 6: interleaved silu-gate
template <int TM, int TN, int BK, int OUTMODE>
__global__ __launch_bounds__(256) void k_gemm2(const bf16_t* __restrict__ A,
                                               const bf16_t* __restrict__ Bt,
                                               float* __restrict__ Cf,
                                               bf16_t* __restrict__ Cb,
                                               bf16_t* __restrict__ aux1,
                                               bf16_t* __restrict__ aux2,
                                               const float* __restrict__ ct,
                                               const float* __restrict__ st,
                                               int M, int N, int K) {
  constexpr int MI = TM / 32;            // A frags per wave
  constexpr int JN = TN / 32;            // B frags per wave
  constexpr int CH = BK / 8;             // 16B chunks per row
  constexpr int RPI = 64 / CH;           // rows per wave-issue
  constexpr int RPR = 4 * RPI;           // rows per issue-round (4 waves)
  constexpr int KK = BK / 32;            // mfma k-steps per tile
  __shared__ bf16_t As[TM * BK];
  __shared__ bf16_t Bs[TN * BK];
  const int t = threadIdx.x;
  const int w = t >> 6, l = t & 63;
  const int h = l >> 4, r16 = l & 15;
  const int m0 = blockIdx.y * TM, n0 = blockIdx.x * TN;
  const int wr = (w >> 1) * (TM / 2);
  const int wc = (w & 1) * (TN / 2);
  const int srl = l / CH;                // row within wave-issue slab
  const int scc = l % CH;                // chunk within row
  const int xch = (scc ^ ((w * RPI + srl) & (CH - 1))) * 8;   // pre-swizzled chunk
  const int sN  = r16 & (CH - 1);        // reader swizzle key

  f32x4 acc[MI][JN] = {};

  const bf16_t* pa = &A[(size_t)(m0 + w * RPI + srl) * K + xch];
  const bf16_t* pb = &Bt[(size_t)(n0 + w * RPI + srl) * K + xch];

  for (int k0 = 0; k0 < K; k0 += BK) {
#pragma unroll
    for (int i = 0; i < TM / RPR; ++i)
      gll16(pa + (size_t)i * RPR * K + k0, &As[(i * RPR + w * RPI) * BK]);
#pragma unroll
    for (int i = 0; i < TN / RPR; ++i)
      gll16(pb + (size_t)i * RPR * K + k0, &Bs[(i * RPR + w * RPI) * BK]);
    __syncthreads();
#pragma unroll
    for (int kk = 0; kk < KK; ++kk) {
      const int p = ((kk * 4 + h) ^ sN) * 8;   // swizzled read position (elems)
      bf16x8 af[MI], bfr[JN];
#pragma unroll
      for (int i = 0; i < MI; ++i)
        af[i] = *(const bf16x8*)&As[(wr + i * 16 + r16) * BK + p];
#pragma unroll
      for (int j = 0; j < JN; ++j)
        bfr[j] = *(const bf16x8*)&Bs[(wc + j * 16 + r16) * BK + p];
#pragma unroll
      for (int i = 0; i < MI; ++i)
#pragma unroll
        for (int j = 0; j < JN; ++j)
          acc[i][j] = __builtin_amdgcn_mfma_f32_16x16x32_bf16(af[i], bfr[j], acc[i][j], 0, 0, 0);
    }
    __syncthreads();
  }

  if constexpr (OUTMODE == 4) {
    const int reg = n0 >> 10;
    const int cbase = (n0 & 1023) + wc;
    if (reg == 2) {
#pragma unroll
      for (int i = 0; i < MI; ++i)
#pragma unroll
        for (int j = 0; j < JN; ++j)
#pragma unroll
          for (int r = 0; r < 4; ++r) {
            int row = m0 + wr + i * 16 + h * 4 + r;
            Cb[(size_t)row * DIM + cbase + j * 16 + r16] = (bf16_t)acc[i][j][r];
          }
    } else {
      bf16_t* dst = reg ? aux2 : aux1;
#pragma unroll
      for (int i = 0; i < MI; ++i)
#pragma unroll
        for (int r = 0; r < 4; ++r) {
          int row = m0 + wr + i * 16 + h * 4 + r;
          float c0 = ct[row * 32 + r16],      s0 = st[row * 32 + r16];
          float c1 = ct[row * 32 + 16 + r16], s1 = st[row * 32 + 16 + r16];
          float lo0 = acc[i][0][r], hi0 = acc[i][2][r];
          float lo1 = acc[i][1][r], hi1 = acc[i][3][r];
          size_t rb = (size_t)row * DIM + cbase;
          dst[rb + r16]      = (bf16_t)(lo0 * c0 - hi0 * s0);
          dst[rb + 32 + r16] = (bf16_t)(hi0 * c0 + lo0 * s0);
          dst[rb + 16 + r16] = (bf16_t)(lo1 * c1 - hi1 * s1);
          dst[rb + 48 + r16] = (bf16_t)(hi1 * c1 + lo1 * s1);
        }
    }
  } else if constexpr (OUTMODE == 6) {
    const int fbase = ((n0 + wc) >> 5) * 16;
#pragma unroll
    for (int i = 0; i < MI; ++i)
#pragma unroll
      for (int r = 0; r < 4; ++r) {
        int row = m0 + wr + i * 16 + h * 4 + r;
        float a0 = acc[i][0][r], b0 = acc[i][1][r];
        float a1 = acc[i][2][r], b1 = acc[i][3][r];
        float g0 = a0 / (1.f + expf(-a0)) * b0;
        float g1v = a1 / (1.f + expf(-a1)) * b1;
        size_t rb = (size_t)row * FF + fbase;
        aux1[rb + r16]      = (bf16_t)g0;
        aux1[rb + 16 + r16] = (bf16_t)g1v;
      }
  } else {
#pragma unroll
    for (int i = 0; i < MI; ++i)
#pragma unroll
      for (int j = 0; j < JN; ++j)
#pragma unroll
        for (int r = 0; r < 4; ++r) {
          int row = m0 + wr + i * 16 + h * 4 + r;
          int col = n0 + wc + j * 16 + r16;
          if (col < N) {
            float vv = acc[i][j][r];
            size_t idx = (size_t)row * N + col;
            if (OUTMODE == 0) Cf[idx] = vv;
            else Cf[idx] += vv;
          }
        }
  }
}

// ------- flash attention: 4 waves/block, swapped-QK, one 64-row tile/block -------
// KVBLK=128 (round-18, best measured). 512 blocks (2/CU), complementary pairing.
// T14 async-STAGE: next chunk's loads issue into regs before chunk-t compute.
__global__ __launch_bounds__(256) void k_attn4(const bf16_t* __restrict__ qb,
                                               const bf16_t* __restrict__ kb,
                                               const bf16_t* __restrict__ vb,
                                               bf16_t* __restrict__ ao) {
  __shared__ bf16_t Ks[128][72];      // K chunk: [key][dh]
  __shared__ bf16_t Vt[64][136];      // V chunk transposed: [dh][key]
  __shared__ bf16_t Pl[4][16][136];   // per-wave P: [qrow][key]
  const int raw = blockIdx.x;         // 0..31
  const int head = blockIdx.y;        // 0..15
  const int qt = (head < 8) ? raw : (31 - raw);   // complementary per-CU pairing
  const int t = threadIdx.x;
  const int w = t >> 6, l = t & 63;
  const int h = l >> 4, r16 = l & 15;
  const size_t hoff = (size_t)head * HD;
  const int srow = t >> 1;            // 0..127 staging row (key)
  const int sc4  = (t & 1) * 4;       // which 4 of 8 dh-vectors

  const int q0 = qt * 64 + w * 16;    // this wave's first q row
  const int q_abs = q0 + r16;         // this lane's q row (softmax axis)

  bf16x8 aq[2];
#pragma unroll
  for (int c = 0; c < 2; ++c)
    aq[c] = *(const bf16x8*)&qb[(size_t)(q0 + r16) * DIM + hoff + c * 32 + h * 8];

  f32x4 o[4] = {};
  float mrun = -1e30f, lrun = 0.f;

  const int kend = qt * 64 + 63;

  // ---- preload chunk 0 into regs ----
  bf16x8 kreg[4], vreg[4];
#pragma unroll
  for (int it = 0; it < 4; ++it) {
    kreg[it] = *(const bf16x8*)&kb[(size_t)srow * DIM + hoff + (sc4 + it) * 8];
    vreg[it] = *(const bf16x8*)&vb[(size_t)srow * DIM + hoff + (sc4 + it) * 8];
  }

  for (int k0 = 0; k0 <= kend; k0 += 128) {
    // ---- write staged regs to LDS: K direct, V transposed ----
#pragma unroll
    for (int it = 0; it < 4; ++it)
      *(bf16x8*)&Ks[srow][(sc4 + it) * 8] = kreg[it];
#pragma unroll
    for (int it = 0; it < 4; ++it)
#pragma unroll
      for (int j = 0; j < 8; ++j) Vt[(sc4 + it) * 8 + j][srow] = vreg[it][j];
    __syncthreads();

    // ---- issue next chunk's global loads (overlap with compute below) ----
    if (k0 + 128 <= kend) {
      const size_t nb = (size_t)(k0 + 128 + srow) * DIM + hoff;
#pragma unroll
      for (int it = 0; it < 4; ++it) {
        kreg[it] = *(const bf16x8*)&kb[nb + (sc4 + it) * 8];
        vreg[it] = *(const bf16x8*)&vb[nb + (sc4 + it) * 8];
      }
    }

    if (k0 <= q0 + 15) {              // wave-uniform: skip fully-masked chunks
      // ---- scores transposed: D[key][q], 8 col-tiles of 16 keys ----
      f32x4 sc[8];
      __builtin_amdgcn_s_setprio(1);
#pragma unroll
      for (int tc = 0; tc < 8; ++tc) {
        f32x4 z = {};
        bf16x8 a0 = *(const bf16x8*)&Ks[tc * 16 + r16][h * 8];
        bf16x8 a1 = *(const bf16x8*)&Ks[tc * 16 + r16][32 + h * 8];
        z = __builtin_amdgcn_mfma_f32_16x16x32_bf16(a0, aq[0], z, 0, 0, 0);
        z = __builtin_amdgcn_mfma_f32_16x16x32_bf16(a1, aq[1], z, 0, 0, 0);
        sc[tc] = z;
      }
      __builtin_amdgcn_s_setprio(0);
      // ---- mask + scale; per-lane max over 32 keys ----
      float pmax = -1e30f;
#pragma unroll
      for (int tc = 0; tc < 8; ++tc)
#pragma unroll
        for (int r = 0; r < 4; ++r) {
          int key = k0 + tc * 16 + h * 4 + r;
          float v = sc[tc][r] * 0.125f;
          if (key > q_abs) v = -1e30f;
          sc[tc][r] = v;
          pmax = fmaxf(pmax, v);
        }
      pmax = fmaxf(pmax, __shfl_xor(pmax, 16));
      pmax = fmaxf(pmax, __shfl_xor(pmax, 32));
      float mnew = fmaxf(mrun, pmax);
      float alpha = expf(mrun - mnew);
      mrun = mnew;
      float ssum = 0.f;
#pragma unroll
      for (int tc = 0; tc < 8; ++tc)
#pragma unroll
        for (int r = 0; r < 4; ++r) {
          float pv = expf(sc[tc][r] - mnew);
          sc[tc][r] = pv;
          ssum += pv;
        }
      ssum += __shfl_xor(ssum, 16);
      ssum += __shfl_xor(ssum, 32);
      lrun = lrun * alpha + ssum;
      // ---- write P^T to LDS: Pl[q][key] ----
#pragma unroll
      for (int tc = 0; tc < 8; ++tc)
#pragma unroll
        for (int r = 0; r < 4; ++r)
          Pl[w][r16][tc * 16 + h * 4 + r] = (bf16_t)sc[tc][r];
      // ---- rescale o: alpha for o-row q=h*4+r lives in lane h*4+r ----
      float ar[4];
#pragma unroll
      for (int r = 0; r < 4; ++r) ar[r] = __shfl(alpha, h * 4 + r);
#pragma unroll
      for (int cti = 0; cti < 4; ++cti)
#pragma unroll
        for (int r = 0; r < 4; ++r) o[cti][r] *= ar[r];
      // ---- PV: 4 k-slices of 32 keys ----
      __builtin_amdgcn_s_setprio(1);
#pragma unroll
      for (int ks = 0; ks < 4; ++ks) {
        bf16x8 pk = *(const bf16x8*)&Pl[w][r16][ks * 32 + h * 8];
#pragma unroll
        for (int cti = 0; cti < 4; ++cti) {
          bf16x8 vv = *(const bf16x8*)&Vt[cti * 16 + r16][ks * 32 + h * 8];
          o[cti] = __builtin_amdgcn_mfma_f32_16x16x32_bf16(pk, vv, o[cti], 0, 0, 0);
        }
      }
      __builtin_amdgcn_s_setprio(0);
    }
    __syncthreads();
  }
  float lr[4];
#pragma unroll
  for (int r = 0; r < 4; ++r) lr[r] = __shfl(lrun, h * 4 + r);
#pragma unroll
  for (int cti = 0; cti < 4; ++cti)
#pragma unroll
    for (int r = 0; r < 4; ++r) {
      int row = q0 + h * 4 + r;
      ao[(size_t)row * DIM + hoff + cti * 16 + r16] = (bf16_t)(o[cti][r] / lr[r]);
    }
}

extern "C" void kernel_launch(void* const* d_in, const int* in_sizes, int n_in,
                              void* d_out, int out_size, void* d_ws, size_t ws_size,
                              hipStream_t stream) {
  const int*   ids  = (const int*)d_in[0];
  const float* temb = (const float*)d_in[1];
  const float* Wq   = (const float*)d_in[2];
  const float* Wk   = (const float*)d_in[3];
  const float* Wv   = (const float*)d_in[4];
  const float* Wo   = (const float*)d_in[5];
  const float* ln1s = (const float*)d_in[6];
  const float* ln1b = (const float*)d_in[7];
  const float* ln2s = (const float*)d_in[8];
  const float* ln2b = (const float*)d_in[9];
  const float* w1   = (const float*)d_in[10];
  const float* w2   = (const float*)d_in[11];
  const float* w3   = (const float*)d_in[12];
  const float* lnfs = (const float*)d_in[13];
  const float* lnfb = (const float*)d_in[14];
  const float* lmh  = (const float*)d_in[15];
  float* out = (float*)d_out;

  char* p = (char*)d_ws;
  size_t used = 0;
  auto alloc = [&](size_t bytes) {
    void* r = (void*)p;
    size_t a = (bytes + 255) & ~(size_t)255;
    p += a; used += a;
    return r;
  };
  // activations + tables
  float*  x     = (float*)alloc((size_t)SEQ * DIM * 4);
  bf16_t* hb    = (bf16_t*)alloc((size_t)SEQ * DIM * 2);
  bf16_t* qb2   = (bf16_t*)alloc((size_t)SEQ * DIM * 2);
  bf16_t* kb2   = (bf16_t*)alloc((size_t)SEQ * DIM * 2);
  bf16_t* vb2   = (bf16_t*)alloc((size_t)SEQ * DIM * 2);
  bf16_t* aob   = (bf16_t*)alloc((size_t)SEQ * DIM * 2);
  bf16_t* gateb = (bf16_t*)alloc((size_t)SEQ * FF * 2);
  float*  ctab  = (float*)alloc((size_t)SEQ * 32 * 4);
  float*  stab  = (float*)alloc((size_t)SEQ * 32 * 4);

  const size_t szDD = (size_t)DIM * DIM;    // 1M elems
  const size_t szDF = (size_t)DIM * FF;     // 4M elems
  const size_t wt_bytes = ((size_t)NL * (3 * szDD + szDD + 2 * szDF + szDF) + (size_t)VOCP * DIM) * 2;
  const bool bigws = (ws_size >= used + wt_bytes + (1u << 20));

  bf16_t *bQKV, *bWo, *bW13, *bw2, *blm, *wscratch = nullptr;
  if (bigws) {
    bQKV = (bf16_t*)alloc(NL * 3 * szDD * 2);
    bWo  = (bf16_t*)alloc(NL * szDD * 2);
    bW13 = (bf16_t*)alloc(NL * 2 * szDF * 2);
    bw2  = (bf16_t*)alloc(NL * szDF * 2);
    blm  = (bf16_t*)alloc((size_t)VOCP * DIM * 2);
  } else {
    wscratch = (bf16_t*)alloc(2 * szDF * 2);   // enough for fused w13 of one layer
    bQKV = bWo = bW13 = bw2 = blm = wscratch;
  }

  auto cvt = [&](const float* src, bf16_t* dst, int K_, int N_, int Npad_, int nz,
                 size_t dstride, int imode) {
    dim3 g(Npad_ / 64, K_ / 64, nz);
    k_cvt_t<<<g, 256, 0, stream>>>(src, dst, K_, N_, Npad_, dstride, imode);
  };

  if (bigws) {
    cvt(Wq, bQKV,             DIM, DIM, DIM, NL, 3 * szDD, 0);
    cvt(Wk, bQKV + szDD,      DIM, DIM, DIM, NL, 3 * szDD, 0);
    cvt(Wv, bQKV + 2 * szDD,  DIM, DIM, DIM, NL, 3 * szDD, 0);
    cvt(Wo, bWo,              DIM, DIM, DIM, NL, szDD, 0);
    cvt(w1, bW13,             DIM, FF,  FF,  NL, 2 * szDF, 1);   // interleaved even
    cvt(w3, bW13,             DIM, FF,  FF,  NL, 2 * szDF, 2);   // interleaved odd
    cvt(w2, bw2,              FF,  DIM, DIM, NL, szDF, 0);
    cvt(lmh, blm,             DIM, VOC, VOCP, 1, 0, 0);
  }
  auto wpQKV = [&](int lyr) -> bf16_t* {
    if (bigws) return bQKV + (size_t)lyr * 3 * szDD;
    cvt(Wq + (size_t)lyr * szDD, wscratch,            DIM, DIM, DIM, 1, 0, 0);
    cvt(Wk + (size_t)lyr * szDD, wscratch + szDD,     DIM, DIM, DIM, 1, 0, 0);
    cvt(Wv + (size_t)lyr * szDD, wscratch + 2 * szDD, DIM, DIM, DIM, 1, 0, 0);
    return wscratch;
  };
  auto wpW13 = [&](int lyr) -> bf16_t* {
    if (bigws) return bW13 + (size_t)lyr * 2 * szDF;
    cvt(w1 + (size_t)lyr * szDF, wscratch, DIM, FF, FF, 1, 0, 1);
    cvt(w3 + (size_t)lyr * szDF, wscratch, DIM, FF, FF, 1, 0, 2);
    return wscratch;
  };
  auto wp1 = [&](bf16_t* big, const float* src, int lyr, int K_, int N_, int Npad_) -> bf16_t* {
    if (bigws) return big + (size_t)lyr * Npad_ * K_;
    cvt(src + (size_t)lyr * K_ * N_, wscratch, K_, N_, Npad_, 1, 0, 0);
    return wscratch;
  };

  k_rtab<<<(SEQ * 32) / 256, 256, 0, stream>>>(ctab, stab);
  k_embed<<<SEQ, 256, 0, stream>>>(ids, temb, x);

  dim3 gQKV(3 * DIM / 128, SEQ / 64);    // 24 x 32 = 768 (3/CU, 64x128 tiles)
  dim3 gDD(DIM / 64, SEQ / 64);          // 16 x 32 = 512 (2/CU, 64x64 tiles)
  dim3 gW13(2 * FF / 128, SEQ / 64);     // 64 x 32 = 2048 (3/CU LDS-resident)
  dim3 gLM(VOCP / 64, SEQ / 64);         // 22 x 32 = 704
  dim3 gAt(32, NH);                      // 32 tiles x 16 heads = 512 (2/CU)

  for (int l = 0; l < NL; ++l) {
    k_ln<<<SEQ / 4, 256, 0, stream>>>(x, ln1s + (size_t)l * DIM, ln1b + (size_t)l * DIM, hb);
    k_gemm2<64, 128, 128, 4><<<gQKV, 256, 0, stream>>>(hb, wpQKV(l), nullptr, vb2, qb2, kb2,
                                                       ctab, stab, SEQ, 3 * DIM, DIM);
    k_attn4<<<gAt, 256, 0, stream>>>(qb2, kb2, vb2, aob);
    k_gemm2<64, 64, 128, 2><<<gDD, 256, 0, stream>>>(aob, wp1(bWo, Wo, l, DIM, DIM, DIM), x, nullptr,
                                                     nullptr, nullptr, nullptr, nullptr, SEQ, DIM, DIM);
    k_ln<<<SEQ / 4, 256, 0, stream>>>(x, ln2s + (size_t)l * DIM, ln2b + (size_t)l * DIM, hb);
    k_gemm2<64, 128, 128, 6><<<gW13, 256, 0, stream>>>(hb, wpW13(l), nullptr, nullptr, gateb, nullptr,
                                                       nullptr, nullptr, SEQ, 2 * FF, DIM);
    k_gemm2<64, 64, 128, 2><<<gDD, 256, 0, stream>>>(gateb, wp1(bw2, w2, l, FF, DIM, DIM), x, nullptr,
                                                     nullptr, nullptr, nullptr, nullptr, SEQ, DIM, FF);
  }
  k_ln<<<SEQ / 4, 256, 0, stream>>>(x, lnfs, lnfb, hb);
  k_gemm2<64, 64, 128, 0><<<gLM, 256, 0, stream>>>(hb, bigws ? blm : wp1(blm, lmh, 0, DIM, VOC, VOCP),
                                                   out, nullptr, nullptr, nullptr, nullptr, nullptr,
                                                   SEQ, VOC, DIM);
}

// Round 21
// 2423.160 us; speedup vs baseline: 1.3961x; 1.0035x over previous
//
#include <hip/hip_runtime.h>
#include <math.h>

// ---- problem constants ----
constexpr int SEQ = 2048;
constexpr int DIM = 1024;
constexpr int NH  = 16;
constexpr int HD  = 64;
constexpr int FF  = 4096;
constexpr int NL  = 12;
constexpr int VOC = 1400;
constexpr int VOCP = 1408;   // padded to 64

typedef __bf16 bf16_t;
typedef __bf16 bf16x8 __attribute__((ext_vector_type(8)));
typedef float  f32x4  __attribute__((ext_vector_type(4)));

typedef __attribute__((address_space(1))) const void GV;
typedef __attribute__((address_space(3))) void LV;

__device__ __forceinline__ void gll16(const bf16_t* g, bf16_t* l) {
  __builtin_amdgcn_global_load_lds((GV*)g, (LV*)l, 16, 0, 0);
}

// ---------------- embedding gather ----------------
__global__ __launch_bounds__(256) void k_embed(const int* __restrict__ ids,
                                               const float* __restrict__ emb,
                                               float* __restrict__ x) {
  int s = blockIdx.x;
  int d = threadIdx.x * 4;
  const float4 v = *(const float4*)&emb[(size_t)ids[s] * DIM + d];
  *(float4*)&x[(size_t)s * DIM + d] = v;
}

// ---------------- RoPE cos/sin table: [s][i], i = freq idx 0..31 ----------------
__global__ __launch_bounds__(256) void k_rtab(float* __restrict__ ct,
                                              float* __restrict__ st) {
  int id = blockIdx.x * 256 + threadIdx.x;   // SEQ*32
  int i = id & 31;
  int s = id >> 5;
  float ang = (float)s * powf(10000.f, -(float)i * (1.f / 32.f));
  float sn, cs;
  sincosf(ang, &sn, &cs);
  ct[id] = cs;
  st[id] = sn;
}

// ------- layernorm (f32 in -> bf16 out), 4 rows/block, 1 wave per row -------
__global__ __launch_bounds__(256) void k_ln(const float* __restrict__ x,
                                            const float* __restrict__ sc,
                                            const float* __restrict__ bi,
                                            bf16_t* __restrict__ out) {
  int s = blockIdx.x * 4 + (threadIdx.x >> 6);
  int l = threadIdx.x & 63;
  const float* xr = x + (size_t)s * DIM;
  float4 v[4];
  float sum = 0.f, sq = 0.f;
#pragma unroll
  for (int i = 0; i < 4; ++i) {
    v[i] = *(const float4*)&xr[i * 256 + l * 4];
#pragma unroll
    for (int j = 0; j < 4; ++j) { sum += v[i][j]; sq += v[i][j] * v[i][j]; }
  }
#pragma unroll
  for (int d = 1; d < 64; d <<= 1) {
    sum += __shfl_xor(sum, d);
    sq  += __shfl_xor(sq, d);
  }
  float mean = sum * (1.f / DIM);
  float var  = sq * (1.f / DIM) - mean * mean;
  float inv  = rsqrtf(var + 1e-5f);
#pragma unroll
  for (int i = 0; i < 4; ++i) {
    int off = i * 256 + l * 4;
    float4 scv = *(const float4*)&sc[off];
    float4 biv = *(const float4*)&bi[off];
#pragma unroll
    for (int j = 0; j < 4; ++j) {
      float o = (v[i][j] - mean) * inv * scv[j] + biv[j];
      out[(size_t)s * DIM + off + j] = (bf16_t)o;
    }
  }
}

// ------- weight convert + transpose: src[K][N] f32 -> dst[...][K] bf16 -------
// imode 0: dst row = n. imode 1: w1 f -> (f>>4)*32+(f&15). imode 2: w3 -> +16.
__global__ __launch_bounds__(256) void k_cvt_t(const float* __restrict__ src,
                                               bf16_t* __restrict__ dst,
                                               int K_, int N_, int Npad_,
                                               size_t dstride, int imode) {
  __shared__ bf16_t T[64][66];
  const int k0 = blockIdx.y * 64;
  const int n0 = blockIdx.x * 64;
  const size_t so = (size_t)blockIdx.z * K_ * N_;
  const size_t dof = (size_t)blockIdx.z * dstride;
  const int t = threadIdx.x;
  const int kk = t >> 4;
  const int nn = (t & 15) * 4;
#pragma unroll
  for (int it = 0; it < 4; ++it) {
    int krow = kk + it * 16;
    float4 v = {0.f, 0.f, 0.f, 0.f};
    if (n0 + nn < N_) v = *(const float4*)&src[so + (size_t)(k0 + krow) * N_ + n0 + nn];
#pragma unroll
    for (int q = 0; q < 4; ++q) T[nn + q][krow] = (bf16_t)v[q];
  }
  __syncthreads();
#pragma unroll
  for (int it = 0; it < 4; ++it) {
    int c = it * 256 + t;
    int nr = c >> 4;
    int kc = (c & 15) * 4;
    int f = n0 + nr;
    int drow = (imode == 0) ? f : ((f >> 4) * 32 + ((imode == 2) ? 16 : 0) + (f & 15));
    ushort4 o = *(const ushort4*)&T[nr][kc];
    *(ushort4*)&dst[dof + (size_t)drow * K_ + k0 + kc] = o;
  }
}

// ---------------- GEMM: C[M,N] = A[M,K] * Bt[N][K], bf16 MFMA ----------------
// tile TM x TN, templated BK (64 or 128), 4 waves (2x2; each wave TM/2 x TN/2).
// XOR-swizzled staging generalized: CH=BK/8 chunks/row; stage key (w*RPI+l/CH)&
// (CH-1); reader key r16&(CH-1) (row offsets are multiples of 16 so row&(CH-1)
// == r16&(CH-1)). LDS linear dest + pre-swizzled global source (rule-21 pair).
// OUTMODE 0: f32 store | 2: f32 += | 4: fused QKV(+RoPE) | 6: interleaved silu-gate
template <int TM, int TN, int BK, int OUTMODE>
__global__ __launch_bounds__(256) void k_gemm2(const bf16_t* __restrict__ A,
                                               const bf16_t* __restrict__ Bt,
                                               float* __restrict__ Cf,
                                               bf16_t* __restrict__ Cb,
                                               bf16_t* __restrict__ aux1,
                                               bf16_t* __restrict__ aux2,
                                               const float* __restrict__ ct,
                                               const float* __restrict__ st,
                                               int M, int N, int K) {
  constexpr int MI = TM / 32;            // A frags per wave
  constexpr int JN = TN / 32;            // B frags per wave
  constexpr int CH = BK / 8;             // 16B chunks per row
  constexpr int RPI = 64 / CH;           // rows per wave-issue
  constexpr int RPR = 4 * RPI;           // rows per issue-round (4 waves)
  constexpr int KK = BK / 32;            // mfma k-steps per tile
  __shared__ bf16_t As[TM * BK];
  __shared__ bf16_t Bs[TN * BK];
  const int t = threadIdx.x;
  const int w = t >> 6, l = t & 63;
  const int h = l >> 4, r16 = l & 15;
  const int m0 = blockIdx.y * TM, n0 = blockIdx.x * TN;
  const int wr = (w >> 1) * (TM / 2);
  const int wc = (w & 1) * (TN / 2);
  const int srl = l / CH;                // row within wave-issue slab
  const int scc = l % CH;                // chunk within row
  const int xch = (scc ^ ((w * RPI + srl) & (CH - 1))) * 8;   // pre-swizzled chunk
  const int sN  = r16 & (CH - 1);        // reader swizzle key

  f32x4 acc[MI][JN] = {};

  const bf16_t* pa = &A[(size_t)(m0 + w * RPI + srl) * K + xch];
  const bf16_t* pb = &Bt[(size_t)(n0 + w * RPI + srl) * K + xch];

  for (int k0 = 0; k0 < K; k0 += BK) {
#pragma unroll
    for (int i = 0; i < TM / RPR; ++i)
      gll16(pa + (size_t)i * RPR * K + k0, &As[(i * RPR + w * RPI) * BK]);
#pragma unroll
    for (int i = 0; i < TN / RPR; ++i)
      gll16(pb + (size_t)i * RPR * K + k0, &Bs[(i * RPR + w * RPI) * BK]);
    __syncthreads();
#pragma unroll
    for (int kk = 0; kk < KK; ++kk) {
      const int p = ((kk * 4 + h) ^ sN) * 8;   // swizzled read position (elems)
      bf16x8 af[MI], bfr[JN];
#pragma unroll
      for (int i = 0; i < MI; ++i)
        af[i] = *(const bf16x8*)&As[(wr + i * 16 + r16) * BK + p];
#pragma unroll
      for (int j = 0; j < JN; ++j)
        bfr[j] = *(const bf16x8*)&Bs[(wc + j * 16 + r16) * BK + p];
#pragma unroll
      for (int i = 0; i < MI; ++i)
#pragma unroll
        for (int j = 0; j < JN; ++j)
          acc[i][j] = __builtin_amdgcn_mfma_f32_16x16x32_bf16(af[i], bfr[j], acc[i][j], 0, 0, 0);
    }
    __syncthreads();
  }

  if constexpr (OUTMODE == 4) {
    const int reg = n0 >> 10;
    const int cbase = (n0 & 1023) + wc;
    if (reg == 2) {
#pragma unroll
      for (int i = 0; i < MI; ++i)
#pragma unroll
        for (int j = 0; j < JN; ++j)
#pragma unroll
          for (int r = 0; r < 4; ++r) {
            int row = m0 + wr + i * 16 + h * 4 + r;
            Cb[(size_t)row * DIM + cbase + j * 16 + r16] = (bf16_t)acc[i][j][r];
          }
    } else {
      bf16_t* dst = reg ? aux2 : aux1;
#pragma unroll
      for (int i = 0; i < MI; ++i)
#pragma unroll
        for (int r = 0; r < 4; ++r) {
          int row = m0 + wr + i * 16 + h * 4 + r;
          float c0 = ct[row * 32 + r16],      s0 = st[row * 32 + r16];
          float c1 = ct[row * 32 + 16 + r16], s1 = st[row * 32 + 16 + r16];
          float lo0 = acc[i][0][r], hi0 = acc[i][2][r];
          float lo1 = acc[i][1][r], hi1 = acc[i][3][r];
          size_t rb = (size_t)row * DIM + cbase;
          dst[rb + r16]      = (bf16_t)(lo0 * c0 - hi0 * s0);
          dst[rb + 32 + r16] = (bf16_t)(hi0 * c0 + lo0 * s0);
          dst[rb + 16 + r16] = (bf16_t)(lo1 * c1 - hi1 * s1);
          dst[rb + 48 + r16] = (bf16_t)(hi1 * c1 + lo1 * s1);
        }
    }
  } else if constexpr (OUTMODE == 6) {
    const int fbase = ((n0 + wc) >> 5) * 16;
#pragma unroll
    for (int i = 0; i < MI; ++i)
#pragma unroll
      for (int r = 0; r < 4; ++r) {
        int row = m0 + wr + i * 16 + h * 4 + r;
        float a0 = acc[i][0][r], b0 = acc[i][1][r];
        float a1 = acc[i][2][r], b1 = acc[i][3][r];
        float g0 = a0 / (1.f + expf(-a0)) * b0;
        float g1v = a1 / (1.f + expf(-a1)) * b1;
        size_t rb = (size_t)row * FF + fbase;
        aux1[rb + r16]      = (bf16_t)g0;
        aux1[rb + 16 + r16] = (bf16_t)g1v;
      }
  } else {
#pragma unroll
    for (int i = 0; i < MI; ++i)
#pragma unroll
      for (int j = 0; j < JN; ++j)
#pragma unroll
        for (int r = 0; r < 4; ++r) {
          int row = m0 + wr + i * 16 + h * 4 + r;
          int col = n0 + wc + j * 16 + r16;
          if (col < N) {
            float vv = acc[i][j][r];
            size_t idx = (size_t)row * N + col;
            if (OUTMODE == 0) Cf[idx] = vv;
            else Cf[idx] += vv;
          }
        }
  }
}

// ------- flash attention: 4 waves/block, swapped-QK, one 64-row tile/block -------
// KVBLK=128 (round-18, best measured). 512 blocks (2/CU), complementary pairing.
// T14 async-STAGE: next chunk's loads issue into regs before chunk-t compute.
__global__ __launch_bounds__(256) void k_attn4(const bf16_t* __restrict__ qb,
                                               const bf16_t* __restrict__ kb,
                                               const bf16_t* __restrict__ vb,
                                               bf16_t* __restrict__ ao) {
  __shared__ bf16_t Ks[128][72];      // K chunk: [key][dh]
  __shared__ bf16_t Vt[64][136];      // V chunk transposed: [dh][key]
  __shared__ bf16_t Pl[4][16][136];   // per-wave P: [qrow][key]
  const int raw = blockIdx.x;         // 0..31
  const int head = blockIdx.y;        // 0..15
  const int qt = (head < 8) ? raw : (31 - raw);   // complementary per-CU pairing
  const int t = threadIdx.x;
  const int w = t >> 6, l = t & 63;
  const int h = l >> 4, r16 = l & 15;
  const size_t hoff = (size_t)head * HD;
  const int srow = t >> 1;            // 0..127 staging row (key)
  const int sc4  = (t & 1) * 4;       // which 4 of 8 dh-vectors

  const int q0 = qt * 64 + w * 16;    // this wave's first q row
  const int q_abs = q0 + r16;         // this lane's q row (softmax axis)

  bf16x8 aq[2];
#pragma unroll
  for (int c = 0; c < 2; ++c)
    aq[c] = *(const bf16x8*)&qb[(size_t)(q0 + r16) * DIM + hoff + c * 32 + h * 8];

  f32x4 o[4] = {};
  float mrun = -1e30f, lrun = 0.f;

  const int kend = qt * 64 + 63;

  // ---- preload chunk 0 into regs ----
  bf16x8 kreg[4], vreg[4];
#pragma unroll
  for (int it = 0; it < 4; ++it) {
    kreg[it] = *(const bf16x8*)&kb[(size_t)srow * DIM + hoff + (sc4 + it) * 8];
    vreg[it] = *(const bf16x8*)&vb[(size_t)srow * DIM + hoff + (sc4 + it) * 8];
  }

  for (int k0 = 0; k0 <= kend; k0 += 128) {
    // ---- write staged regs to LDS: K direct, V transposed ----
#pragma unroll
    for (int it = 0; it < 4; ++it)
      *(bf16x8*)&Ks[srow][(sc4 + it) * 8] = kreg[it];
#pragma unroll
    for (int it = 0; it < 4; ++it)
#pragma unroll
      for (int j = 0; j < 8; ++j) Vt[(sc4 + it) * 8 + j][srow] = vreg[it][j];
    __syncthreads();

    // ---- issue next chunk's global loads (overlap with compute below) ----
    if (k0 + 128 <= kend) {
      const size_t nb = (size_t)(k0 + 128 + srow) * DIM + hoff;
#pragma unroll
      for (int it = 0; it < 4; ++it) {
        kreg[it] = *(const bf16x8*)&kb[nb + (sc4 + it) * 8];
        vreg[it] = *(const bf16x8*)&vb[nb + (sc4 + it) * 8];
      }
    }

    if (k0 <= q0 + 15) {              // wave-uniform: skip fully-masked chunks
      // ---- scores transposed: D[key][q], 8 col-tiles of 16 keys ----
      f32x4 sc[8];
      __builtin_amdgcn_s_setprio(1);
#pragma unroll
      for (int tc = 0; tc < 8; ++tc) {
        f32x4 z = {};
        bf16x8 a0 = *(const bf16x8*)&Ks[tc * 16 + r16][h * 8];
        bf16x8 a1 = *(const bf16x8*)&Ks[tc * 16 + r16][32 + h * 8];
        z = __builtin_amdgcn_mfma_f32_16x16x32_bf16(a0, aq[0], z, 0, 0, 0);
        z = __builtin_amdgcn_mfma_f32_16x16x32_bf16(a1, aq[1], z, 0, 0, 0);
        sc[tc] = z;
      }
      __builtin_amdgcn_s_setprio(0);
      // ---- mask + scale; per-lane max over 32 keys ----
      float pmax = -1e30f;
#pragma unroll
      for (int tc = 0; tc < 8; ++tc)
#pragma unroll
        for (int r = 0; r < 4; ++r) {
          int key = k0 + tc * 16 + h * 4 + r;
          float v = sc[tc][r] * 0.125f;
          if (key > q_abs) v = -1e30f;
          sc[tc][r] = v;
          pmax = fmaxf(pmax, v);
        }
      pmax = fmaxf(pmax, __shfl_xor(pmax, 16));
      pmax = fmaxf(pmax, __shfl_xor(pmax, 32));
      float mnew = fmaxf(mrun, pmax);
      float alpha = expf(mrun - mnew);
      mrun = mnew;
      float ssum = 0.f;
#pragma unroll
      for (int tc = 0; tc < 8; ++tc)
#pragma unroll
        for (int r = 0; r < 4; ++r) {
          float pv = expf(sc[tc][r] - mnew);
          sc[tc][r] = pv;
          ssum += pv;
        }
      ssum += __shfl_xor(ssum, 16);
      ssum += __shfl_xor(ssum, 32);
      lrun = lrun * alpha + ssum;
      // ---- write P^T to LDS: Pl[q][key] ----
#pragma unroll
      for (int tc = 0; tc < 8; ++tc)
#pragma unroll
        for (int r = 0; r < 4; ++r)
          Pl[w][r16][tc * 16 + h * 4 + r] = (bf16_t)sc[tc][r];
      // ---- rescale o: alpha for o-row q=h*4+r lives in lane h*4+r ----
      float ar[4];
#pragma unroll
      for (int r = 0; r < 4; ++r) ar[r] = __shfl(alpha, h * 4 + r);
#pragma unroll
      for (int cti = 0; cti < 4; ++cti)
#pragma unroll
        for (int r = 0; r < 4; ++r) o[cti][r] *= ar[r];
      // ---- PV: 4 k-slices of 32 keys ----
      __builtin_amdgcn_s_setprio(1);
#pragma unroll
      for (int ks = 0; ks < 4; ++ks) {
        bf16x8 pk = *(const bf16x8*)&Pl[w][r16][ks * 32 + h * 8];
#pragma unroll
        for (int cti = 0; cti < 4; ++cti) {
          bf16x8 vv = *(const bf16x8*)&Vt[cti * 16 + r16][ks * 32 + h * 8];
          o[cti] = __builtin_amdgcn_mfma_f32_16x16x32_bf16(pk, vv, o[cti], 0, 0, 0);
        }
      }
      __builtin_amdgcn_s_setprio(0);
    }
    __syncthreads();
  }
  float lr[4];
#pragma unroll
  for (int r = 0; r < 4; ++r) lr[r] = __shfl(lrun, h * 4 + r);
#pragma unroll
  for (int cti = 0; cti < 4; ++cti)
#pragma unroll
    for (int r = 0; r < 4; ++r) {
      int row = q0 + h * 4 + r;
      ao[(size_t)row * DIM + hoff + cti * 16 + r16] = (bf16_t)(o[cti][r] / lr[r]);
    }
}

extern "C" void kernel_launch(void* const* d_in, const int* in_sizes, int n_in,
                              void* d_out, int out_size, void* d_ws, size_t ws_size,
                              hipStream_t stream) {
  const int*   ids  = (const int*)d_in[0];
  const float* temb = (const float*)d_in[1];
  const float* Wq   = (const float*)d_in[2];
  const float* Wk   = (const float*)d_in[3];
  const float* Wv   = (const float*)d_in[4];
  const float* Wo   = (const float*)d_in[5];
  const float* ln1s = (const float*)d_in[6];
  const float* ln1b = (const float*)d_in[7];
  const float* ln2s = (const float*)d_in[8];
  const float* ln2b = (const float*)d_in[9];
  const float* w1   = (const float*)d_in[10];
  const float* w2   = (const float*)d_in[11];
  const float* w3   = (const float*)d_in[12];
  const float* lnfs = (const float*)d_in[13];
  const float* lnfb = (const float*)d_in[14];
  const float* lmh  = (const float*)d_in[15];
  float* out = (float*)d_out;

  char* p = (char*)d_ws;
  size_t used = 0;
  auto alloc = [&](size_t bytes) {
    void* r = (void*)p;
    size_t a = (bytes + 255) & ~(size_t)255;
    p += a; used += a;
    return r;
  };
  // activations + tables
  float*  x     = (float*)alloc((size_t)SEQ * DIM * 4);
  bf16_t* hb    = (bf16_t*)alloc((size_t)SEQ * DIM * 2);
  bf16_t* qb2   = (bf16_t*)alloc((size_t)SEQ * DIM * 2);
  bf16_t* kb2   = (bf16_t*)alloc((size_t)SEQ * DIM * 2);
  bf16_t* vb2   = (bf16_t*)alloc((size_t)SEQ * DIM * 2);
  bf16_t* aob   = (bf16_t*)alloc((size_t)SEQ * DIM * 2);
  bf16_t* gateb = (bf16_t*)alloc((size_t)SEQ * FF * 2);
  float*  ctab  = (float*)alloc((size_t)SEQ * 32 * 4);
  float*  stab  = (float*)alloc((size_t)SEQ * 32 * 4);

  const size_t szDD = (size_t)DIM * DIM;    // 1M elems
  const size_t szDF = (size_t)DIM * FF;     // 4M elems
  const size_t wt_bytes = ((size_t)NL * (3 * szDD + szDD + 2 * szDF + szDF) + (size_t)VOCP * DIM) * 2;
  const bool bigws = (ws_size >= used + wt_bytes + (1u << 20));

  bf16_t *bQKV, *bWo, *bW13, *bw2, *blm, *wscratch = nullptr;
  if (bigws) {
    bQKV = (bf16_t*)alloc(NL * 3 * szDD * 2);
    bWo  = (bf16_t*)alloc(NL * szDD * 2);
    bW13 = (bf16_t*)alloc(NL * 2 * szDF * 2);
    bw2  = (bf16_t*)alloc(NL * szDF * 2);
    blm  = (bf16_t*)alloc((size_t)VOCP * DIM * 2);
  } else {
    wscratch = (bf16_t*)alloc(2 * szDF * 2);   // enough for fused w13 of one layer
    bQKV = bWo = bW13 = bw2 = blm = wscratch;
  }

  auto cvt = [&](const float* src, bf16_t* dst, int K_, int N_, int Npad_, int nz,
                 size_t dstride, int imode) {
    dim3 g(Npad_ / 64, K_ / 64, nz);
    k_cvt_t<<<g, 256, 0, stream>>>(src, dst, K_, N_, Npad_, dstride, imode);
  };

  if (bigws) {
    cvt(Wq, bQKV,             DIM, DIM, DIM, NL, 3 * szDD, 0);
    cvt(Wk, bQKV + szDD,      DIM, DIM, DIM, NL, 3 * szDD, 0);
    cvt(Wv, bQKV + 2 * szDD,  DIM, DIM, DIM, NL, 3 * szDD, 0);
    cvt(Wo, bWo,              DIM, DIM, DIM, NL, szDD, 0);
    cvt(w1, bW13,             DIM, FF,  FF,  NL, 2 * szDF, 1);   // interleaved even
    cvt(w3, bW13,             DIM, FF,  FF,  NL, 2 * szDF, 2);   // interleaved odd
    cvt(w2, bw2,              FF,  DIM, DIM, NL, szDF, 0);
    cvt(lmh, blm,             DIM, VOC, VOCP, 1, 0, 0);
  }
  auto wpQKV = [&](int lyr) -> bf16_t* {
    if (bigws) return bQKV + (size_t)lyr * 3 * szDD;
    cvt(Wq + (size_t)lyr * szDD, wscratch,            DIM, DIM, DIM, 1, 0, 0);
    cvt(Wk + (size_t)lyr * szDD, wscratch + szDD,     DIM, DIM, DIM, 1, 0, 0);
    cvt(Wv + (size_t)lyr * szDD, wscratch + 2 * szDD, DIM, DIM, DIM, 1, 0, 0);
    return wscratch;
  };
  auto wpW13 = [&](int lyr) -> bf16_t* {
    if (bigws) return bW13 + (size_t)lyr * 2 * szDF;
    cvt(w1 + (size_t)lyr * szDF, wscratch, DIM, FF, FF, 1, 0, 1);
    cvt(w3 + (size_t)lyr * szDF, wscratch, DIM, FF, FF, 1, 0, 2);
    return wscratch;
  };
  auto wp1 = [&](bf16_t* big, const float* src, int lyr, int K_, int N_, int Npad_) -> bf16_t* {
    if (bigws) return big + (size_t)lyr * Npad_ * K_;
    cvt(src + (size_t)lyr * K_ * N_, wscratch, K_, N_, Npad_, 1, 0, 0);
    return wscratch;
  };

  k_rtab<<<(SEQ * 32) / 256, 256, 0, stream>>>(ctab, stab);
  k_embed<<<SEQ, 256, 0, stream>>>(ids, temb, x);

  dim3 gQKV(3 * DIM / 128, SEQ / 64);    // 24 x 32 = 768 (3/CU, 64x128 tiles)
  dim3 gDD(DIM / 64, SEQ / 32);          // 16 x 64 = 1024 (4/CU, 32x64 tiles)
  dim3 gW13(2 * FF / 128, SEQ / 64);     // 64 x 32 = 2048 (3/CU LDS-resident)
  dim3 gLM(VOCP / 64, SEQ / 32);         // 22 x 64 = 1408
  dim3 gAt(32, NH);                      // 32 tiles x 16 heads = 512 (2/CU)

  for (int l = 0; l < NL; ++l) {
    k_ln<<<SEQ / 4, 256, 0, stream>>>(x, ln1s + (size_t)l * DIM, ln1b + (size_t)l * DIM, hb);
    k_gemm2<64, 128, 128, 4><<<gQKV, 256, 0, stream>>>(hb, wpQKV(l), nullptr, vb2, qb2, kb2,
                                                       ctab, stab, SEQ, 3 * DIM, DIM);
    k_attn4<<<gAt, 256, 0, stream>>>(qb2, kb2, vb2, aob);
    k_gemm2<32, 64, 128, 2><<<gDD, 256, 0, stream>>>(aob, wp1(bWo, Wo, l, DIM, DIM, DIM), x, nullptr,
                                                     nullptr, nullptr, nullptr, nullptr, SEQ, DIM, DIM);
    k_ln<<<SEQ / 4, 256, 0, stream>>>(x, ln2s + (size_t)l * DIM, ln2b + (size_t)l * DIM, hb);
    k_gemm2<64, 128, 128, 6><<<gW13, 256, 0, stream>>>(hb, wpW13(l), nullptr, nullptr, gateb, nullptr,
                                                       nullptr, nullptr, SEQ, 2 * FF, DIM);
    k_gemm2<32, 64, 128, 2><<<gDD, 256, 0, stream>>>(gateb, wp1(bw2, w2, l, FF, DIM, DIM), x, nullptr,
                                                     nullptr, nullptr, nullptr, nullptr, SEQ, DIM, FF);
  }
  k_ln<<<SEQ / 4, 256, 0, stream>>>(x, lnfs, lnfb, hb);
  k_gemm2<32, 64, 128, 0><<<gLM, 256, 0, stream>>>(hb, bigws ? blm : wp1(blm, lmh, 0, DIM, VOC, VOCP),
                                                   out, nullptr, nullptr, nullptr, nullptr, nullptr,
                                                   SEQ, VOC, DIM);
}